// Round 3
// baseline (1560.758 us; speedup 1.0000x reference)
//
#include <hip/hip_runtime.h>
#include <hip/hip_bf16.h>

#define N_ENT 100000
#define HDIM 128
#define NE 200000
#define NR 460
#define NSTEP 4
#define SLOPE 0.22916666666666666f
#define NPAD 100352            // N_ENT padded to 1024 multiple (98*1024)
#define SCAN_NB 98

typedef __attribute__((ext_vector_type(8))) short short8;
typedef __attribute__((ext_vector_type(4))) float f32x4;

__device__ __forceinline__ float sigm(float x) { return 1.0f / (1.0f + __expf(-x)); }
__device__ __forceinline__ short f2bs(float f) {
    __hip_bfloat16 b = __float2bfloat16(f);
    short s; __builtin_memcpy(&s, &b, 2); return s;
}
__device__ __forceinline__ float bs2f(short s) {
    union { unsigned int u; float f; } c;
    c.u = ((unsigned int)(unsigned short)s) << 16;
    return c.f;
}

// ---------------------------------------------------------------------------
__global__ void zero_int_kernel(int* __restrict__ p, int n)
{
    int i = blockIdx.x * 256 + threadIdx.x;
    if (i < n) p[i] = 0;
}

__global__ void diag_kernel(float* o, float v)
{
    if (threadIdx.x == 0) o[0] = v;
}

// ---------------------------------------------------------------------------
// CSR build: histogram -> 3-phase exclusive scan -> fill
// ---------------------------------------------------------------------------
__global__ void hist_kernel(const int* __restrict__ dst, int* __restrict__ cnt)
{
    int e = blockIdx.x * 256 + threadIdx.x;
    if (e < NE) atomicAdd(&cnt[dst[e]], 1);
}

__global__ __launch_bounds__(256)
void scan1_kernel(const int* __restrict__ cnt, int* __restrict__ rowptr,
                  int* __restrict__ bsum)
{
    __shared__ int ts[256];
    int b = blockIdx.x, t = threadIdx.x;
    int base = b * 1024 + t * 4;
    int4 v = *(const int4*)&cnt[base];
    int s = v.x + v.y + v.z + v.w;
    ts[t] = s;
    __syncthreads();
    for (int off = 1; off < 256; off <<= 1) {
        int x = 0;
        if (t >= off) x = ts[t - off];
        __syncthreads();
        if (t >= off) ts[t] += x;
        __syncthreads();
    }
    int excl = ts[t] - s;
    if (t == 255) bsum[b] = ts[t];
    rowptr[base + 0] = excl;
    rowptr[base + 1] = excl + v.x;
    rowptr[base + 2] = excl + v.x + v.y;
    rowptr[base + 3] = excl + v.x + v.y + v.z;
}

__global__ __launch_bounds__(128)
void scan2_kernel(int* __restrict__ bsum, int nb)
{
    __shared__ int ts[128];
    int t = threadIdx.x;
    int v = (t < nb) ? bsum[t] : 0;
    ts[t] = v;
    __syncthreads();
    for (int off = 1; off < 128; off <<= 1) {
        int x = 0;
        if (t >= off) x = ts[t - off];
        __syncthreads();
        if (t >= off) ts[t] += x;
        __syncthreads();
    }
    if (t < nb) bsum[t] = ts[t] - v;   // exclusive
}

__global__ __launch_bounds__(256)
void scan3_kernel(int* __restrict__ rowptr, const int* __restrict__ bsum)
{
    int b = blockIdx.x, t = threadIdx.x;
    int add = bsum[b];
    int base = b * 1024 + t * 4;
    rowptr[base + 0] += add;
    rowptr[base + 1] += add;
    rowptr[base + 2] += add;
    rowptr[base + 3] += add;
}

__global__ void fill_kernel(const int* __restrict__ dst,
                            const int* __restrict__ rowptr,
                            int* __restrict__ c2, int* __restrict__ eidx)
{
    int e = blockIdx.x * 256 + threadIdx.x;
    if (e < NE) {
        int d = dst[e];
        int p = atomicAdd(&c2[d], 1);
        eidx[rowptr[d] + p] = e;
    }
}

// ---------------------------------------------------------------------------
// Prep: GRU weight transposes (f32) + bf16 B^T buffers for the MFMA GEMMs.
// ---------------------------------------------------------------------------
__global__ void prep_kernel(
    const float* __restrict__ emb_rel,
    const float* __restrict__ Wx, const float* __restrict__ Wh,
    const float* __restrict__ Wn1, const float* __restrict__ Wl1,
    const float* __restrict__ Wn2, const float* __restrict__ Wl2,
    const float* __restrict__ tgW, const float* __restrict__ gateW,
    const float* __restrict__ tdW,
    float* __restrict__ rel,
    float* __restrict__ WxT, float* __restrict__ WhT,
    short* __restrict__ BT1, short* __restrict__ BT2,
    short* __restrict__ BTe1, short* __restrict__ BTe2,
    short* __restrict__ BTe3)
{
    int tid = blockIdx.x * blockDim.x + threadIdx.x;
    int nthr = gridDim.x * blockDim.x;
    for (int i = tid; i < NR * HDIM; i += nthr)
        rel[i] = emb_rel[i];
    for (int i = tid; i < 384 * 256; i += nthr) {
        int r = i >> 8, c = i & 255;
        WxT[c * 384 + r] = Wx[i];
    }
    for (int i = tid; i < 384 * 128; i += nthr) {
        int r = i >> 7, c = i & 127;
        WhT[c * 384 + r] = Wh[i];
    }
    for (int i = tid; i < 128 * 256; i += nthr) {   // layer BTs: [x|h]@[Wn;Wl]
        int n = i >> 8, k = i & 255;
        float v1 = (k < 128) ? Wn1[k * 128 + n] : Wl1[(k - 128) * 128 + n];
        float v2 = (k < 128) ? Wn2[k * 128 + n] : Wl2[(k - 128) * 128 + n];
        BT1[n * 256 + k] = f2bs(v1);
        BT2[n * 256 + k] = f2bs(v2);
    }
    for (int i = tid; i < 128 * 128; i += nthr) {   // E1 (transpose), E3 (direct)
        int n = i >> 7, k = i & 127;
        BTe1[n * 128 + k] = f2bs(tgW[k * 128 + n]);
        BTe3[n * 128 + k] = f2bs(tdW[n * 128 + k]);
    }
    for (int i = tid; i < 128 * 256; i += nthr) {   // E2 (direct)
        int n = i >> 8, k = i & 255;
        BTe2[n * 256 + k] = f2bs(gateW[n * 256 + k]);
    }
}

// ---------------------------------------------------------------------------
// h0 = l2norm(dynamic_emb); one wave per row.
// ---------------------------------------------------------------------------
__global__ __launch_bounds__(64)
void norm_init_kernel(const float* __restrict__ emb, float* __restrict__ h)
{
    int row = blockIdx.x, lane = threadIdx.x;
    float v0 = emb[row * HDIM + lane];
    float v1 = emb[row * HDIM + 64 + lane];
    float s = v0 * v0 + v1 * v1;
    #pragma unroll
    for (int off = 32; off; off >>= 1) s += __shfl_xor(s, off);
    float invn = 1.0f / fmaxf(sqrtf(s), 1e-12f);
    h[row * HDIM + lane] = v0 * invn;
    h[row * HDIM + 64 + lane] = v1 * invn;
}

// ---------------------------------------------------------------------------
// GRUCell relation evolution (f32 GEMV — tiny: 460 rows).
// ---------------------------------------------------------------------------
__global__ __launch_bounds__(128)
void gru_kernel(float* rel, const float* __restrict__ emb_rel,
                const float* __restrict__ WxT, const float* __restrict__ WhT,
                const float* __restrict__ bx, const float* __restrict__ bh)
{
    __shared__ __align__(16) float x[256];
    __shared__ __align__(16) float hh[128];
    int b = blockIdx.x, j = threadIdx.x;
    float hj = rel[b * HDIM + j];
    x[j] = emb_rel[b * HDIM + j];
    x[128 + j] = hj;
    hh[j] = hj;
    __syncthreads();
    float xr = 0, xz = 0, xn = 0, hr = 0, hz = 0, hn = 0;
    for (int k = 0; k < 256; k++) {
        float xv = x[k];
        const float* w = &WxT[k * 384];
        xr += xv * w[j]; xz += xv * w[128 + j]; xn += xv * w[256 + j];
    }
    for (int k = 0; k < 128; k++) {
        float hv = hh[k];
        const float* w = &WhT[k * 384];
        hr += hv * w[j]; hz += hv * w[128 + j]; hn += hv * w[256 + j];
    }
    float r = sigm(xr + bx[j] + hr + bh[j]);
    float z = sigm(xz + bx[128 + j] + hz + bh[128 + j]);
    float n = tanhf(xn + bx[256 + j] + r * (hn + bh[256 + j]));
    rel[b * HDIM + j] = (1.0f - z) * n + z * hj;
}

// ---------------------------------------------------------------------------
// CSR gather for rows [lo,hi): aggb[r-lo] = bf16((sum_e h[src]+rel[et])/deg).
// One thread per (row, 2 dims); 64 threads per row; packed 4B stores.
// ---------------------------------------------------------------------------
__global__ __launch_bounds__(256)
void gather_kernel(const int* __restrict__ src, const int* __restrict__ et,
                   const int* __restrict__ eidx, const int* __restrict__ rowptr,
                   const float* __restrict__ hin, const float* __restrict__ rel,
                   short* __restrict__ aggb, int lo, int hi)
{
    int idx = blockIdx.x * 256 + threadIdx.x;
    int r = lo + (idx >> 6);
    int i2 = (idx & 63) * 2;
    if (r >= hi) return;
    int p0 = rowptr[r], p1 = rowptr[r + 1];
    float v0 = 0.0f, v1 = 0.0f;
    for (int p = p0; p < p1; p++) {
        int e = eidx[p];
        int s = src[e], rt = et[e];
        const float* ph = &hin[(long)s * HDIM + i2];
        const float* pr = &rel[rt * HDIM + i2];
        v0 += ph[0] + pr[0];
        v1 += ph[1] + pr[1];
    }
    float rdeg = (p1 > p0) ? 1.0f / (float)(p1 - p0) : 0.0f;
    unsigned int pk = (unsigned int)(unsigned short)f2bs(v0 * rdeg)
                    | ((unsigned int)(unsigned short)f2bs(v1 * rdeg) << 16);
    *(unsigned int*)&aggb[(long)(r - lo) * HDIM + i2] = pk;
}

// ---------------------------------------------------------------------------
// Layer-1 MFMA GEMM: out = rrelu([aggb | h] @ BT^T).
// ---------------------------------------------------------------------------
__global__ __launch_bounds__(256, 2)
void layer_gemm(const short* __restrict__ aggb, const float* __restrict__ hin,
                const short* __restrict__ BTg, float* __restrict__ out,
                int lo, int hi)
{
    const int tid = threadIdx.x;
    const int lane = tid & 63;
    const int wv = tid >> 6;
    const int m = lane & 15, q = lane >> 4;
    const int rowBase = lo + blockIdx.x * 256 + wv * 64;

    f32x4 acc[4][8];
    #pragma unroll
    for (int rt = 0; rt < 4; rt++)
        #pragma unroll
        for (int ct = 0; ct < 8; ct++)
            acc[rt][ct] = (f32x4)0.0f;

    for (int kc = 0; kc < 8; kc++) {
        short8 a[4];
        #pragma unroll
        for (int rt = 0; rt < 4; rt++) {
            int row = rowBase + rt * 16 + m;
            int k0 = kc * 32 + q * 8;
            if (row < hi) {
                if (kc < 4) {
                    a[rt] = *(const short8*)&aggb[(long)(row - lo) * HDIM + k0];
                } else {
                    const float* p = &hin[(long)row * HDIM + (k0 - 128)];
                    float4 u0 = *(const float4*)p;
                    float4 u1 = *(const float4*)(p + 4);
                    short8 t;
                    t[0]=f2bs(u0.x); t[1]=f2bs(u0.y); t[2]=f2bs(u0.z); t[3]=f2bs(u0.w);
                    t[4]=f2bs(u1.x); t[5]=f2bs(u1.y); t[6]=f2bs(u1.z); t[7]=f2bs(u1.w);
                    a[rt] = t;
                }
            } else {
                short8 t;
                #pragma unroll
                for (int i = 0; i < 8; i++) t[i] = 0;
                a[rt] = t;
            }
        }
        short8 b[8];
        #pragma unroll
        for (int ct = 0; ct < 8; ct++)
            b[ct] = *(const short8*)&BTg[(ct * 16 + m) * 256 + kc * 32 + q * 8];
        #pragma unroll
        for (int rt = 0; rt < 4; rt++)
            #pragma unroll
            for (int ct = 0; ct < 8; ct++)
                acc[rt][ct] = __builtin_amdgcn_mfma_f32_16x16x32_bf16(
                    a[rt], b[ct], acc[rt][ct], 0, 0, 0);
    }

    #pragma unroll
    for (int rt = 0; rt < 4; rt++) {
        #pragma unroll
        for (int rg = 0; rg < 4; rg++) {
            int row = rowBase + rt * 16 + q * 4 + rg;
            if (row >= hi) continue;
            #pragma unroll
            for (int ct = 0; ct < 8; ct++) {
                int col = ct * 16 + m;
                float c = acc[rt][ct][rg];
                c = c >= 0.0f ? c : SLOPE * c;
                out[(long)row * HDIM + col] = c;
            }
        }
    }
}

// ---------------------------------------------------------------------------
// Fused layer2 GEMM + epilogue v6: cur = rrelu([aggb|B] @ BT2^T) is computed
// in registers (never materialized to HBM), l2-normalized via shfl+LDS
// partials, then the v5 epilogue (E1/E2/E3) runs in-block.
//   32 rows/block, 4 waves; wave = 16 rows x 64 cols (4 col-tiles).
//   In-place A update is safe: each block owns its 32 rows exclusively.
//   Saves per step: C write + C read (102.4 MB) + one full dispatch.
// ---------------------------------------------------------------------------
#define ER 32                  // rows per block
#define ES 136                 // bf16 row stride (shorts)
__global__ __launch_bounds__(256, 8)
void layer2_epi_kernel(const short* __restrict__ aggb, const float* __restrict__ Bin,
                       const short* __restrict__ BTg, const float* __restrict__ hprev,
                       const short* __restrict__ BTe1, const short* __restrict__ BTe2,
                       const short* __restrict__ BTe3,
                       const float* __restrict__ bt, const float* __restrict__ bg,
                       const float* __restrict__ btd,
                       float* __restrict__ outp, int lo)
{
    __shared__ __align__(16) short cs[ER * ES];   // cur_n -> h1 -> h2
    __shared__ __align__(16) short hd[ER * ES];   // h -> d
    __shared__ float part[2][ER];                 // per-row sumsq halves
    const int tid = threadIdx.x;
    const long row0 = (long)lo + (long)blockIdx.x * ER;   // all rows valid

    // ---- stage hprev (A) rows as bf16 into hd (loads overlap the GEMM)
    #pragma unroll
    for (int it = 0; it < 2; it++) {
        int s = it * 256 + tid;
        int r = s >> 4, c8 = (s & 15) * 8;
        const float* ph = &hprev[(row0 + r) * HDIM + c8];
        float4 h0 = *(const float4*)ph, h1 = *(const float4*)(ph + 4);
        short8 th;
        th[0]=f2bs(h0.x); th[1]=f2bs(h0.y); th[2]=f2bs(h0.z); th[3]=f2bs(h0.w);
        th[4]=f2bs(h1.x); th[5]=f2bs(h1.y); th[6]=f2bs(h1.z); th[7]=f2bs(h1.w);
        *(short8*)&hd[r * ES + c8] = th;
    }

    const int wv = tid >> 6, lane = tid & 63;
    const int m = lane & 15, q = lane >> 4;
    const int wr0 = (wv >> 1) * 16;                // wave's row base (0 or 16)
    const int ct0 = (wv & 1) * 4;                  // wave's col-tile base

    // ---- layer-2 GEMM: wave computes cur[wr0..wr0+16) x cols [ct0*16, ct0*16+64)
    f32x4 acc[4];
    #pragma unroll
    for (int ct = 0; ct < 4; ct++) acc[ct] = (f32x4)0.0f;
    #pragma unroll
    for (int kc = 0; kc < 8; kc++) {
        int k0 = kc * 32 + q * 8;
        short8 a;
        if (kc < 4) {
            a = *(const short8*)&aggb[((long)blockIdx.x * ER + wr0 + m) * HDIM + k0];
        } else {
            const float* p = &Bin[(row0 + wr0 + m) * HDIM + (k0 - 128)];
            float4 u0 = *(const float4*)p;
            float4 u1 = *(const float4*)(p + 4);
            a[0]=f2bs(u0.x); a[1]=f2bs(u0.y); a[2]=f2bs(u0.z); a[3]=f2bs(u0.w);
            a[4]=f2bs(u1.x); a[5]=f2bs(u1.y); a[6]=f2bs(u1.z); a[7]=f2bs(u1.w);
        }
        #pragma unroll
        for (int ct = 0; ct < 4; ct++) {
            short8 b = *(const short8*)&BTg[((ct0 + ct) * 16 + m) * 256 + k0];
            acc[ct] = __builtin_amdgcn_mfma_f32_16x16x32_bf16(a, b, acc[ct], 0, 0, 0);
        }
    }

    // ---- rrelu + per-row sumsq over this wave's 64 cols
    float vals[4][4];            // [ct][rg]
    float ssq0 = 0, ssq1 = 0, ssq2 = 0, ssq3 = 0;
    #pragma unroll
    for (int ct = 0; ct < 4; ct++) {
        float c0 = acc[ct][0]; c0 = c0 >= 0.0f ? c0 : SLOPE * c0; vals[ct][0] = c0; ssq0 += c0 * c0;
        float c1 = acc[ct][1]; c1 = c1 >= 0.0f ? c1 : SLOPE * c1; vals[ct][1] = c1; ssq1 += c1 * c1;
        float c2 = acc[ct][2]; c2 = c2 >= 0.0f ? c2 : SLOPE * c2; vals[ct][2] = c2; ssq2 += c2 * c2;
        float c3 = acc[ct][3]; c3 = c3 >= 0.0f ? c3 : SLOPE * c3; vals[ct][3] = c3; ssq3 += c3 * c3;
    }
    // reduce over the 16-lane m-group (q stays fixed for xor masks 1,2,4,8)
    #pragma unroll
    for (int off = 1; off < 16; off <<= 1) {
        ssq0 += __shfl_xor(ssq0, off);
        ssq1 += __shfl_xor(ssq1, off);
        ssq2 += __shfl_xor(ssq2, off);
        ssq3 += __shfl_xor(ssq3, off);
    }
    if (m == 0) {
        part[wv & 1][wr0 + q * 4 + 0] = ssq0;
        part[wv & 1][wr0 + q * 4 + 1] = ssq1;
        part[wv & 1][wr0 + q * 4 + 2] = ssq2;
        part[wv & 1][wr0 + q * 4 + 3] = ssq3;
    }
    __syncthreads();

    // ---- normalize in-register, write cur_n bf16 to cs
    #pragma unroll
    for (int rg = 0; rg < 4; rg++) {
        int rl = wr0 + q * 4 + rg;
        float inv = 1.0f / fmaxf(sqrtf(part[0][rl] + part[1][rl]), 1e-12f);
        #pragma unroll
        for (int ct = 0; ct < 4; ct++) {
            int col = (ct0 + ct) * 16 + m;
            cs[rl * ES + col] = f2bs(vals[ct][rg] * inv);
        }
    }
    __syncthreads();

    // hoisted bias fragments (L2-hot)
    float btr[4], bgr[4], btdr[4];
    #pragma unroll
    for (int ct = 0; ct < 4; ct++) {
        btr[ct]  = bt[(ct0 + ct) * 16 + m];
        bgr[ct]  = bg[(ct0 + ct) * 16 + m];
        btdr[ct] = btd[(ct0 + ct) * 16 + m];
    }

    // ---- E1: acc = cur_n @ Wt
    #pragma unroll
    for (int ct = 0; ct < 4; ct++) acc[ct] = (f32x4)0.0f;
    #pragma unroll
    for (int kc = 0; kc < 4; kc++) {
        int k0 = kc * 32 + q * 8;
        short8 a = *(const short8*)&cs[(wr0 + m) * ES + k0];
        #pragma unroll
        for (int ct = 0; ct < 4; ct++) {
            short8 b = *(const short8*)&BTe1[((ct0 + ct) * 16 + m) * 128 + k0];
            acc[ct] = __builtin_amdgcn_mfma_f32_16x16x32_bf16(a, b, acc[ct], 0, 0, 0);
        }
    }
    __syncthreads();   // all E1 A-reads complete before h1 overwrites cs

    #pragma unroll
    for (int ct = 0; ct < 4; ct++) {
        int col = (ct0 + ct) * 16 + m;
        #pragma unroll
        for (int rg = 0; rg < 4; rg++) {
            int rl = wr0 + q * 4 + rg;
            float tw = sigm(acc[ct][rg] + btr[ct]);
            float curn = bs2f(cs[rl * ES + col]);
            float hv = bs2f(hd[rl * ES + col]);
            cs[rl * ES + col] = f2bs(tw * curn + (1.0f - tw) * hv);   // h1
        }
    }
    __syncthreads();

    // ---- E2: acc = [h1|h] @ Wg^T
    #pragma unroll
    for (int ct = 0; ct < 4; ct++) acc[ct] = (f32x4)0.0f;
    #pragma unroll
    for (int kc = 0; kc < 8; kc++) {
        int k0 = kc * 32 + q * 8;
        short8 a = (kc < 4) ? *(const short8*)&cs[(wr0 + m) * ES + k0]
                            : *(const short8*)&hd[(wr0 + m) * ES + (k0 - 128)];
        #pragma unroll
        for (int ct = 0; ct < 4; ct++) {
            short8 b = *(const short8*)&BTe2[((ct0 + ct) * 16 + m) * 256 + k0];
            acc[ct] = __builtin_amdgcn_mfma_f32_16x16x32_bf16(a, b, acc[ct], 0, 0, 0);
        }
    }
    __syncthreads();   // all E2 reads of cs/hd done before h2/d overwrite

    #pragma unroll
    for (int ct = 0; ct < 4; ct++) {
        int col = (ct0 + ct) * 16 + m;
        #pragma unroll
        for (int rg = 0; rg < 4; rg++) {
            int rl = wr0 + q * 4 + rg;
            float g = sigm(acc[ct][rg] + bgr[ct]);
            float h1v = bs2f(cs[rl * ES + col]);
            float hv = bs2f(hd[rl * ES + col]);
            float h2 = g * h1v + (1.0f - g) * hv;
            cs[rl * ES + col] = f2bs(h2);              // h2
            hd[rl * ES + col] = f2bs(h2 - hv);         // d (h dead now)
        }
    }
    __syncthreads();

    // ---- E3: acc = d @ Wtd^T
    #pragma unroll
    for (int ct = 0; ct < 4; ct++) acc[ct] = (f32x4)0.0f;
    #pragma unroll
    for (int kc = 0; kc < 4; kc++) {
        int k0 = kc * 32 + q * 8;
        short8 a = *(const short8*)&hd[(wr0 + m) * ES + k0];
        #pragma unroll
        for (int ct = 0; ct < 4; ct++) {
            short8 b = *(const short8*)&BTe3[((ct0 + ct) * 16 + m) * 128 + k0];
            acc[ct] = __builtin_amdgcn_mfma_f32_16x16x32_bf16(a, b, acc[ct], 0, 0, 0);
        }
    }

    // ---- final: out = h2 + relu(d@Wtd + btd); cs reads are same-lane.
    #pragma unroll
    for (int ct = 0; ct < 4; ct++) {
        int col = (ct0 + ct) * 16 + m;
        #pragma unroll
        for (int rg = 0; rg < 4; rg++) {
            int rl = wr0 + q * 4 + rg;
            float td = fmaxf(acc[ct][rg] + btdr[ct], 0.0f);
            outp[(row0 + rl) * HDIM + col] = bs2f(cs[rl * ES + col]) + td;
        }
    }
}

// ---------------------------------------------------------------------------
extern "C" void kernel_launch(void* const* d_in, const int* in_sizes, int n_in,
                              void* d_out, int out_size, void* d_ws, size_t ws_size,
                              hipStream_t stream)
{
    const int* src = (const int*)d_in[0];
    const int* dst = (const int*)d_in[1];
    const int* ety = (const int*)d_in[2];
    const float* dyn     = (const float*)d_in[3];
    const float* emb_rel = (const float*)d_in[4];
    const float* Wn1     = (const float*)d_in[5];
    const float* Wl1     = (const float*)d_in[6];
    const float* Wn2     = (const float*)d_in[7];
    const float* Wl2     = (const float*)d_in[8];
    const float* gWx     = (const float*)d_in[9];
    const float* gWh     = (const float*)d_in[10];
    const float* gbx     = (const float*)d_in[11];
    const float* gbh     = (const float*)d_in[12];
    const float* gateW   = (const float*)d_in[13];
    const float* gateb   = (const float*)d_in[14];
    const float* tdW     = (const float*)d_in[15];
    const float* tdb     = (const float*)d_in[16];
    const float* tgW     = (const float*)d_in[17];
    const float* tgb     = (const float*)d_in[18];

    const long NH = (long)N_ENT * HDIM;          // 12,800,000
    float* ws = (float*)d_ws;
    long off = 0;
    float* A    = ws + off; off += NH;           // h state
    float* B    = ws + off; off += NH;           // layer1 out
    float* rel  = ws + off; off += (long)NR * HDIM;
    float* WxT  = ws + off; off += 98304;
    float* WhT  = ws + off; off += 49152;
    short* BT1  = (short*)(ws + off); off += 16384;   // 128x256 bf16
    short* BT2  = (short*)(ws + off); off += 16384;
    short* BTe1 = (short*)(ws + off); off += 8192;    // 128x128 bf16
    short* BTe2 = (short*)(ws + off); off += 16384;
    short* BTe3 = (short*)(ws + off); off += 8192;
    int* rowptr = (int*)(ws + off); off += NPAD;
    int* cnt    = (int*)(ws + off); off += NPAD;      // cnt, cnt2 contiguous
    int* cnt2   = (int*)(ws + off); off += NPAD;
    int* eidx   = (int*)(ws + off); off += 200704;
    int* bsum   = (int*)(ws + off); off += 128;
    short* aggb = (short*)(ws + off);            // chunk*128 bf16
    float* C    = (float*)d_out;                 // final-step output only

    const long avail = (long)(ws_size / 4) - off;
    // chunk candidates are multiples of 32 so every layer2_epi block is full
    const int cand[5] = {100000, 50016, 25024, 12512, 6272};
    int chunk = -1;
    for (int c = 0; c < 5; c++)
        if (avail >= (long)cand[c] * 64) { chunk = cand[c]; break; }

    if (chunk < 0) {
        diag_kernel<<<1, 64, 0, stream>>>((float*)d_out, (float)ws_size);
        return;
    }

    prep_kernel<<<256, 256, 0, stream>>>(
        emb_rel, gWx, gWh, Wn1, Wl1, Wn2, Wl2, tgW, gateW, tdW,
        rel, WxT, WhT, BT1, BT2, BTe1, BTe2, BTe3);

    norm_init_kernel<<<N_ENT, 64, 0, stream>>>(dyn, A);

    const int egrid = (NE + 255) / 256;          // 782 blocks

    for (int t = 0; t < NSTEP; t++) {
        const int* st = src + (long)t * NE;
        const int* dt = dst + (long)t * NE;
        const int* et = ety + (long)t * NE;

        // ---- CSR build for this step's graph (shared by both layers)
        zero_int_kernel<<<(2 * NPAD + 255) / 256, 256, 0, stream>>>(cnt, 2 * NPAD);
        hist_kernel<<<egrid, 256, 0, stream>>>(dt, cnt);
        scan1_kernel<<<SCAN_NB, 256, 0, stream>>>(cnt, rowptr, bsum);
        scan2_kernel<<<1, 128, 0, stream>>>(bsum, SCAN_NB);
        scan3_kernel<<<SCAN_NB, 256, 0, stream>>>(rowptr, bsum);
        fill_kernel<<<egrid, 256, 0, stream>>>(dt, rowptr, cnt2, eidx);

        gru_kernel<<<NR, 128, 0, stream>>>(rel, emb_rel, WxT, WhT, gbx, gbh);

        // layer 1: A -> B
        for (int lo = 0; lo < N_ENT; lo += chunk) {
            int hi = lo + chunk > N_ENT ? N_ENT : lo + chunk;
            gather_kernel<<<((hi - lo) * 64 + 255) / 256, 256, 0, stream>>>(
                st, et, eidx, rowptr, A, rel, aggb, lo, hi);
            layer_gemm<<<(hi - lo + 255) / 256, 256, 0, stream>>>(
                aggb, A, BT1, B, lo, hi);
        }
        // layer 2 + epilogue fused: B -> (A or d_out), in-place A update
        float* outp = (t == NSTEP - 1) ? C : A;
        for (int lo = 0; lo < N_ENT; lo += chunk) {
            int hi = lo + chunk > N_ENT ? N_ENT : lo + chunk;
            gather_kernel<<<((hi - lo) * 64 + 255) / 256, 256, 0, stream>>>(
                st, et, eidx, rowptr, B, rel, aggb, lo, hi);
            layer2_epi_kernel<<<(hi - lo) / 32, 256, 0, stream>>>(
                aggb, B, BT2, A, BTe1, BTe2, BTe3, tgb, gateb, tdb, outp, lo);
        }
    }
}

// Round 4
// 1201.573 us; speedup vs baseline: 1.2989x; 1.2989x over previous
//
#include <hip/hip_runtime.h>
#include <hip/hip_bf16.h>

#define N_ENT 100000
#define HDIM 128
#define NE 200000
#define NR 460
#define NSTEP 4
#define SLOPE 0.22916666666666666f
#define NPAD 100352            // N_ENT padded to 1024 multiple (98*1024)
#define SCAN_NB 98

typedef __attribute__((ext_vector_type(8))) short short8;
typedef __attribute__((ext_vector_type(4))) float f32x4;

__device__ __forceinline__ float sigm(float x) { return 1.0f / (1.0f + __expf(-x)); }
__device__ __forceinline__ short f2bs(float f) {
    __hip_bfloat16 b = __float2bfloat16(f);
    short s; __builtin_memcpy(&s, &b, 2); return s;
}
__device__ __forceinline__ float bs2f(short s) {
    union { unsigned int u; float f; } c;
    c.u = ((unsigned int)(unsigned short)s) << 16;
    return c.f;
}

// ---------------------------------------------------------------------------
__global__ void zero_int_kernel(int* __restrict__ p, int n)
{
    int i = blockIdx.x * 256 + threadIdx.x;
    if (i < n) p[i] = 0;
}

__global__ void diag_kernel(float* o, float v)
{
    if (threadIdx.x == 0) o[0] = v;
}

// ---------------------------------------------------------------------------
// CSR build: histogram -> 3-phase exclusive scan -> fill
// ---------------------------------------------------------------------------
__global__ void hist_kernel(const int* __restrict__ dst, int* __restrict__ cnt)
{
    int e = blockIdx.x * 256 + threadIdx.x;
    if (e < NE) atomicAdd(&cnt[dst[e]], 1);
}

__global__ __launch_bounds__(256)
void scan1_kernel(const int* __restrict__ cnt, int* __restrict__ rowptr,
                  int* __restrict__ bsum)
{
    __shared__ int ts[256];
    int b = blockIdx.x, t = threadIdx.x;
    int base = b * 1024 + t * 4;
    int4 v = *(const int4*)&cnt[base];
    int s = v.x + v.y + v.z + v.w;
    ts[t] = s;
    __syncthreads();
    for (int off = 1; off < 256; off <<= 1) {
        int x = 0;
        if (t >= off) x = ts[t - off];
        __syncthreads();
        if (t >= off) ts[t] += x;
        __syncthreads();
    }
    int excl = ts[t] - s;
    if (t == 255) bsum[b] = ts[t];
    rowptr[base + 0] = excl;
    rowptr[base + 1] = excl + v.x;
    rowptr[base + 2] = excl + v.x + v.y;
    rowptr[base + 3] = excl + v.x + v.y + v.z;
}

__global__ __launch_bounds__(128)
void scan2_kernel(int* __restrict__ bsum, int nb)
{
    __shared__ int ts[128];
    int t = threadIdx.x;
    int v = (t < nb) ? bsum[t] : 0;
    ts[t] = v;
    __syncthreads();
    for (int off = 1; off < 128; off <<= 1) {
        int x = 0;
        if (t >= off) x = ts[t - off];
        __syncthreads();
        if (t >= off) ts[t] += x;
        __syncthreads();
    }
    if (t < nb) bsum[t] = ts[t] - v;   // exclusive
}

__global__ __launch_bounds__(256)
void scan3_kernel(int* __restrict__ rowptr, const int* __restrict__ bsum)
{
    int b = blockIdx.x, t = threadIdx.x;
    int add = bsum[b];
    int base = b * 1024 + t * 4;
    rowptr[base + 0] += add;
    rowptr[base + 1] += add;
    rowptr[base + 2] += add;
    rowptr[base + 3] += add;
}

__global__ void fill_kernel(const int* __restrict__ dst,
                            const int* __restrict__ rowptr,
                            int* __restrict__ c2, int* __restrict__ eidx)
{
    int e = blockIdx.x * 256 + threadIdx.x;
    if (e < NE) {
        int d = dst[e];
        int p = atomicAdd(&c2[d], 1);
        eidx[rowptr[d] + p] = e;
    }
}

// ---------------------------------------------------------------------------
// Prep: GRU weight transposes (f32) + bf16 B^T buffers for the MFMA GEMMs.
// ---------------------------------------------------------------------------
__global__ void prep_kernel(
    const float* __restrict__ emb_rel,
    const float* __restrict__ Wx, const float* __restrict__ Wh,
    const float* __restrict__ Wn1, const float* __restrict__ Wl1,
    const float* __restrict__ Wn2, const float* __restrict__ Wl2,
    const float* __restrict__ tgW, const float* __restrict__ gateW,
    const float* __restrict__ tdW,
    float* __restrict__ rel,
    float* __restrict__ WxT, float* __restrict__ WhT,
    short* __restrict__ BT1, short* __restrict__ BT2,
    short* __restrict__ BTe1, short* __restrict__ BTe2,
    short* __restrict__ BTe3)
{
    int tid = blockIdx.x * blockDim.x + threadIdx.x;
    int nthr = gridDim.x * blockDim.x;
    for (int i = tid; i < NR * HDIM; i += nthr)
        rel[i] = emb_rel[i];
    for (int i = tid; i < 384 * 256; i += nthr) {
        int r = i >> 8, c = i & 255;
        WxT[c * 384 + r] = Wx[i];
    }
    for (int i = tid; i < 384 * 128; i += nthr) {
        int r = i >> 7, c = i & 127;
        WhT[c * 384 + r] = Wh[i];
    }
    for (int i = tid; i < 128 * 256; i += nthr) {   // layer BTs: [x|h]@[Wn;Wl]
        int n = i >> 8, k = i & 255;
        float v1 = (k < 128) ? Wn1[k * 128 + n] : Wl1[(k - 128) * 128 + n];
        float v2 = (k < 128) ? Wn2[k * 128 + n] : Wl2[(k - 128) * 128 + n];
        BT1[n * 256 + k] = f2bs(v1);
        BT2[n * 256 + k] = f2bs(v2);
    }
    for (int i = tid; i < 128 * 128; i += nthr) {   // E1 (transpose), E3 (direct)
        int n = i >> 7, k = i & 127;
        BTe1[n * 128 + k] = f2bs(tgW[k * 128 + n]);
        BTe3[n * 128 + k] = f2bs(tdW[n * 128 + k]);
    }
    for (int i = tid; i < 128 * 256; i += nthr) {   // E2 (direct)
        int n = i >> 8, k = i & 255;
        BTe2[n * 256 + k] = f2bs(gateW[n * 256 + k]);
    }
}

// ---------------------------------------------------------------------------
// h0 = l2norm(dynamic_emb) stored bf16; one wave per row.
// (All downstream consumers of the state round to bf16 anyway.)
// ---------------------------------------------------------------------------
__global__ __launch_bounds__(64)
void norm_init_kernel(const float* __restrict__ emb, short* __restrict__ hb)
{
    int row = blockIdx.x, lane = threadIdx.x;
    float v0 = emb[row * HDIM + lane];
    float v1 = emb[row * HDIM + 64 + lane];
    float s = v0 * v0 + v1 * v1;
    #pragma unroll
    for (int off = 32; off; off >>= 1) s += __shfl_xor(s, off);
    float invn = 1.0f / fmaxf(sqrtf(s), 1e-12f);
    hb[row * HDIM + lane] = f2bs(v0 * invn);
    hb[row * HDIM + 64 + lane] = f2bs(v1 * invn);
}

// ---------------------------------------------------------------------------
// GRUCell relation evolution (f32 GEMV — tiny: 460 rows). Also writes a bf16
// shadow of the relation embeddings for the gather kernel.
// ---------------------------------------------------------------------------
__global__ __launch_bounds__(128)
void gru_kernel(float* rel, short* __restrict__ relb,
                const float* __restrict__ emb_rel,
                const float* __restrict__ WxT, const float* __restrict__ WhT,
                const float* __restrict__ bx, const float* __restrict__ bh)
{
    __shared__ __align__(16) float x[256];
    __shared__ __align__(16) float hh[128];
    int b = blockIdx.x, j = threadIdx.x;
    float hj = rel[b * HDIM + j];
    x[j] = emb_rel[b * HDIM + j];
    x[128 + j] = hj;
    hh[j] = hj;
    __syncthreads();
    float xr = 0, xz = 0, xn = 0, hr = 0, hz = 0, hn = 0;
    for (int k = 0; k < 256; k++) {
        float xv = x[k];
        const float* w = &WxT[k * 384];
        xr += xv * w[j]; xz += xv * w[128 + j]; xn += xv * w[256 + j];
    }
    for (int k = 0; k < 128; k++) {
        float hv = hh[k];
        const float* w = &WhT[k * 384];
        hr += hv * w[j]; hz += hv * w[128 + j]; hn += hv * w[256 + j];
    }
    float r = sigm(xr + bx[j] + hr + bh[j]);
    float z = sigm(xz + bx[128 + j] + hz + bh[128 + j]);
    float n = tanhf(xn + bx[256 + j] + r * (hn + bh[256 + j]));
    float nv = (1.0f - z) * n + z * hj;
    rel[b * HDIM + j] = nv;
    relb[b * HDIM + j] = f2bs(nv);
}

// ---------------------------------------------------------------------------
// CSR gather (bf16 state): aggb[r-lo] = bf16((sum_e hb[src]+relb[et])/deg).
// 16 lanes per row (short8 = 8 cols/lane) -> 4 independent row chains per
// wave = 4x memory-level parallelism on the eidx->src->row load chain.
// ---------------------------------------------------------------------------
__global__ __launch_bounds__(256)
void gather_kernel(const int* __restrict__ src, const int* __restrict__ et,
                   const int* __restrict__ eidx, const int* __restrict__ rowptr,
                   const short* __restrict__ hb, const short* __restrict__ relb,
                   short* __restrict__ aggb, int lo, int hi)
{
    int idx = blockIdx.x * 256 + threadIdx.x;
    int r = lo + (idx >> 4);
    int i8 = (idx & 15) * 8;
    if (r >= hi) return;
    int p0 = rowptr[r], p1 = rowptr[r + 1];
    float v[8] = {0, 0, 0, 0, 0, 0, 0, 0};
    for (int p = p0; p < p1; p++) {
        int e = eidx[p];
        int s = src[e], rt = et[e];
        short8 hv = *(const short8*)&hb[(long)s * HDIM + i8];
        short8 rv = *(const short8*)&relb[rt * HDIM + i8];
        #pragma unroll
        for (int j = 0; j < 8; j++) v[j] += bs2f(hv[j]) + bs2f(rv[j]);
    }
    float rdeg = (p1 > p0) ? 1.0f / (float)(p1 - p0) : 0.0f;
    short8 o;
    #pragma unroll
    for (int j = 0; j < 8; j++) o[j] = f2bs(v[j] * rdeg);
    *(short8*)&aggb[(long)(r - lo) * HDIM + i8] = o;
}

// ---------------------------------------------------------------------------
// Layer MFMA GEMM: out = rrelu([aggb | hb] @ BT^T).  All A-operands are
// bf16 short8 loads (no conversion).  F32OUT=1 -> f32 out (layer 2 -> C);
// F32OUT=0 -> bf16 out (layer 1 -> Bb).
// ---------------------------------------------------------------------------
template<int F32OUT>
__global__ __launch_bounds__(256, 2)
void layer_gemm(const short* __restrict__ aggb, const short* __restrict__ hb,
                const short* __restrict__ BTg, float* __restrict__ outf,
                short* __restrict__ outb, int lo, int hi)
{
    const int tid = threadIdx.x;
    const int lane = tid & 63;
    const int wv = tid >> 6;
    const int m = lane & 15, q = lane >> 4;
    const int rowBase = lo + blockIdx.x * 256 + wv * 64;

    f32x4 acc[4][8];
    #pragma unroll
    for (int rt = 0; rt < 4; rt++)
        #pragma unroll
        for (int ct = 0; ct < 8; ct++)
            acc[rt][ct] = (f32x4)0.0f;

    for (int kc = 0; kc < 8; kc++) {
        short8 a[4];
        #pragma unroll
        for (int rt = 0; rt < 4; rt++) {
            int row = rowBase + rt * 16 + m;
            int k0 = kc * 32 + q * 8;
            if (row < hi) {
                if (kc < 4) {
                    a[rt] = *(const short8*)&aggb[(long)(row - lo) * HDIM + k0];
                } else {
                    a[rt] = *(const short8*)&hb[(long)row * HDIM + (k0 - 128)];
                }
            } else {
                short8 t;
                #pragma unroll
                for (int i = 0; i < 8; i++) t[i] = 0;
                a[rt] = t;
            }
        }
        short8 b[8];
        #pragma unroll
        for (int ct = 0; ct < 8; ct++)
            b[ct] = *(const short8*)&BTg[(ct * 16 + m) * 256 + kc * 32 + q * 8];
        #pragma unroll
        for (int rt = 0; rt < 4; rt++)
            #pragma unroll
            for (int ct = 0; ct < 8; ct++)
                acc[rt][ct] = __builtin_amdgcn_mfma_f32_16x16x32_bf16(
                    a[rt], b[ct], acc[rt][ct], 0, 0, 0);
    }

    #pragma unroll
    for (int rt = 0; rt < 4; rt++) {
        #pragma unroll
        for (int rg = 0; rg < 4; rg++) {
            int row = rowBase + rt * 16 + q * 4 + rg;
            if (row >= hi) continue;
            #pragma unroll
            for (int ct = 0; ct < 8; ct++) {
                int col = ct * 16 + m;
                float c = acc[rt][ct][rg];
                c = c >= 0.0f ? c : SLOPE * c;
                if (F32OUT) outf[(long)row * HDIM + col] = c;
                else        outb[(long)row * HDIM + col] = f2bs(c);
            }
        }
    }
}

// ---------------------------------------------------------------------------
// Fused epilogue v7 — v5 structure with bf16 state:
//   hprev read as bf16 (direct short8 stage, no cvts); output stored bf16
//   (next-step state) on t<3 or f32 (d_out) on the last step.
//   LDS 17.4 KB -> 8 blocks/CU.  5 barriers.
// ---------------------------------------------------------------------------
#define ER 32                  // rows per block
#define ES 136                 // bf16 row stride (shorts)
__global__ __launch_bounds__(256, 8)
void fused_epi_kernel(const float* __restrict__ cur, const short* __restrict__ hb,
                      const short* __restrict__ BTe1, const short* __restrict__ BTe2,
                      const short* __restrict__ BTe3,
                      const float* __restrict__ bt, const float* __restrict__ bg,
                      const float* __restrict__ btd,
                      float* __restrict__ outp, short* __restrict__ abfo, int wf)
{
    __shared__ __align__(16) short cs[ER * ES];   // cur_n -> h1 -> h2
    __shared__ __align__(16) short hd[ER * ES];   // h -> d
    const int tid = threadIdx.x;
    const long row0 = (long)blockIdx.x * ER;

    // stage cur (f32, fused l2-norm) and hb (bf16 passthrough)
    #pragma unroll
    for (int it = 0; it < 2; it++) {
        int s = it * 256 + tid;
        int r = s >> 4, c8 = (s & 15) * 8;
        const float* pc = &cur[(row0 + r) * HDIM + c8];
        float4 c0 = *(const float4*)pc, c1 = *(const float4*)(pc + 4);
        short8 th = *(const short8*)&hb[(row0 + r) * HDIM + c8];
        float ss = c0.x*c0.x + c0.y*c0.y + c0.z*c0.z + c0.w*c0.w
                 + c1.x*c1.x + c1.y*c1.y + c1.z*c1.z + c1.w*c1.w;
        ss += __shfl_xor(ss, 1);
        ss += __shfl_xor(ss, 2);
        ss += __shfl_xor(ss, 4);
        ss += __shfl_xor(ss, 8);
        float inv = 1.0f / fmaxf(sqrtf(ss), 1e-12f);
        short8 tc;
        tc[0]=f2bs(c0.x*inv); tc[1]=f2bs(c0.y*inv);
        tc[2]=f2bs(c0.z*inv); tc[3]=f2bs(c0.w*inv);
        tc[4]=f2bs(c1.x*inv); tc[5]=f2bs(c1.y*inv);
        tc[6]=f2bs(c1.z*inv); tc[7]=f2bs(c1.w*inv);
        *(short8*)&cs[r * ES + c8] = tc;
        *(short8*)&hd[r * ES + c8] = th;
    }
    __syncthreads();

    const int wv = tid >> 6, lane = tid & 63;
    const int m = lane & 15, q = lane >> 4;
    const int wr0 = (wv >> 1) * 16;                // wave's row base (0 or 16)
    const int ct0 = (wv & 1) * 4;                  // wave's col-tile base

    // hoisted bias fragments (L2-hot)
    float btr[4], bgr[4], btdr[4];
    #pragma unroll
    for (int ct = 0; ct < 4; ct++) {
        btr[ct]  = bt[(ct0 + ct) * 16 + m];
        bgr[ct]  = bg[(ct0 + ct) * 16 + m];
        btdr[ct] = btd[(ct0 + ct) * 16 + m];
    }

    f32x4 acc[4];

    // ---- E1: acc = cur_n @ Wt
    #pragma unroll
    for (int ct = 0; ct < 4; ct++) acc[ct] = (f32x4)0.0f;
    #pragma unroll
    for (int kc = 0; kc < 4; kc++) {
        int k0 = kc * 32 + q * 8;
        short8 a = *(const short8*)&cs[(wr0 + m) * ES + k0];
        #pragma unroll
        for (int ct = 0; ct < 4; ct++) {
            short8 b = *(const short8*)&BTe1[((ct0 + ct) * 16 + m) * 128 + k0];
            acc[ct] = __builtin_amdgcn_mfma_f32_16x16x32_bf16(a, b, acc[ct], 0, 0, 0);
        }
    }
    __syncthreads();   // all E1 A-reads complete before h1 overwrites cs

    #pragma unroll
    for (int ct = 0; ct < 4; ct++) {
        int col = (ct0 + ct) * 16 + m;
        #pragma unroll
        for (int rg = 0; rg < 4; rg++) {
            int rl = wr0 + q * 4 + rg;
            float tw = sigm(acc[ct][rg] + btr[ct]);
            float curn = bs2f(cs[rl * ES + col]);
            float hv = bs2f(hd[rl * ES + col]);
            cs[rl * ES + col] = f2bs(tw * curn + (1.0f - tw) * hv);   // h1
        }
    }
    __syncthreads();

    // ---- E2: acc = [h1|h] @ Wg^T
    #pragma unroll
    for (int ct = 0; ct < 4; ct++) acc[ct] = (f32x4)0.0f;
    #pragma unroll
    for (int kc = 0; kc < 8; kc++) {
        int k0 = kc * 32 + q * 8;
        short8 a = (kc < 4) ? *(const short8*)&cs[(wr0 + m) * ES + k0]
                            : *(const short8*)&hd[(wr0 + m) * ES + (k0 - 128)];
        #pragma unroll
        for (int ct = 0; ct < 4; ct++) {
            short8 b = *(const short8*)&BTe2[((ct0 + ct) * 16 + m) * 256 + k0];
            acc[ct] = __builtin_amdgcn_mfma_f32_16x16x32_bf16(a, b, acc[ct], 0, 0, 0);
        }
    }
    __syncthreads();   // all E2 reads of cs/hd done before h2/d overwrite

    #pragma unroll
    for (int ct = 0; ct < 4; ct++) {
        int col = (ct0 + ct) * 16 + m;
        #pragma unroll
        for (int rg = 0; rg < 4; rg++) {
            int rl = wr0 + q * 4 + rg;
            float g = sigm(acc[ct][rg] + bgr[ct]);
            float h1v = bs2f(cs[rl * ES + col]);
            float hv = bs2f(hd[rl * ES + col]);
            float h2 = g * h1v + (1.0f - g) * hv;
            cs[rl * ES + col] = f2bs(h2);              // h2
            hd[rl * ES + col] = f2bs(h2 - hv);         // d (h dead now)
        }
    }
    __syncthreads();

    // ---- E3: acc = d @ Wtd^T
    #pragma unroll
    for (int ct = 0; ct < 4; ct++) acc[ct] = (f32x4)0.0f;
    #pragma unroll
    for (int kc = 0; kc < 4; kc++) {
        int k0 = kc * 32 + q * 8;
        short8 a = *(const short8*)&hd[(wr0 + m) * ES + k0];
        #pragma unroll
        for (int ct = 0; ct < 4; ct++) {
            short8 b = *(const short8*)&BTe3[((ct0 + ct) * 16 + m) * 128 + k0];
            acc[ct] = __builtin_amdgcn_mfma_f32_16x16x32_bf16(a, b, acc[ct], 0, 0, 0);
        }
    }

    // ---- final: out = h2 + relu(d@Wtd + btd); cs reads are same-lane.
    #pragma unroll
    for (int ct = 0; ct < 4; ct++) {
        int col = (ct0 + ct) * 16 + m;
        #pragma unroll
        for (int rg = 0; rg < 4; rg++) {
            int rl = wr0 + q * 4 + rg;
            float td = fmaxf(acc[ct][rg] + btdr[ct], 0.0f);
            float val = bs2f(cs[rl * ES + col]) + td;
            if (wf) outp[(row0 + rl) * HDIM + col] = val;
            else    abfo[(row0 + rl) * HDIM + col] = f2bs(val);
        }
    }
}

// ---------------------------------------------------------------------------
extern "C" void kernel_launch(void* const* d_in, const int* in_sizes, int n_in,
                              void* d_out, int out_size, void* d_ws, size_t ws_size,
                              hipStream_t stream)
{
    const int* src = (const int*)d_in[0];
    const int* dst = (const int*)d_in[1];
    const int* ety = (const int*)d_in[2];
    const float* dyn     = (const float*)d_in[3];
    const float* emb_rel = (const float*)d_in[4];
    const float* Wn1     = (const float*)d_in[5];
    const float* Wl1     = (const float*)d_in[6];
    const float* Wn2     = (const float*)d_in[7];
    const float* Wl2     = (const float*)d_in[8];
    const float* gWx     = (const float*)d_in[9];
    const float* gWh     = (const float*)d_in[10];
    const float* gbx     = (const float*)d_in[11];
    const float* gbh     = (const float*)d_in[12];
    const float* gateW   = (const float*)d_in[13];
    const float* gateb   = (const float*)d_in[14];
    const float* tdW     = (const float*)d_in[15];
    const float* tdb     = (const float*)d_in[16];
    const float* tgW     = (const float*)d_in[17];
    const float* tgb     = (const float*)d_in[18];

    const long NH = (long)N_ENT * HDIM;          // 12,800,000
    float* ws = (float*)d_ws;
    long off = 0;
    short* Abf  = (short*)(ws + off); off += NH / 2;   // bf16 h-state
    short* Bb   = (short*)(ws + off); off += NH / 2;   // bf16 layer1 out
    float* rel  = ws + off; off += (long)NR * HDIM;
    short* relb = (short*)(ws + off); off += (NR * HDIM) / 2;
    float* WxT  = ws + off; off += 98304;
    float* WhT  = ws + off; off += 49152;
    short* BT1  = (short*)(ws + off); off += 16384;   // 128x256 bf16
    short* BT2  = (short*)(ws + off); off += 16384;
    short* BTe1 = (short*)(ws + off); off += 8192;    // 128x128 bf16
    short* BTe2 = (short*)(ws + off); off += 16384;
    short* BTe3 = (short*)(ws + off); off += 8192;
    int* rowptr = (int*)(ws + off); off += NPAD;
    int* cnt    = (int*)(ws + off); off += NPAD;      // cnt, cnt2 contiguous
    int* cnt2   = (int*)(ws + off); off += NPAD;
    int* eidx   = (int*)(ws + off); off += 200704;
    int* bsum   = (int*)(ws + off); off += 128;
    short* aggb = (short*)(ws + off);            // chunk*128 bf16
    float* C    = (float*)d_out;                 // layer2 out (= cur)

    const long avail = (long)(ws_size / 4) - off;
    const int cand[5] = {100000, 50000, 25008, 12512, 6256};
    int chunk = -1;
    for (int c = 0; c < 5; c++)
        if (avail >= (long)cand[c] * 64) { chunk = cand[c]; break; }

    if (chunk < 0) {
        diag_kernel<<<1, 64, 0, stream>>>((float*)d_out, (float)ws_size);
        return;
    }

    prep_kernel<<<256, 256, 0, stream>>>(
        emb_rel, gWx, gWh, Wn1, Wl1, Wn2, Wl2, tgW, gateW, tdW,
        rel, WxT, WhT, BT1, BT2, BTe1, BTe2, BTe3);

    norm_init_kernel<<<N_ENT, 64, 0, stream>>>(dyn, Abf);

    const int egrid = (NE + 255) / 256;          // 782 blocks
    const int fe_grid = N_ENT / 32;              // 3125 blocks

    for (int t = 0; t < NSTEP; t++) {
        const int* st = src + (long)t * NE;
        const int* dt = dst + (long)t * NE;
        const int* et = ety + (long)t * NE;

        // ---- CSR build for this step's graph (shared by both layers)
        zero_int_kernel<<<(2 * NPAD + 255) / 256, 256, 0, stream>>>(cnt, 2 * NPAD);
        hist_kernel<<<egrid, 256, 0, stream>>>(dt, cnt);
        scan1_kernel<<<SCAN_NB, 256, 0, stream>>>(cnt, rowptr, bsum);
        scan2_kernel<<<1, 128, 0, stream>>>(bsum, SCAN_NB);
        scan3_kernel<<<SCAN_NB, 256, 0, stream>>>(rowptr, bsum);
        fill_kernel<<<egrid, 256, 0, stream>>>(dt, rowptr, cnt2, eidx);

        gru_kernel<<<NR, 128, 0, stream>>>(rel, relb, emb_rel, WxT, WhT, gbx, gbh);

        // layer 1: Abf -> Bb (bf16)
        for (int lo = 0; lo < N_ENT; lo += chunk) {
            int hi = lo + chunk > N_ENT ? N_ENT : lo + chunk;
            gather_kernel<<<((hi - lo) * 16 + 255) / 256, 256, 0, stream>>>(
                st, et, eidx, rowptr, Abf, relb, aggb, lo, hi);
            layer_gemm<0><<<(hi - lo + 255) / 256, 256, 0, stream>>>(
                aggb, Abf, BT1, nullptr, Bb, lo, hi);
        }
        // layer 2: Bb -> C (f32)
        for (int lo = 0; lo < N_ENT; lo += chunk) {
            int hi = lo + chunk > N_ENT ? N_ENT : lo + chunk;
            gather_kernel<<<((hi - lo) * 16 + 255) / 256, 256, 0, stream>>>(
                st, et, eidx, rowptr, Bb, relb, aggb, lo, hi);
            layer_gemm<1><<<(hi - lo + 255) / 256, 256, 0, stream>>>(
                aggb, Bb, BT2, C, nullptr, lo, hi);
        }

        // fused epilogue: (C, Abf) -> Abf (t<3, bf16) or d_out == C (t=3, f32)
        int wf = (t == NSTEP - 1) ? 1 : 0;
        fused_epi_kernel<<<fe_grid, 256, 0, stream>>>(
            C, Abf, BTe1, BTe2, BTe3, tgb, gateb, tdb, C, Abf, wf);
    }
}

// Round 5
// 1096.954 us; speedup vs baseline: 1.4228x; 1.0954x over previous
//
#include <hip/hip_runtime.h>
#include <hip/hip_bf16.h>

#define N_ENT 100000
#define HDIM 128
#define NE 200000
#define NR 460
#define NSTEP 4
#define SLOPE 0.22916666666666666f
#define NPAD 100352            // N_ENT padded to 1024 multiple (98*1024)
#define SCAN_NB 98

typedef __attribute__((ext_vector_type(8))) short short8;
typedef __attribute__((ext_vector_type(4))) float f32x4;

__device__ __forceinline__ float sigm(float x) { return 1.0f / (1.0f + __expf(-x)); }
__device__ __forceinline__ short f2bs(float f) {
    __hip_bfloat16 b = __float2bfloat16(f);
    short s; __builtin_memcpy(&s, &b, 2); return s;
}
__device__ __forceinline__ float bs2f(short s) {
    union { unsigned int u; float f; } c;
    c.u = ((unsigned int)(unsigned short)s) << 16;
    return c.f;
}

// ---------------------------------------------------------------------------
__global__ void zero_int_kernel(int* __restrict__ p, int n)
{
    int i = blockIdx.x * 256 + threadIdx.x;
    if (i < n) p[i] = 0;
}

__global__ void diag_kernel(float* o, float v)
{
    if (threadIdx.x == 0) o[0] = v;
}

// ---------------------------------------------------------------------------
// CSR build: histogram -> 3-phase exclusive scan -> fill
// ---------------------------------------------------------------------------
__global__ void hist_kernel(const int* __restrict__ dst, int* __restrict__ cnt)
{
    int e = blockIdx.x * 256 + threadIdx.x;
    if (e < NE) atomicAdd(&cnt[dst[e]], 1);
}

__global__ __launch_bounds__(256)
void scan1_kernel(const int* __restrict__ cnt, int* __restrict__ rowptr,
                  int* __restrict__ bsum)
{
    __shared__ int ts[256];
    int b = blockIdx.x, t = threadIdx.x;
    int base = b * 1024 + t * 4;
    int4 v = *(const int4*)&cnt[base];
    int s = v.x + v.y + v.z + v.w;
    ts[t] = s;
    __syncthreads();
    for (int off = 1; off < 256; off <<= 1) {
        int x = 0;
        if (t >= off) x = ts[t - off];
        __syncthreads();
        if (t >= off) ts[t] += x;
        __syncthreads();
    }
    int excl = ts[t] - s;
    if (t == 255) bsum[b] = ts[t];
    rowptr[base + 0] = excl;
    rowptr[base + 1] = excl + v.x;
    rowptr[base + 2] = excl + v.x + v.y;
    rowptr[base + 3] = excl + v.x + v.y + v.z;
}

__global__ __launch_bounds__(128)
void scan2_kernel(int* __restrict__ bsum, int nb)
{
    __shared__ int ts[128];
    int t = threadIdx.x;
    int v = (t < nb) ? bsum[t] : 0;
    ts[t] = v;
    __syncthreads();
    for (int off = 1; off < 128; off <<= 1) {
        int x = 0;
        if (t >= off) x = ts[t - off];
        __syncthreads();
        if (t >= off) ts[t] += x;
        __syncthreads();
    }
    if (t < nb) bsum[t] = ts[t] - v;   // exclusive
}

__global__ __launch_bounds__(256)
void scan3_kernel(int* __restrict__ rowptr, const int* __restrict__ bsum)
{
    int b = blockIdx.x, t = threadIdx.x;
    int add = bsum[b];
    int base = b * 1024 + t * 4;
    rowptr[base + 0] += add;
    rowptr[base + 1] += add;
    rowptr[base + 2] += add;
    rowptr[base + 3] += add;
}

__global__ void fill_kernel(const int* __restrict__ dst,
                            const int* __restrict__ rowptr,
                            int* __restrict__ c2, int* __restrict__ eidx)
{
    int e = blockIdx.x * 256 + threadIdx.x;
    if (e < NE) {
        int d = dst[e];
        int p = atomicAdd(&c2[d], 1);
        eidx[rowptr[d] + p] = e;
    }
}

// ---------------------------------------------------------------------------
// Prep: GRU weight transposes (f32) + bf16 B^T buffers for the MFMA GEMMs.
// ---------------------------------------------------------------------------
__global__ void prep_kernel(
    const float* __restrict__ emb_rel,
    const float* __restrict__ Wx, const float* __restrict__ Wh,
    const float* __restrict__ Wn1, const float* __restrict__ Wl1,
    const float* __restrict__ Wn2, const float* __restrict__ Wl2,
    const float* __restrict__ tgW, const float* __restrict__ gateW,
    const float* __restrict__ tdW,
    float* __restrict__ rel,
    float* __restrict__ WxT, float* __restrict__ WhT,
    short* __restrict__ BT1, short* __restrict__ BT2,
    short* __restrict__ BTe1, short* __restrict__ BTe2,
    short* __restrict__ BTe3)
{
    int tid = blockIdx.x * blockDim.x + threadIdx.x;
    int nthr = gridDim.x * blockDim.x;
    for (int i = tid; i < NR * HDIM; i += nthr)
        rel[i] = emb_rel[i];
    for (int i = tid; i < 384 * 256; i += nthr) {
        int r = i >> 8, c = i & 255;
        WxT[c * 384 + r] = Wx[i];
    }
    for (int i = tid; i < 384 * 128; i += nthr) {
        int r = i >> 7, c = i & 127;
        WhT[c * 384 + r] = Wh[i];
    }
    for (int i = tid; i < 128 * 256; i += nthr) {   // layer BTs: [x|h]@[Wn;Wl]
        int n = i >> 8, k = i & 255;
        float v1 = (k < 128) ? Wn1[k * 128 + n] : Wl1[(k - 128) * 128 + n];
        float v2 = (k < 128) ? Wn2[k * 128 + n] : Wl2[(k - 128) * 128 + n];
        BT1[n * 256 + k] = f2bs(v1);
        BT2[n * 256 + k] = f2bs(v2);
    }
    for (int i = tid; i < 128 * 128; i += nthr) {   // E1 (transpose), E3 (direct)
        int n = i >> 7, k = i & 127;
        BTe1[n * 128 + k] = f2bs(tgW[k * 128 + n]);
        BTe3[n * 128 + k] = f2bs(tdW[n * 128 + k]);
    }
    for (int i = tid; i < 128 * 256; i += nthr) {   // E2 (direct)
        int n = i >> 8, k = i & 255;
        BTe2[n * 256 + k] = f2bs(gateW[n * 256 + k]);
    }
}

// ---------------------------------------------------------------------------
// h0 = l2norm(dynamic_emb) stored bf16; one wave per row.
// ---------------------------------------------------------------------------
__global__ __launch_bounds__(64)
void norm_init_kernel(const float* __restrict__ emb, short* __restrict__ hb)
{
    int row = blockIdx.x, lane = threadIdx.x;
    float v0 = emb[row * HDIM + lane];
    float v1 = emb[row * HDIM + 64 + lane];
    float s = v0 * v0 + v1 * v1;
    #pragma unroll
    for (int off = 32; off; off >>= 1) s += __shfl_xor(s, off);
    float invn = 1.0f / fmaxf(sqrtf(s), 1e-12f);
    hb[row * HDIM + lane] = f2bs(v0 * invn);
    hb[row * HDIM + 64 + lane] = f2bs(v1 * invn);
}

// ---------------------------------------------------------------------------
// GRUCell relation evolution (f32 GEMV — tiny: 460 rows). Also writes a bf16
// shadow of the relation embeddings for the gather kernel.
// ---------------------------------------------------------------------------
__global__ __launch_bounds__(128)
void gru_kernel(float* rel, short* __restrict__ relb,
                const float* __restrict__ emb_rel,
                const float* __restrict__ WxT, const float* __restrict__ WhT,
                const float* __restrict__ bx, const float* __restrict__ bh)
{
    __shared__ __align__(16) float x[256];
    __shared__ __align__(16) float hh[128];
    int b = blockIdx.x, j = threadIdx.x;
    float hj = rel[b * HDIM + j];
    x[j] = emb_rel[b * HDIM + j];
    x[128 + j] = hj;
    hh[j] = hj;
    __syncthreads();
    float xr = 0, xz = 0, xn = 0, hr = 0, hz = 0, hn = 0;
    for (int k = 0; k < 256; k++) {
        float xv = x[k];
        const float* w = &WxT[k * 384];
        xr += xv * w[j]; xz += xv * w[128 + j]; xn += xv * w[256 + j];
    }
    for (int k = 0; k < 128; k++) {
        float hv = hh[k];
        const float* w = &WhT[k * 384];
        hr += hv * w[j]; hz += hv * w[128 + j]; hn += hv * w[256 + j];
    }
    float r = sigm(xr + bx[j] + hr + bh[j]);
    float z = sigm(xz + bx[128 + j] + hz + bh[128 + j]);
    float n = tanhf(xn + bx[256 + j] + r * (hn + bh[256 + j]));
    float nv = (1.0f - z) * n + z * hj;
    rel[b * HDIM + j] = nv;
    relb[b * HDIM + j] = f2bs(nv);
}

// ---------------------------------------------------------------------------
// CSR gather (bf16 state): aggb[r-lo] = bf16((sum_e hb[src]+relb[et])/deg).
// 16 lanes per row (short8 = 8 cols/lane) -> 4 independent row chains/wave.
// ---------------------------------------------------------------------------
__global__ __launch_bounds__(256)
void gather_kernel(const int* __restrict__ src, const int* __restrict__ et,
                   const int* __restrict__ eidx, const int* __restrict__ rowptr,
                   const short* __restrict__ hb, const short* __restrict__ relb,
                   short* __restrict__ aggb, int lo, int hi)
{
    int idx = blockIdx.x * 256 + threadIdx.x;
    int r = lo + (idx >> 4);
    int i8 = (idx & 15) * 8;
    if (r >= hi) return;
    int p0 = rowptr[r], p1 = rowptr[r + 1];
    float v[8] = {0, 0, 0, 0, 0, 0, 0, 0};
    for (int p = p0; p < p1; p++) {
        int e = eidx[p];
        int s = src[e], rt = et[e];
        short8 hv = *(const short8*)&hb[(long)s * HDIM + i8];
        short8 rv = *(const short8*)&relb[rt * HDIM + i8];
        #pragma unroll
        for (int j = 0; j < 8; j++) v[j] += bs2f(hv[j]) + bs2f(rv[j]);
    }
    float rdeg = (p1 > p0) ? 1.0f / (float)(p1 - p0) : 0.0f;
    short8 o;
    #pragma unroll
    for (int j = 0; j < 8; j++) o[j] = f2bs(v[j] * rdeg);
    *(short8*)&aggb[(long)(r - lo) * HDIM + i8] = o;
}

// ---------------------------------------------------------------------------
// Layer MFMA GEMM: out = rrelu([aggb | hb] @ BT^T).
// BT (128x256 bf16 = 64 KB) is staged into LDS once per block with an
// XOR-swizzle (slot ^= row&7 in 8-short units) so the stride-512B column
// reads are bank-balanced (without it all 16 m-lanes hit one bank group).
// F32OUT=1 -> f32 out (last-step layer2 -> d_out); F32OUT=0 -> bf16 out.
// ---------------------------------------------------------------------------
template<int F32OUT>
__global__ __launch_bounds__(256, 2)
void layer_gemm(const short* __restrict__ aggb, const short* __restrict__ hb,
                const short* __restrict__ BTg, float* __restrict__ outf,
                short* __restrict__ outb, int lo, int hi)
{
    __shared__ __align__(16) short smBT[128 * 256];   // 64 KB
    const int tid = threadIdx.x;

    // stage BT with swizzle: 4096 slots of 8 shorts, 16 per thread
    #pragma unroll
    for (int it = 0; it < 16; it++) {
        int s = it * 256 + tid;
        int row = s >> 5, k8 = s & 31;
        short8 v = *(const short8*)&BTg[row * 256 + k8 * 8];
        *(short8*)&smBT[row * 256 + 8 * (k8 ^ (row & 7))] = v;
    }
    __syncthreads();

    const int lane = tid & 63;
    const int wv = tid >> 6;
    const int m = lane & 15, q = lane >> 4;
    const int rowBase = lo + blockIdx.x * 256 + wv * 64;

    f32x4 acc[4][8];
    #pragma unroll
    for (int rt = 0; rt < 4; rt++)
        #pragma unroll
        for (int ct = 0; ct < 8; ct++)
            acc[rt][ct] = (f32x4)0.0f;

    for (int kc = 0; kc < 8; kc++) {
        short8 a[4];
        #pragma unroll
        for (int rt = 0; rt < 4; rt++) {
            int row = rowBase + rt * 16 + m;
            int k0 = kc * 32 + q * 8;
            if (row < hi) {
                if (kc < 4) {
                    a[rt] = *(const short8*)&aggb[(long)(row - lo) * HDIM + k0];
                } else {
                    a[rt] = *(const short8*)&hb[(long)row * HDIM + (k0 - 128)];
                }
            } else {
                short8 t;
                #pragma unroll
                for (int i = 0; i < 8; i++) t[i] = 0;
                a[rt] = t;
            }
        }
        short8 b[8];
        #pragma unroll
        for (int ct = 0; ct < 8; ct++)
            b[ct] = *(const short8*)&smBT[(ct * 16 + m) * 256
                                          + 8 * ((kc * 4 + q) ^ (m & 7))];
        #pragma unroll
        for (int rt = 0; rt < 4; rt++)
            #pragma unroll
            for (int ct = 0; ct < 8; ct++)
                acc[rt][ct] = __builtin_amdgcn_mfma_f32_16x16x32_bf16(
                    a[rt], b[ct], acc[rt][ct], 0, 0, 0);
    }

    #pragma unroll
    for (int rt = 0; rt < 4; rt++) {
        #pragma unroll
        for (int rg = 0; rg < 4; rg++) {
            int row = rowBase + rt * 16 + q * 4 + rg;
            if (row >= hi) continue;
            #pragma unroll
            for (int ct = 0; ct < 8; ct++) {
                int col = ct * 16 + m;
                float c = acc[rt][ct][rg];
                c = c >= 0.0f ? c : SLOPE * c;
                if (F32OUT) outf[(long)row * HDIM + col] = c;
                else        outb[(long)row * HDIM + col] = f2bs(c);
            }
        }
    }
}

// ---------------------------------------------------------------------------
// Fused epilogue v8 — v5 structure, bf16 cur input (except last step):
//   wf=0: cur read from Cb (bf16), state written bf16.
//   wf=1: cur read from C (f32), output written f32 (d_out).
//   LDS 17.4 KB -> 8 blocks/CU.  5 barriers.
// ---------------------------------------------------------------------------
#define ER 32                  // rows per block
#define ES 136                 // bf16 row stride (shorts)
__global__ __launch_bounds__(256, 8)
void fused_epi_kernel(const float* __restrict__ curf, const short* __restrict__ curb,
                      const short* __restrict__ hb,
                      const short* __restrict__ BTe1, const short* __restrict__ BTe2,
                      const short* __restrict__ BTe3,
                      const float* __restrict__ bt, const float* __restrict__ bg,
                      const float* __restrict__ btd,
                      float* __restrict__ outp, short* __restrict__ abfo, int wf)
{
    __shared__ __align__(16) short cs[ER * ES];   // cur_n -> h1 -> h2
    __shared__ __align__(16) short hd[ER * ES];   // h -> d
    const int tid = threadIdx.x;
    const long row0 = (long)blockIdx.x * ER;

    // stage cur (fused l2-norm) and hb (bf16 passthrough)
    #pragma unroll
    for (int it = 0; it < 2; it++) {
        int s = it * 256 + tid;
        int r = s >> 4, c8 = (s & 15) * 8;
        float x[8];
        if (wf) {
            const float* pc = &curf[(row0 + r) * HDIM + c8];
            float4 c0 = *(const float4*)pc, c1 = *(const float4*)(pc + 4);
            x[0]=c0.x; x[1]=c0.y; x[2]=c0.z; x[3]=c0.w;
            x[4]=c1.x; x[5]=c1.y; x[6]=c1.z; x[7]=c1.w;
        } else {
            short8 cv = *(const short8*)&curb[(row0 + r) * HDIM + c8];
            #pragma unroll
            for (int j = 0; j < 8; j++) x[j] = bs2f(cv[j]);
        }
        short8 th = *(const short8*)&hb[(row0 + r) * HDIM + c8];
        float ss = x[0]*x[0] + x[1]*x[1] + x[2]*x[2] + x[3]*x[3]
                 + x[4]*x[4] + x[5]*x[5] + x[6]*x[6] + x[7]*x[7];
        ss += __shfl_xor(ss, 1);
        ss += __shfl_xor(ss, 2);
        ss += __shfl_xor(ss, 4);
        ss += __shfl_xor(ss, 8);
        float inv = 1.0f / fmaxf(sqrtf(ss), 1e-12f);
        short8 tc;
        #pragma unroll
        for (int j = 0; j < 8; j++) tc[j] = f2bs(x[j] * inv);
        *(short8*)&cs[r * ES + c8] = tc;
        *(short8*)&hd[r * ES + c8] = th;
    }
    __syncthreads();

    const int wv = tid >> 6, lane = tid & 63;
    const int m = lane & 15, q = lane >> 4;
    const int wr0 = (wv >> 1) * 16;                // wave's row base (0 or 16)
    const int ct0 = (wv & 1) * 4;                  // wave's col-tile base

    // hoisted bias fragments (L2-hot)
    float btr[4], bgr[4], btdr[4];
    #pragma unroll
    for (int ct = 0; ct < 4; ct++) {
        btr[ct]  = bt[(ct0 + ct) * 16 + m];
        bgr[ct]  = bg[(ct0 + ct) * 16 + m];
        btdr[ct] = btd[(ct0 + ct) * 16 + m];
    }

    f32x4 acc[4];

    // ---- E1: acc = cur_n @ Wt
    #pragma unroll
    for (int ct = 0; ct < 4; ct++) acc[ct] = (f32x4)0.0f;
    #pragma unroll
    for (int kc = 0; kc < 4; kc++) {
        int k0 = kc * 32 + q * 8;
        short8 a = *(const short8*)&cs[(wr0 + m) * ES + k0];
        #pragma unroll
        for (int ct = 0; ct < 4; ct++) {
            short8 b = *(const short8*)&BTe1[((ct0 + ct) * 16 + m) * 128 + k0];
            acc[ct] = __builtin_amdgcn_mfma_f32_16x16x32_bf16(a, b, acc[ct], 0, 0, 0);
        }
    }
    __syncthreads();   // all E1 A-reads complete before h1 overwrites cs

    #pragma unroll
    for (int ct = 0; ct < 4; ct++) {
        int col = (ct0 + ct) * 16 + m;
        #pragma unroll
        for (int rg = 0; rg < 4; rg++) {
            int rl = wr0 + q * 4 + rg;
            float tw = sigm(acc[ct][rg] + btr[ct]);
            float curn = bs2f(cs[rl * ES + col]);
            float hv = bs2f(hd[rl * ES + col]);
            cs[rl * ES + col] = f2bs(tw * curn + (1.0f - tw) * hv);   // h1
        }
    }
    __syncthreads();

    // ---- E2: acc = [h1|h] @ Wg^T
    #pragma unroll
    for (int ct = 0; ct < 4; ct++) acc[ct] = (f32x4)0.0f;
    #pragma unroll
    for (int kc = 0; kc < 8; kc++) {
        int k0 = kc * 32 + q * 8;
        short8 a = (kc < 4) ? *(const short8*)&cs[(wr0 + m) * ES + k0]
                            : *(const short8*)&hd[(wr0 + m) * ES + (k0 - 128)];
        #pragma unroll
        for (int ct = 0; ct < 4; ct++) {
            short8 b = *(const short8*)&BTe2[((ct0 + ct) * 16 + m) * 256 + k0];
            acc[ct] = __builtin_amdgcn_mfma_f32_16x16x32_bf16(a, b, acc[ct], 0, 0, 0);
        }
    }
    __syncthreads();   // all E2 reads of cs/hd done before h2/d overwrite

    #pragma unroll
    for (int ct = 0; ct < 4; ct++) {
        int col = (ct0 + ct) * 16 + m;
        #pragma unroll
        for (int rg = 0; rg < 4; rg++) {
            int rl = wr0 + q * 4 + rg;
            float g = sigm(acc[ct][rg] + bgr[ct]);
            float h1v = bs2f(cs[rl * ES + col]);
            float hv = bs2f(hd[rl * ES + col]);
            float h2 = g * h1v + (1.0f - g) * hv;
            cs[rl * ES + col] = f2bs(h2);              // h2
            hd[rl * ES + col] = f2bs(h2 - hv);         // d (h dead now)
        }
    }
    __syncthreads();

    // ---- E3: acc = d @ Wtd^T
    #pragma unroll
    for (int ct = 0; ct < 4; ct++) acc[ct] = (f32x4)0.0f;
    #pragma unroll
    for (int kc = 0; kc < 4; kc++) {
        int k0 = kc * 32 + q * 8;
        short8 a = *(const short8*)&hd[(wr0 + m) * ES + k0];
        #pragma unroll
        for (int ct = 0; ct < 4; ct++) {
            short8 b = *(const short8*)&BTe3[((ct0 + ct) * 16 + m) * 128 + k0];
            acc[ct] = __builtin_amdgcn_mfma_f32_16x16x32_bf16(a, b, acc[ct], 0, 0, 0);
        }
    }

    // ---- final: out = h2 + relu(d@Wtd + btd); cs reads are same-lane.
    #pragma unroll
    for (int ct = 0; ct < 4; ct++) {
        int col = (ct0 + ct) * 16 + m;
        #pragma unroll
        for (int rg = 0; rg < 4; rg++) {
            int rl = wr0 + q * 4 + rg;
            float td = fmaxf(acc[ct][rg] + btdr[ct], 0.0f);
            float val = bs2f(cs[rl * ES + col]) + td;
            if (wf) outp[(row0 + rl) * HDIM + col] = val;
            else    abfo[(row0 + rl) * HDIM + col] = f2bs(val);
        }
    }
}

// ---------------------------------------------------------------------------
extern "C" void kernel_launch(void* const* d_in, const int* in_sizes, int n_in,
                              void* d_out, int out_size, void* d_ws, size_t ws_size,
                              hipStream_t stream)
{
    const int* src = (const int*)d_in[0];
    const int* dst = (const int*)d_in[1];
    const int* ety = (const int*)d_in[2];
    const float* dyn     = (const float*)d_in[3];
    const float* emb_rel = (const float*)d_in[4];
    const float* Wn1     = (const float*)d_in[5];
    const float* Wl1     = (const float*)d_in[6];
    const float* Wn2     = (const float*)d_in[7];
    const float* Wl2     = (const float*)d_in[8];
    const float* gWx     = (const float*)d_in[9];
    const float* gWh     = (const float*)d_in[10];
    const float* gbx     = (const float*)d_in[11];
    const float* gbh     = (const float*)d_in[12];
    const float* gateW   = (const float*)d_in[13];
    const float* gateb   = (const float*)d_in[14];
    const float* tdW     = (const float*)d_in[15];
    const float* tdb     = (const float*)d_in[16];
    const float* tgW     = (const float*)d_in[17];
    const float* tgb     = (const float*)d_in[18];

    const long NH = (long)N_ENT * HDIM;          // 12,800,000
    float* ws = (float*)d_ws;
    long off = 0;
    short* Abf  = (short*)(ws + off); off += NH / 2;   // bf16 h-state
    short* Bb   = (short*)(ws + off); off += NH / 2;   // bf16 layer1 out
    short* Cb   = (short*)(ws + off); off += NH / 2;   // bf16 layer2 out (t<3)
    float* rel  = ws + off; off += (long)NR * HDIM;
    short* relb = (short*)(ws + off); off += (NR * HDIM) / 2;
    float* WxT  = ws + off; off += 98304;
    float* WhT  = ws + off; off += 49152;
    short* BT1  = (short*)(ws + off); off += 16384;   // 128x256 bf16
    short* BT2  = (short*)(ws + off); off += 16384;
    short* BTe1 = (short*)(ws + off); off += 8192;    // 128x128 bf16
    short* BTe2 = (short*)(ws + off); off += 16384;
    short* BTe3 = (short*)(ws + off); off += 8192;
    int* rowptr = (int*)(ws + off); off += NPAD;
    int* cnt    = (int*)(ws + off); off += NPAD;      // cnt, cnt2 contiguous
    int* cnt2   = (int*)(ws + off); off += NPAD;
    int* eidx   = (int*)(ws + off); off += 200704;
    int* bsum   = (int*)(ws + off); off += 128;
    short* aggb = (short*)(ws + off);            // chunk*128 bf16
    float* C    = (float*)d_out;                 // f32 layer2 out (last step)

    const long avail = (long)(ws_size / 4) - off;
    const int cand[5] = {100000, 50000, 25008, 12512, 6256};
    int chunk = -1;
    for (int c = 0; c < 5; c++)
        if (avail >= (long)cand[c] * 64) { chunk = cand[c]; break; }

    if (chunk < 0) {
        diag_kernel<<<1, 64, 0, stream>>>((float*)d_out, (float)ws_size);
        return;
    }

    prep_kernel<<<256, 256, 0, stream>>>(
        emb_rel, gWx, gWh, Wn1, Wl1, Wn2, Wl2, tgW, gateW, tdW,
        rel, WxT, WhT, BT1, BT2, BTe1, BTe2, BTe3);

    norm_init_kernel<<<N_ENT, 64, 0, stream>>>(dyn, Abf);

    const int egrid = (NE + 255) / 256;          // 782 blocks
    const int fe_grid = N_ENT / 32;              // 3125 blocks

    for (int t = 0; t < NSTEP; t++) {
        const int* st = src + (long)t * NE;
        const int* dt = dst + (long)t * NE;
        const int* et = ety + (long)t * NE;

        // ---- CSR build for this step's graph (shared by both layers)
        zero_int_kernel<<<(2 * NPAD + 255) / 256, 256, 0, stream>>>(cnt, 2 * NPAD);
        hist_kernel<<<egrid, 256, 0, stream>>>(dt, cnt);
        scan1_kernel<<<SCAN_NB, 256, 0, stream>>>(cnt, rowptr, bsum);
        scan2_kernel<<<1, 128, 0, stream>>>(bsum, SCAN_NB);
        scan3_kernel<<<SCAN_NB, 256, 0, stream>>>(rowptr, bsum);
        fill_kernel<<<egrid, 256, 0, stream>>>(dt, rowptr, cnt2, eidx);

        gru_kernel<<<NR, 128, 0, stream>>>(rel, relb, emb_rel, WxT, WhT, gbx, gbh);

        int wf = (t == NSTEP - 1) ? 1 : 0;

        // layer 1: Abf -> Bb (bf16)
        for (int lo = 0; lo < N_ENT; lo += chunk) {
            int hi = lo + chunk > N_ENT ? N_ENT : lo + chunk;
            gather_kernel<<<((hi - lo) * 16 + 255) / 256, 256, 0, stream>>>(
                st, et, eidx, rowptr, Abf, relb, aggb, lo, hi);
            layer_gemm<0><<<(hi - lo + 255) / 256, 256, 0, stream>>>(
                aggb, Abf, BT1, nullptr, Bb, lo, hi);
        }
        // layer 2: Bb -> Cb (bf16, t<3) or C (f32, t=3)
        for (int lo = 0; lo < N_ENT; lo += chunk) {
            int hi = lo + chunk > N_ENT ? N_ENT : lo + chunk;
            gather_kernel<<<((hi - lo) * 16 + 255) / 256, 256, 0, stream>>>(
                st, et, eidx, rowptr, Bb, relb, aggb, lo, hi);
            if (wf)
                layer_gemm<1><<<(hi - lo + 255) / 256, 256, 0, stream>>>(
                    aggb, Bb, BT2, C, nullptr, lo, hi);
            else
                layer_gemm<0><<<(hi - lo + 255) / 256, 256, 0, stream>>>(
                    aggb, Bb, BT2, nullptr, Cb, lo, hi);
        }

        // fused epilogue: (cur, Abf) -> Abf (t<3, bf16) or d_out == C (t=3)
        fused_epi_kernel<<<fe_grid, 256, 0, stream>>>(
            C, Cb, Abf, BTe1, BTe2, BTe3, tgb, gateb, tdb, C, Abf, wf);
    }
}

// Round 6
// 1063.587 us; speedup vs baseline: 1.4674x; 1.0314x over previous
//
#include <hip/hip_runtime.h>
#include <hip/hip_bf16.h>

#define N_ENT 100000
#define HDIM 128
#define NE 200000
#define NR 460
#define NSTEP 4
#define SLOPE 0.22916666666666666f
#define NPAD 100352            // N_ENT padded to 1024 multiple (98*1024)
#define SCAN_NB 98

typedef __attribute__((ext_vector_type(8))) short short8;
typedef __attribute__((ext_vector_type(4))) float f32x4;

__device__ __forceinline__ float sigm(float x) { return 1.0f / (1.0f + __expf(-x)); }
__device__ __forceinline__ short f2bs(float f) {
    __hip_bfloat16 b = __float2bfloat16(f);
    short s; __builtin_memcpy(&s, &b, 2); return s;
}
__device__ __forceinline__ float bs2f(short s) {
    union { unsigned int u; float f; } c;
    c.u = ((unsigned int)(unsigned short)s) << 16;
    return c.f;
}

// ---------------------------------------------------------------------------
__global__ void zero_int_kernel(int* __restrict__ p, int n)
{
    int i = blockIdx.x * 256 + threadIdx.x;
    if (i < n) p[i] = 0;
}

__global__ void diag_kernel(float* o, float v)
{
    if (threadIdx.x == 0) o[0] = v;
}

// ---------------------------------------------------------------------------
// CSR build: histogram -> 3-phase exclusive scan -> fill
// ---------------------------------------------------------------------------
__global__ void hist_kernel(const int* __restrict__ dst, int* __restrict__ cnt)
{
    int e = blockIdx.x * 256 + threadIdx.x;
    if (e < NE) atomicAdd(&cnt[dst[e]], 1);
}

__global__ __launch_bounds__(256)
void scan1_kernel(const int* __restrict__ cnt, int* __restrict__ rowptr,
                  int* __restrict__ bsum)
{
    __shared__ int ts[256];
    int b = blockIdx.x, t = threadIdx.x;
    int base = b * 1024 + t * 4;
    int4 v = *(const int4*)&cnt[base];
    int s = v.x + v.y + v.z + v.w;
    ts[t] = s;
    __syncthreads();
    for (int off = 1; off < 256; off <<= 1) {
        int x = 0;
        if (t >= off) x = ts[t - off];
        __syncthreads();
        if (t >= off) ts[t] += x;
        __syncthreads();
    }
    int excl = ts[t] - s;
    if (t == 255) bsum[b] = ts[t];
    rowptr[base + 0] = excl;
    rowptr[base + 1] = excl + v.x;
    rowptr[base + 2] = excl + v.x + v.y;
    rowptr[base + 3] = excl + v.x + v.y + v.z;
}

__global__ __launch_bounds__(128)
void scan2_kernel(int* __restrict__ bsum, int nb)
{
    __shared__ int ts[128];
    int t = threadIdx.x;
    int v = (t < nb) ? bsum[t] : 0;
    ts[t] = v;
    __syncthreads();
    for (int off = 1; off < 128; off <<= 1) {
        int x = 0;
        if (t >= off) x = ts[t - off];
        __syncthreads();
        if (t >= off) ts[t] += x;
        __syncthreads();
    }
    if (t < nb) bsum[t] = ts[t] - v;   // exclusive
}

__global__ __launch_bounds__(256)
void scan3_kernel(int* __restrict__ rowptr, const int* __restrict__ bsum)
{
    int b = blockIdx.x, t = threadIdx.x;
    int add = bsum[b];
    int base = b * 1024 + t * 4;
    rowptr[base + 0] += add;
    rowptr[base + 1] += add;
    rowptr[base + 2] += add;
    rowptr[base + 3] += add;
}

__global__ void fill_kernel(const int* __restrict__ dst,
                            const int* __restrict__ rowptr,
                            int* __restrict__ c2, int* __restrict__ eidx)
{
    int e = blockIdx.x * 256 + threadIdx.x;
    if (e < NE) {
        int d = dst[e];
        int p = atomicAdd(&c2[d], 1);
        eidx[rowptr[d] + p] = e;
    }
}

// ---------------------------------------------------------------------------
// Prep: GRU weight transposes (f32) + bf16 B^T buffers for the MFMA GEMMs.
// ---------------------------------------------------------------------------
__global__ void prep_kernel(
    const float* __restrict__ emb_rel,
    const float* __restrict__ Wx, const float* __restrict__ Wh,
    const float* __restrict__ Wn1, const float* __restrict__ Wl1,
    const float* __restrict__ Wn2, const float* __restrict__ Wl2,
    const float* __restrict__ tgW, const float* __restrict__ gateW,
    const float* __restrict__ tdW,
    float* __restrict__ rel,
    float* __restrict__ WxT, float* __restrict__ WhT,
    short* __restrict__ BT1, short* __restrict__ BT2,
    short* __restrict__ BTe1, short* __restrict__ BTe2,
    short* __restrict__ BTe3)
{
    int tid = blockIdx.x * blockDim.x + threadIdx.x;
    int nthr = gridDim.x * blockDim.x;
    for (int i = tid; i < NR * HDIM; i += nthr)
        rel[i] = emb_rel[i];
    for (int i = tid; i < 384 * 256; i += nthr) {
        int r = i >> 8, c = i & 255;
        WxT[c * 384 + r] = Wx[i];
    }
    for (int i = tid; i < 384 * 128; i += nthr) {
        int r = i >> 7, c = i & 127;
        WhT[c * 384 + r] = Wh[i];
    }
    for (int i = tid; i < 128 * 256; i += nthr) {   // layer BTs: [x|h]@[Wn;Wl]
        int n = i >> 8, k = i & 255;
        float v1 = (k < 128) ? Wn1[k * 128 + n] : Wl1[(k - 128) * 128 + n];
        float v2 = (k < 128) ? Wn2[k * 128 + n] : Wl2[(k - 128) * 128 + n];
        BT1[n * 256 + k] = f2bs(v1);
        BT2[n * 256 + k] = f2bs(v2);
    }
    for (int i = tid; i < 128 * 128; i += nthr) {   // E1 (transpose), E3 (direct)
        int n = i >> 7, k = i & 127;
        BTe1[n * 128 + k] = f2bs(tgW[k * 128 + n]);
        BTe3[n * 128 + k] = f2bs(tdW[n * 128 + k]);
    }
    for (int i = tid; i < 128 * 256; i += nthr) {   // E2 (direct)
        int n = i >> 8, k = i & 255;
        BTe2[n * 256 + k] = f2bs(gateW[n * 256 + k]);
    }
}

// ---------------------------------------------------------------------------
// h0 = l2norm(dynamic_emb) stored bf16; one wave per row.
// ---------------------------------------------------------------------------
__global__ __launch_bounds__(64)
void norm_init_kernel(const float* __restrict__ emb, short* __restrict__ hb)
{
    int row = blockIdx.x, lane = threadIdx.x;
    float v0 = emb[row * HDIM + lane];
    float v1 = emb[row * HDIM + 64 + lane];
    float s = v0 * v0 + v1 * v1;
    #pragma unroll
    for (int off = 32; off; off >>= 1) s += __shfl_xor(s, off);
    float invn = 1.0f / fmaxf(sqrtf(s), 1e-12f);
    hb[row * HDIM + lane] = f2bs(v0 * invn);
    hb[row * HDIM + 64 + lane] = f2bs(v1 * invn);
}

// ---------------------------------------------------------------------------
// GRUCell relation evolution (f32 GEMV — tiny: 460 rows). Also writes a bf16
// shadow of the relation embeddings for the gather kernel.
// ---------------------------------------------------------------------------
__global__ __launch_bounds__(128)
void gru_kernel(float* rel, short* __restrict__ relb,
                const float* __restrict__ emb_rel,
                const float* __restrict__ WxT, const float* __restrict__ WhT,
                const float* __restrict__ bx, const float* __restrict__ bh)
{
    __shared__ __align__(16) float x[256];
    __shared__ __align__(16) float hh[128];
    int b = blockIdx.x, j = threadIdx.x;
    float hj = rel[b * HDIM + j];
    x[j] = emb_rel[b * HDIM + j];
    x[128 + j] = hj;
    hh[j] = hj;
    __syncthreads();
    float xr = 0, xz = 0, xn = 0, hr = 0, hz = 0, hn = 0;
    for (int k = 0; k < 256; k++) {
        float xv = x[k];
        const float* w = &WxT[k * 384];
        xr += xv * w[j]; xz += xv * w[128 + j]; xn += xv * w[256 + j];
    }
    for (int k = 0; k < 128; k++) {
        float hv = hh[k];
        const float* w = &WhT[k * 384];
        hr += hv * w[j]; hz += hv * w[128 + j]; hn += hv * w[256 + j];
    }
    float r = sigm(xr + bx[j] + hr + bh[j]);
    float z = sigm(xz + bx[128 + j] + hz + bh[128 + j]);
    float n = tanhf(xn + bx[256 + j] + r * (hn + bh[256 + j]));
    float nv = (1.0f - z) * n + z * hj;
    rel[b * HDIM + j] = nv;
    relb[b * HDIM + j] = f2bs(nv);
}

// ---------------------------------------------------------------------------
// CSR gather (bf16 state): aggb[r-lo] = bf16((sum_e hb[src]+relb[et])/deg).
// 16 lanes per row (short8 = 8 cols/lane) -> 4 independent row chains/wave.
// ---------------------------------------------------------------------------
__global__ __launch_bounds__(256)
void gather_kernel(const int* __restrict__ src, const int* __restrict__ et,
                   const int* __restrict__ eidx, const int* __restrict__ rowptr,
                   const short* __restrict__ hb, const short* __restrict__ relb,
                   short* __restrict__ aggb, int lo, int hi)
{
    int idx = blockIdx.x * 256 + threadIdx.x;
    int r = lo + (idx >> 4);
    int i8 = (idx & 15) * 8;
    if (r >= hi) return;
    int p0 = rowptr[r], p1 = rowptr[r + 1];
    float v[8] = {0, 0, 0, 0, 0, 0, 0, 0};
    for (int p = p0; p < p1; p++) {
        int e = eidx[p];
        int s = src[e], rt = et[e];
        short8 hv = *(const short8*)&hb[(long)s * HDIM + i8];
        short8 rv = *(const short8*)&relb[rt * HDIM + i8];
        #pragma unroll
        for (int j = 0; j < 8; j++) v[j] += bs2f(hv[j]) + bs2f(rv[j]);
    }
    float rdeg = (p1 > p0) ? 1.0f / (float)(p1 - p0) : 0.0f;
    short8 o;
    #pragma unroll
    for (int j = 0; j < 8; j++) o[j] = f2bs(v[j] * rdeg);
    *(short8*)&aggb[(long)(r - lo) * HDIM + i8] = o;
}

// ---------------------------------------------------------------------------
// Layer MFMA GEMM: out = rrelu([aggb | hb] @ BT^T).
// BT (128x256 bf16 = 64 KB) staged into LDS once per block, XOR-swizzled.
// ---------------------------------------------------------------------------
template<int F32OUT>
__global__ __launch_bounds__(256, 2)
void layer_gemm(const short* __restrict__ aggb, const short* __restrict__ hb,
                const short* __restrict__ BTg, float* __restrict__ outf,
                short* __restrict__ outb, int lo, int hi)
{
    __shared__ __align__(16) short smBT[128 * 256];   // 64 KB
    const int tid = threadIdx.x;

    // stage BT with swizzle: 4096 slots of 8 shorts, 16 per thread
    #pragma unroll
    for (int it = 0; it < 16; it++) {
        int s = it * 256 + tid;
        int row = s >> 5, k8 = s & 31;
        short8 v = *(const short8*)&BTg[row * 256 + k8 * 8];
        *(short8*)&smBT[row * 256 + 8 * (k8 ^ (row & 7))] = v;
    }
    __syncthreads();

    const int lane = tid & 63;
    const int wv = tid >> 6;
    const int m = lane & 15, q = lane >> 4;
    const int rowBase = lo + blockIdx.x * 256 + wv * 64;

    f32x4 acc[4][8];
    #pragma unroll
    for (int rt = 0; rt < 4; rt++)
        #pragma unroll
        for (int ct = 0; ct < 8; ct++)
            acc[rt][ct] = (f32x4)0.0f;

    for (int kc = 0; kc < 8; kc++) {
        short8 a[4];
        #pragma unroll
        for (int rt = 0; rt < 4; rt++) {
            int row = rowBase + rt * 16 + m;
            int k0 = kc * 32 + q * 8;
            if (row < hi) {
                if (kc < 4) {
                    a[rt] = *(const short8*)&aggb[(long)(row - lo) * HDIM + k0];
                } else {
                    a[rt] = *(const short8*)&hb[(long)row * HDIM + (k0 - 128)];
                }
            } else {
                short8 t;
                #pragma unroll
                for (int i = 0; i < 8; i++) t[i] = 0;
                a[rt] = t;
            }
        }
        short8 b[8];
        #pragma unroll
        for (int ct = 0; ct < 8; ct++)
            b[ct] = *(const short8*)&smBT[(ct * 16 + m) * 256
                                          + 8 * ((kc * 4 + q) ^ (m & 7))];
        #pragma unroll
        for (int rt = 0; rt < 4; rt++)
            #pragma unroll
            for (int ct = 0; ct < 8; ct++)
                acc[rt][ct] = __builtin_amdgcn_mfma_f32_16x16x32_bf16(
                    a[rt], b[ct], acc[rt][ct], 0, 0, 0);
    }

    #pragma unroll
    for (int rt = 0; rt < 4; rt++) {
        #pragma unroll
        for (int rg = 0; rg < 4; rg++) {
            int row = rowBase + rt * 16 + q * 4 + rg;
            if (row >= hi) continue;
            #pragma unroll
            for (int ct = 0; ct < 8; ct++) {
                int col = ct * 16 + m;
                float c = acc[rt][ct][rg];
                c = c >= 0.0f ? c : SLOPE * c;
                if (F32OUT) outf[(long)row * HDIM + col] = c;
                else        outb[(long)row * HDIM + col] = f2bs(c);
            }
        }
    }
}

// ---------------------------------------------------------------------------
// Fused epilogue v9 — dual-tile interleaved pipeline:
//   Each block owns TWO independent 32-row tiles; every phase runs T0 then T1
//   so each dependent {LDS read -> ops -> barrier} chain has an equal-sized
//   independent twin to fill its stall slots (5 structural variants showed
//   the single-tile version is latency-pinned at ~115us regardless of bytes
//   or occupancy).  LDS 34.8 KB -> 4 blocks/CU x 4 waves.
// ---------------------------------------------------------------------------
#define ER 32                  // rows per tile
#define ES 136                 // bf16 row stride (shorts)

__device__ __forceinline__ void stage_tile(
    const float* __restrict__ curf, const short* __restrict__ curb,
    const short* __restrict__ hb, long rb, int tid, int wf,
    short* cs, short* hd)
{
    #pragma unroll
    for (int it = 0; it < 2; it++) {
        int s = it * 256 + tid;
        int r = s >> 4, c8 = (s & 15) * 8;
        float x[8];
        if (wf) {
            const float* pc = &curf[(rb + r) * HDIM + c8];
            float4 c0 = *(const float4*)pc, c1 = *(const float4*)(pc + 4);
            x[0]=c0.x; x[1]=c0.y; x[2]=c0.z; x[3]=c0.w;
            x[4]=c1.x; x[5]=c1.y; x[6]=c1.z; x[7]=c1.w;
        } else {
            short8 cv = *(const short8*)&curb[(rb + r) * HDIM + c8];
            #pragma unroll
            for (int j = 0; j < 8; j++) x[j] = bs2f(cv[j]);
        }
        short8 th = *(const short8*)&hb[(rb + r) * HDIM + c8];
        float ss = x[0]*x[0] + x[1]*x[1] + x[2]*x[2] + x[3]*x[3]
                 + x[4]*x[4] + x[5]*x[5] + x[6]*x[6] + x[7]*x[7];
        ss += __shfl_xor(ss, 1);
        ss += __shfl_xor(ss, 2);
        ss += __shfl_xor(ss, 4);
        ss += __shfl_xor(ss, 8);
        float inv = 1.0f / fmaxf(sqrtf(ss), 1e-12f);
        short8 tc;
        #pragma unroll
        for (int j = 0; j < 8; j++) tc[j] = f2bs(x[j] * inv);
        *(short8*)&cs[r * ES + c8] = tc;
        *(short8*)&hd[r * ES + c8] = th;
    }
}

// K=128 GEMM tile: acc = A(LDS) @ Bg^T  (4 col-tiles of this wave)
__device__ __forceinline__ void mm128(const short* As, const short* __restrict__ Bg,
                                      int wr0, int ct0, int m, int q, f32x4 acc[4])
{
    #pragma unroll
    for (int ct = 0; ct < 4; ct++) acc[ct] = (f32x4)0.0f;
    #pragma unroll
    for (int kc = 0; kc < 4; kc++) {
        int k0 = kc * 32 + q * 8;
        short8 a = *(const short8*)&As[(wr0 + m) * ES + k0];
        #pragma unroll
        for (int ct = 0; ct < 4; ct++) {
            short8 b = *(const short8*)&Bg[((ct0 + ct) * 16 + m) * 128 + k0];
            acc[ct] = __builtin_amdgcn_mfma_f32_16x16x32_bf16(a, b, acc[ct], 0, 0, 0);
        }
    }
}

// K=256 GEMM tile: acc = [cs|hd](LDS) @ Bg^T
__device__ __forceinline__ void mm256(const short* cs, const short* hd,
                                      const short* __restrict__ Bg,
                                      int wr0, int ct0, int m, int q, f32x4 acc[4])
{
    #pragma unroll
    for (int ct = 0; ct < 4; ct++) acc[ct] = (f32x4)0.0f;
    #pragma unroll
    for (int kc = 0; kc < 8; kc++) {
        int k0 = kc * 32 + q * 8;
        short8 a = (kc < 4) ? *(const short8*)&cs[(wr0 + m) * ES + k0]
                            : *(const short8*)&hd[(wr0 + m) * ES + (k0 - 128)];
        #pragma unroll
        for (int ct = 0; ct < 4; ct++) {
            short8 b = *(const short8*)&Bg[((ct0 + ct) * 16 + m) * 256 + k0];
            acc[ct] = __builtin_amdgcn_mfma_f32_16x16x32_bf16(a, b, acc[ct], 0, 0, 0);
        }
    }
}

__device__ __forceinline__ void epi1_f(const f32x4 acc[4], const float btr[4],
                                       short* cs, const short* hd,
                                       int wr0, int ct0, int m, int q)
{
    #pragma unroll
    for (int ct = 0; ct < 4; ct++) {
        int col = (ct0 + ct) * 16 + m;
        #pragma unroll
        for (int rg = 0; rg < 4; rg++) {
            int rl = wr0 + q * 4 + rg;
            float tw = sigm(acc[ct][rg] + btr[ct]);
            float curn = bs2f(cs[rl * ES + col]);
            float hv = bs2f(hd[rl * ES + col]);
            cs[rl * ES + col] = f2bs(tw * curn + (1.0f - tw) * hv);   // h1
        }
    }
}

__device__ __forceinline__ void epi2_f(const f32x4 acc[4], const float bgr[4],
                                       short* cs, short* hd,
                                       int wr0, int ct0, int m, int q)
{
    #pragma unroll
    for (int ct = 0; ct < 4; ct++) {
        int col = (ct0 + ct) * 16 + m;
        #pragma unroll
        for (int rg = 0; rg < 4; rg++) {
            int rl = wr0 + q * 4 + rg;
            float g = sigm(acc[ct][rg] + bgr[ct]);
            float h1v = bs2f(cs[rl * ES + col]);
            float hv = bs2f(hd[rl * ES + col]);
            float h2 = g * h1v + (1.0f - g) * hv;
            cs[rl * ES + col] = f2bs(h2);              // h2
            hd[rl * ES + col] = f2bs(h2 - hv);         // d (h dead now)
        }
    }
}

__device__ __forceinline__ void fin_f(const f32x4 acc[4], const float btdr[4],
                                      const short* cs, long rb,
                                      float* __restrict__ outp,
                                      short* __restrict__ abfo, int wf,
                                      int wr0, int ct0, int m, int q)
{
    #pragma unroll
    for (int ct = 0; ct < 4; ct++) {
        int col = (ct0 + ct) * 16 + m;
        #pragma unroll
        for (int rg = 0; rg < 4; rg++) {
            int rl = wr0 + q * 4 + rg;
            float td = fmaxf(acc[ct][rg] + btdr[ct], 0.0f);
            float val = bs2f(cs[rl * ES + col]) + td;
            if (wf) outp[(rb + rl) * HDIM + col] = val;
            else    abfo[(rb + rl) * HDIM + col] = f2bs(val);
        }
    }
}

__global__ __launch_bounds__(256, 4)
void fused_epi_kernel(const float* __restrict__ curf, const short* __restrict__ curb,
                      const short* __restrict__ hb,
                      const short* __restrict__ BTe1, const short* __restrict__ BTe2,
                      const short* __restrict__ BTe3,
                      const float* __restrict__ bt, const float* __restrict__ bg,
                      const float* __restrict__ btd,
                      float* __restrict__ outp, short* __restrict__ abfo, int wf)
{
    __shared__ __align__(16) short cs[2][ER * ES];   // cur_n -> h1 -> h2
    __shared__ __align__(16) short hd[2][ER * ES];   // h -> d
    const int tid = threadIdx.x;
    const long row0 = (long)blockIdx.x * (2 * ER);
    const long row1 = row0 + ER;
    const bool t1v = (row1 < N_ENT);

    stage_tile(curf, curb, hb, row0, tid, wf, cs[0], hd[0]);
    if (t1v) stage_tile(curf, curb, hb, row1, tid, wf, cs[1], hd[1]);
    __syncthreads();

    const int wv = tid >> 6, lane = tid & 63;
    const int m = lane & 15, q = lane >> 4;
    const int wr0 = (wv >> 1) * 16;                // wave's row base (0 or 16)
    const int ct0 = (wv & 1) * 4;                  // wave's col-tile base

    float btr[4], bgr[4], btdr[4];
    #pragma unroll
    for (int ct = 0; ct < 4; ct++) {
        btr[ct]  = bt[(ct0 + ct) * 16 + m];
        bgr[ct]  = bg[(ct0 + ct) * 16 + m];
        btdr[ct] = btd[(ct0 + ct) * 16 + m];
    }

    f32x4 a0[4], a1[4];

    // ---- E1 (both tiles, independent)
    mm128(cs[0], BTe1, wr0, ct0, m, q, a0);
    if (t1v) mm128(cs[1], BTe1, wr0, ct0, m, q, a1);
    __syncthreads();
    epi1_f(a0, btr, cs[0], hd[0], wr0, ct0, m, q);
    if (t1v) epi1_f(a1, btr, cs[1], hd[1], wr0, ct0, m, q);
    __syncthreads();

    // ---- E2
    mm256(cs[0], hd[0], BTe2, wr0, ct0, m, q, a0);
    if (t1v) mm256(cs[1], hd[1], BTe2, wr0, ct0, m, q, a1);
    __syncthreads();
    epi2_f(a0, bgr, cs[0], hd[0], wr0, ct0, m, q);
    if (t1v) epi2_f(a1, bgr, cs[1], hd[1], wr0, ct0, m, q);
    __syncthreads();

    // ---- E3
    mm128(hd[0], BTe3, wr0, ct0, m, q, a0);
    if (t1v) mm128(hd[1], BTe3, wr0, ct0, m, q, a1);
    // final: cs reads are same-lane (epi2 wrote them) -> no barrier
    fin_f(a0, btdr, cs[0], row0, outp, abfo, wf, wr0, ct0, m, q);
    if (t1v) fin_f(a1, btdr, cs[1], row1, outp, abfo, wf, wr0, ct0, m, q);
}

// ---------------------------------------------------------------------------
extern "C" void kernel_launch(void* const* d_in, const int* in_sizes, int n_in,
                              void* d_out, int out_size, void* d_ws, size_t ws_size,
                              hipStream_t stream)
{
    const int* src = (const int*)d_in[0];
    const int* dst = (const int*)d_in[1];
    const int* ety = (const int*)d_in[2];
    const float* dyn     = (const float*)d_in[3];
    const float* emb_rel = (const float*)d_in[4];
    const float* Wn1     = (const float*)d_in[5];
    const float* Wl1     = (const float*)d_in[6];
    const float* Wn2     = (const float*)d_in[7];
    const float* Wl2     = (const float*)d_in[8];
    const float* gWx     = (const float*)d_in[9];
    const float* gWh     = (const float*)d_in[10];
    const float* gbx     = (const float*)d_in[11];
    const float* gbh     = (const float*)d_in[12];
    const float* gateW   = (const float*)d_in[13];
    const float* gateb   = (const float*)d_in[14];
    const float* tdW     = (const float*)d_in[15];
    const float* tdb     = (const float*)d_in[16];
    const float* tgW     = (const float*)d_in[17];
    const float* tgb     = (const float*)d_in[18];

    const long NH = (long)N_ENT * HDIM;          // 12,800,000
    float* ws = (float*)d_ws;
    long off = 0;
    short* Abf  = (short*)(ws + off); off += NH / 2;   // bf16 h-state
    short* Bb   = (short*)(ws + off); off += NH / 2;   // bf16 layer1 out
    short* Cb   = (short*)(ws + off); off += NH / 2;   // bf16 layer2 out (t<3)
    float* rel  = ws + off; off += (long)NR * HDIM;
    short* relb = (short*)(ws + off); off += (NR * HDIM) / 2;
    float* WxT  = ws + off; off += 98304;
    float* WhT  = ws + off; off += 49152;
    short* BT1  = (short*)(ws + off); off += 16384;   // 128x256 bf16
    short* BT2  = (short*)(ws + off); off += 16384;
    short* BTe1 = (short*)(ws + off); off += 8192;    // 128x128 bf16
    short* BTe2 = (short*)(ws + off); off += 16384;
    short* BTe3 = (short*)(ws + off); off += 8192;
    int* rowptr = (int*)(ws + off); off += NPAD;
    int* cnt    = (int*)(ws + off); off += NPAD;      // cnt, cnt2 contiguous
    int* cnt2   = (int*)(ws + off); off += NPAD;
    int* eidx   = (int*)(ws + off); off += 200704;
    int* bsum   = (int*)(ws + off); off += 128;
    short* aggb = (short*)(ws + off);            // chunk*128 bf16
    float* C    = (float*)d_out;                 // f32 layer2 out (last step)

    const long avail = (long)(ws_size / 4) - off;
    const int cand[5] = {100000, 50000, 25008, 12512, 6256};
    int chunk = -1;
    for (int c = 0; c < 5; c++)
        if (avail >= (long)cand[c] * 64) { chunk = cand[c]; break; }

    if (chunk < 0) {
        diag_kernel<<<1, 64, 0, stream>>>((float*)d_out, (float)ws_size);
        return;
    }

    prep_kernel<<<256, 256, 0, stream>>>(
        emb_rel, gWx, gWh, Wn1, Wl1, Wn2, Wl2, tgW, gateW, tdW,
        rel, WxT, WhT, BT1, BT2, BTe1, BTe2, BTe3);

    norm_init_kernel<<<N_ENT, 64, 0, stream>>>(dyn, Abf);

    const int egrid = (NE + 255) / 256;          // 782 blocks
    const int fe_grid = (N_ENT + 63) / 64;       // 1563 dual-tile blocks

    for (int t = 0; t < NSTEP; t++) {
        const int* st = src + (long)t * NE;
        const int* dt = dst + (long)t * NE;
        const int* et = ety + (long)t * NE;

        // ---- CSR build for this step's graph (shared by both layers)
        zero_int_kernel<<<(2 * NPAD + 255) / 256, 256, 0, stream>>>(cnt, 2 * NPAD);
        hist_kernel<<<egrid, 256, 0, stream>>>(dt, cnt);
        scan1_kernel<<<SCAN_NB, 256, 0, stream>>>(cnt, rowptr, bsum);
        scan2_kernel<<<1, 128, 0, stream>>>(bsum, SCAN_NB);
        scan3_kernel<<<SCAN_NB, 256, 0, stream>>>(rowptr, bsum);
        fill_kernel<<<egrid, 256, 0, stream>>>(dt, rowptr, cnt2, eidx);

        gru_kernel<<<NR, 128, 0, stream>>>(rel, relb, emb_rel, WxT, WhT, gbx, gbh);

        int wf = (t == NSTEP - 1) ? 1 : 0;

        // layer 1: Abf -> Bb (bf16)
        for (int lo = 0; lo < N_ENT; lo += chunk) {
            int hi = lo + chunk > N_ENT ? N_ENT : lo + chunk;
            gather_kernel<<<((hi - lo) * 16 + 255) / 256, 256, 0, stream>>>(
                st, et, eidx, rowptr, Abf, relb, aggb, lo, hi);
            layer_gemm<0><<<(hi - lo + 255) / 256, 256, 0, stream>>>(
                aggb, Abf, BT1, nullptr, Bb, lo, hi);
        }
        // layer 2: Bb -> Cb (bf16, t<3) or C (f32, t=3)
        for (int lo = 0; lo < N_ENT; lo += chunk) {
            int hi = lo + chunk > N_ENT ? N_ENT : lo + chunk;
            gather_kernel<<<((hi - lo) * 16 + 255) / 256, 256, 0, stream>>>(
                st, et, eidx, rowptr, Bb, relb, aggb, lo, hi);
            if (wf)
                layer_gemm<1><<<(hi - lo + 255) / 256, 256, 0, stream>>>(
                    aggb, Bb, BT2, C, nullptr, lo, hi);
            else
                layer_gemm<0><<<(hi - lo + 255) / 256, 256, 0, stream>>>(
                    aggb, Bb, BT2, nullptr, Cb, lo, hi);
        }

        // fused epilogue: (cur, Abf) -> Abf (t<3, bf16) or d_out == C (t=3)
        fused_epi_kernel<<<fe_grid, 256, 0, stream>>>(
            C, Cb, Abf, BTe1, BTe2, BTe3, tgb, gateb, tdb, C, Abf, wf);
    }
}

// Round 7
// 1037.310 us; speedup vs baseline: 1.5046x; 1.0253x over previous
//
#include <hip/hip_runtime.h>
#include <hip/hip_bf16.h>

#define N_ENT 100000
#define HDIM 128
#define NE 200000
#define NR 460
#define NSTEP 4
#define SLOPE 0.22916666666666666f
#define NPAD 100352            // N_ENT padded to 1024 multiple (98*1024)
#define SCAN_NB 98

typedef __attribute__((ext_vector_type(8))) short short8;
typedef __attribute__((ext_vector_type(4))) float f32x4;

__device__ __forceinline__ float sigm(float x) { return 1.0f / (1.0f + __expf(-x)); }
__device__ __forceinline__ short f2bs(float f) {
    __hip_bfloat16 b = __float2bfloat16(f);
    short s; __builtin_memcpy(&s, &b, 2); return s;
}
__device__ __forceinline__ float bs2f(short s) {
    union { unsigned int u; float f; } c;
    c.u = ((unsigned int)(unsigned short)s) << 16;
    return c.f;
}

// ---------------------------------------------------------------------------
__global__ void zero_int_kernel(int* __restrict__ p, int n)
{
    int i = blockIdx.x * 256 + threadIdx.x;
    if (i < n) p[i] = 0;
}

__global__ void diag_kernel(float* o, float v)
{
    if (threadIdx.x == 0) o[0] = v;
}

// ---------------------------------------------------------------------------
// CSR build: histogram -> 2-phase scan (block offsets applied on the fly by
// consumers) -> fill.  cnt is decremented back to zero by fill, so it is
// zeroed ONCE at start, not per step.
// ---------------------------------------------------------------------------
__global__ void hist_kernel(const int* __restrict__ dst, int* __restrict__ cnt)
{
    int e = blockIdx.x * 256 + threadIdx.x;
    if (e < NE) atomicAdd(&cnt[dst[e]], 1);
}

__global__ __launch_bounds__(256)
void scan1_kernel(const int* __restrict__ cnt, int* __restrict__ rowptr,
                  int* __restrict__ bsum)
{
    __shared__ int ts[256];
    int b = blockIdx.x, t = threadIdx.x;
    int base = b * 1024 + t * 4;
    int4 v = *(const int4*)&cnt[base];
    int s = v.x + v.y + v.z + v.w;
    ts[t] = s;
    __syncthreads();
    for (int off = 1; off < 256; off <<= 1) {
        int x = 0;
        if (t >= off) x = ts[t - off];
        __syncthreads();
        if (t >= off) ts[t] += x;
        __syncthreads();
    }
    int excl = ts[t] - s;
    if (t == 255) bsum[b] = ts[t];
    rowptr[base + 0] = excl;
    rowptr[base + 1] = excl + v.x;
    rowptr[base + 2] = excl + v.x + v.y;
    rowptr[base + 3] = excl + v.x + v.y + v.z;
}

__global__ __launch_bounds__(128)
void scan2_kernel(int* __restrict__ bsum, int nb)
{
    __shared__ int ts[128];
    int t = threadIdx.x;
    int v = (t < nb) ? bsum[t] : 0;
    ts[t] = v;
    __syncthreads();
    for (int off = 1; off < 128; off <<= 1) {
        int x = 0;
        if (t >= off) x = ts[t - off];
        __syncthreads();
        if (t >= off) ts[t] += x;
        __syncthreads();
    }
    if (t < nb) bsum[t] = ts[t] - v;   // exclusive
}

// fill: slot = final_rowptr[d] + (cnt[d]-- - 1); leaves cnt all-zero.
__global__ void fill_kernel(const int* __restrict__ dst,
                            const int* __restrict__ rowptr,
                            const int* __restrict__ bsum,
                            int* __restrict__ cnt, int* __restrict__ eidx)
{
    int e = blockIdx.x * 256 + threadIdx.x;
    if (e < NE) {
        int d = dst[e];
        int p = atomicAdd(&cnt[d], -1);            // old value in [1..deg]
        eidx[rowptr[d] + bsum[d >> 10] + p - 1] = e;
    }
}

// ---------------------------------------------------------------------------
// Prep: GRU weight transposes (f32) + bf16 B^T buffers for the MFMA GEMMs.
// ---------------------------------------------------------------------------
__global__ void prep_kernel(
    const float* __restrict__ emb_rel,
    const float* __restrict__ Wx, const float* __restrict__ Wh,
    const float* __restrict__ Wn1, const float* __restrict__ Wl1,
    const float* __restrict__ Wn2, const float* __restrict__ Wl2,
    const float* __restrict__ tgW, const float* __restrict__ gateW,
    const float* __restrict__ tdW,
    float* __restrict__ rel,
    float* __restrict__ WxT, float* __restrict__ WhT,
    short* __restrict__ BT1, short* __restrict__ BT2,
    short* __restrict__ BTe1, short* __restrict__ BTe2,
    short* __restrict__ BTe3)
{
    int tid = blockIdx.x * blockDim.x + threadIdx.x;
    int nthr = gridDim.x * blockDim.x;
    for (int i = tid; i < NR * HDIM; i += nthr)
        rel[i] = emb_rel[i];
    for (int i = tid; i < 384 * 256; i += nthr) {
        int r = i >> 8, c = i & 255;
        WxT[c * 384 + r] = Wx[i];
    }
    for (int i = tid; i < 384 * 128; i += nthr) {
        int r = i >> 7, c = i & 127;
        WhT[c * 384 + r] = Wh[i];
    }
    for (int i = tid; i < 128 * 256; i += nthr) {   // layer BTs: [x|h]@[Wn;Wl]
        int n = i >> 8, k = i & 255;
        float v1 = (k < 128) ? Wn1[k * 128 + n] : Wl1[(k - 128) * 128 + n];
        float v2 = (k < 128) ? Wn2[k * 128 + n] : Wl2[(k - 128) * 128 + n];
        BT1[n * 256 + k] = f2bs(v1);
        BT2[n * 256 + k] = f2bs(v2);
    }
    for (int i = tid; i < 128 * 128; i += nthr) {   // E1 (transpose), E3 (direct)
        int n = i >> 7, k = i & 127;
        BTe1[n * 128 + k] = f2bs(tgW[k * 128 + n]);
        BTe3[n * 128 + k] = f2bs(tdW[n * 128 + k]);
    }
    for (int i = tid; i < 128 * 256; i += nthr) {   // E2 (direct)
        int n = i >> 8, k = i & 255;
        BTe2[n * 256 + k] = f2bs(gateW[n * 256 + k]);
    }
}

// ---------------------------------------------------------------------------
// h0 = l2norm(dynamic_emb) stored bf16; one wave per row.
// ---------------------------------------------------------------------------
__global__ __launch_bounds__(64)
void norm_init_kernel(const float* __restrict__ emb, short* __restrict__ hb)
{
    int row = blockIdx.x, lane = threadIdx.x;
    float v0 = emb[row * HDIM + lane];
    float v1 = emb[row * HDIM + 64 + lane];
    float s = v0 * v0 + v1 * v1;
    #pragma unroll
    for (int off = 32; off; off >>= 1) s += __shfl_xor(s, off);
    float invn = 1.0f / fmaxf(sqrtf(s), 1e-12f);
    hb[row * HDIM + lane] = f2bs(v0 * invn);
    hb[row * HDIM + 64 + lane] = f2bs(v1 * invn);
}

// ---------------------------------------------------------------------------
// GRUCell relation evolution (f32 GEMV — tiny: 460 rows). Also writes a bf16
// shadow of the relation embeddings for the gather kernel.
// ---------------------------------------------------------------------------
__global__ __launch_bounds__(128)
void gru_kernel(float* rel, short* __restrict__ relb,
                const float* __restrict__ emb_rel,
                const float* __restrict__ WxT, const float* __restrict__ WhT,
                const float* __restrict__ bx, const float* __restrict__ bh)
{
    __shared__ __align__(16) float x[256];
    __shared__ __align__(16) float hh[128];
    int b = blockIdx.x, j = threadIdx.x;
    float hj = rel[b * HDIM + j];
    x[j] = emb_rel[b * HDIM + j];
    x[128 + j] = hj;
    hh[j] = hj;
    __syncthreads();
    float xr = 0, xz = 0, xn = 0, hr = 0, hz = 0, hn = 0;
    for (int k = 0; k < 256; k++) {
        float xv = x[k];
        const float* w = &WxT[k * 384];
        xr += xv * w[j]; xz += xv * w[128 + j]; xn += xv * w[256 + j];
    }
    for (int k = 0; k < 128; k++) {
        float hv = hh[k];
        const float* w = &WhT[k * 384];
        hr += hv * w[j]; hz += hv * w[128 + j]; hn += hv * w[256 + j];
    }
    float r = sigm(xr + bx[j] + hr + bh[j]);
    float z = sigm(xz + bx[128 + j] + hz + bh[128 + j]);
    float n = tanhf(xn + bx[256 + j] + r * (hn + bh[256 + j]));
    float nv = (1.0f - z) * n + z * hj;
    rel[b * HDIM + j] = nv;
    relb[b * HDIM + j] = f2bs(nv);
}

// ---------------------------------------------------------------------------
// CSR gather v3: 8 lanes/row (2x short8 per lane) -> 8 independent row
// chains per wave; 2-edge unrolled inner loop with independent load pairs.
// Mean degree is 2, so the cost is the dependent chain -> maximize MLP.
// rowptr is block-local; bsum[i>>10] applied on the fly.
// ---------------------------------------------------------------------------
__global__ __launch_bounds__(256)
void gather_kernel(const int* __restrict__ src, const int* __restrict__ et,
                   const int* __restrict__ eidx, const int* __restrict__ rowptr,
                   const int* __restrict__ bsum,
                   const short* __restrict__ hb, const short* __restrict__ relb,
                   short* __restrict__ aggb, int lo, int hi)
{
    int idx = blockIdx.x * 256 + threadIdx.x;
    int r = lo + (idx >> 3);
    if (r >= hi) return;
    int c16 = (idx & 7) * 16;
    int p0 = rowptr[r] + bsum[r >> 10];
    int p1 = rowptr[r + 1] + bsum[(r + 1) >> 10];
    float v[16];
    #pragma unroll
    for (int j = 0; j < 16; j++) v[j] = 0.0f;

    int p = p0;
    for (; p + 2 <= p1; p += 2) {
        int e0 = eidx[p], e1 = eidx[p + 1];
        int s0 = src[e0], t0 = et[e0];
        int s1 = src[e1], t1 = et[e1];
        short8 h00 = *(const short8*)&hb[(long)s0 * HDIM + c16];
        short8 h01 = *(const short8*)&hb[(long)s0 * HDIM + c16 + 8];
        short8 h10 = *(const short8*)&hb[(long)s1 * HDIM + c16];
        short8 h11 = *(const short8*)&hb[(long)s1 * HDIM + c16 + 8];
        short8 r00 = *(const short8*)&relb[t0 * HDIM + c16];
        short8 r01 = *(const short8*)&relb[t0 * HDIM + c16 + 8];
        short8 r10 = *(const short8*)&relb[t1 * HDIM + c16];
        short8 r11 = *(const short8*)&relb[t1 * HDIM + c16 + 8];
        #pragma unroll
        for (int j = 0; j < 8; j++) {
            v[j]     += bs2f(h00[j]) + bs2f(r00[j]) + bs2f(h10[j]) + bs2f(r10[j]);
            v[8 + j] += bs2f(h01[j]) + bs2f(r01[j]) + bs2f(h11[j]) + bs2f(r11[j]);
        }
    }
    if (p < p1) {
        int e0 = eidx[p];
        int s0 = src[e0], t0 = et[e0];
        short8 h00 = *(const short8*)&hb[(long)s0 * HDIM + c16];
        short8 h01 = *(const short8*)&hb[(long)s0 * HDIM + c16 + 8];
        short8 r00 = *(const short8*)&relb[t0 * HDIM + c16];
        short8 r01 = *(const short8*)&relb[t0 * HDIM + c16 + 8];
        #pragma unroll
        for (int j = 0; j < 8; j++) {
            v[j]     += bs2f(h00[j]) + bs2f(r00[j]);
            v[8 + j] += bs2f(h01[j]) + bs2f(r01[j]);
        }
    }

    float rdeg = (p1 > p0) ? 1.0f / (float)(p1 - p0) : 0.0f;
    short8 o0, o1;
    #pragma unroll
    for (int j = 0; j < 8; j++) {
        o0[j] = f2bs(v[j] * rdeg);
        o1[j] = f2bs(v[8 + j] * rdeg);
    }
    *(short8*)&aggb[(long)(r - lo) * HDIM + c16] = o0;
    *(short8*)&aggb[(long)(r - lo) * HDIM + c16 + 8] = o1;
}

// ---------------------------------------------------------------------------
// Layer MFMA GEMM: out = rrelu([aggb | hb] @ BT^T).
// BT (128x256 bf16 = 64 KB) staged into LDS once per block, XOR-swizzled.
// ---------------------------------------------------------------------------
template<int F32OUT>
__global__ __launch_bounds__(256, 2)
void layer_gemm(const short* __restrict__ aggb, const short* __restrict__ hb,
                const short* __restrict__ BTg, float* __restrict__ outf,
                short* __restrict__ outb, int lo, int hi)
{
    __shared__ __align__(16) short smBT[128 * 256];   // 64 KB
    const int tid = threadIdx.x;

    // stage BT with swizzle: 4096 slots of 8 shorts, 16 per thread
    #pragma unroll
    for (int it = 0; it < 16; it++) {
        int s = it * 256 + tid;
        int row = s >> 5, k8 = s & 31;
        short8 v = *(const short8*)&BTg[row * 256 + k8 * 8];
        *(short8*)&smBT[row * 256 + 8 * (k8 ^ (row & 7))] = v;
    }
    __syncthreads();

    const int lane = tid & 63;
    const int wv = tid >> 6;
    const int m = lane & 15, q = lane >> 4;
    const int rowBase = lo + blockIdx.x * 256 + wv * 64;

    f32x4 acc[4][8];
    #pragma unroll
    for (int rt = 0; rt < 4; rt++)
        #pragma unroll
        for (int ct = 0; ct < 8; ct++)
            acc[rt][ct] = (f32x4)0.0f;

    for (int kc = 0; kc < 8; kc++) {
        short8 a[4];
        #pragma unroll
        for (int rt = 0; rt < 4; rt++) {
            int row = rowBase + rt * 16 + m;
            int k0 = kc * 32 + q * 8;
            if (row < hi) {
                if (kc < 4) {
                    a[rt] = *(const short8*)&aggb[(long)(row - lo) * HDIM + k0];
                } else {
                    a[rt] = *(const short8*)&hb[(long)row * HDIM + (k0 - 128)];
                }
            } else {
                short8 t;
                #pragma unroll
                for (int i = 0; i < 8; i++) t[i] = 0;
                a[rt] = t;
            }
        }
        short8 b[8];
        #pragma unroll
        for (int ct = 0; ct < 8; ct++)
            b[ct] = *(const short8*)&smBT[(ct * 16 + m) * 256
                                          + 8 * ((kc * 4 + q) ^ (m & 7))];
        #pragma unroll
        for (int rt = 0; rt < 4; rt++)
            #pragma unroll
            for (int ct = 0; ct < 8; ct++)
                acc[rt][ct] = __builtin_amdgcn_mfma_f32_16x16x32_bf16(
                    a[rt], b[ct], acc[rt][ct], 0, 0, 0);
    }

    #pragma unroll
    for (int rt = 0; rt < 4; rt++) {
        #pragma unroll
        for (int rg = 0; rg < 4; rg++) {
            int row = rowBase + rt * 16 + q * 4 + rg;
            if (row >= hi) continue;
            #pragma unroll
            for (int ct = 0; ct < 8; ct++) {
                int col = ct * 16 + m;
                float c = acc[rt][ct][rg];
                c = c >= 0.0f ? c : SLOPE * c;
                if (F32OUT) outf[(long)row * HDIM + col] = c;
                else        outb[(long)row * HDIM + col] = f2bs(c);
            }
        }
    }
}

// ---------------------------------------------------------------------------
// Fused epilogue v9 — dual-tile interleaved pipeline (round-6 winner, frozen).
// ---------------------------------------------------------------------------
#define ER 32                  // rows per tile
#define ES 136                 // bf16 row stride (shorts)

__device__ __forceinline__ void stage_tile(
    const float* __restrict__ curf, const short* __restrict__ curb,
    const short* __restrict__ hb, long rb, int tid, int wf,
    short* cs, short* hd)
{
    #pragma unroll
    for (int it = 0; it < 2; it++) {
        int s = it * 256 + tid;
        int r = s >> 4, c8 = (s & 15) * 8;
        float x[8];
        if (wf) {
            const float* pc = &curf[(rb + r) * HDIM + c8];
            float4 c0 = *(const float4*)pc, c1 = *(const float4*)(pc + 4);
            x[0]=c0.x; x[1]=c0.y; x[2]=c0.z; x[3]=c0.w;
            x[4]=c1.x; x[5]=c1.y; x[6]=c1.z; x[7]=c1.w;
        } else {
            short8 cv = *(const short8*)&curb[(rb + r) * HDIM + c8];
            #pragma unroll
            for (int j = 0; j < 8; j++) x[j] = bs2f(cv[j]);
        }
        short8 th = *(const short8*)&hb[(rb + r) * HDIM + c8];
        float ss = x[0]*x[0] + x[1]*x[1] + x[2]*x[2] + x[3]*x[3]
                 + x[4]*x[4] + x[5]*x[5] + x[6]*x[6] + x[7]*x[7];
        ss += __shfl_xor(ss, 1);
        ss += __shfl_xor(ss, 2);
        ss += __shfl_xor(ss, 4);
        ss += __shfl_xor(ss, 8);
        float inv = 1.0f / fmaxf(sqrtf(ss), 1e-12f);
        short8 tc;
        #pragma unroll
        for (int j = 0; j < 8; j++) tc[j] = f2bs(x[j] * inv);
        *(short8*)&cs[r * ES + c8] = tc;
        *(short8*)&hd[r * ES + c8] = th;
    }
}

__device__ __forceinline__ void mm128(const short* As, const short* __restrict__ Bg,
                                      int wr0, int ct0, int m, int q, f32x4 acc[4])
{
    #pragma unroll
    for (int ct = 0; ct < 4; ct++) acc[ct] = (f32x4)0.0f;
    #pragma unroll
    for (int kc = 0; kc < 4; kc++) {
        int k0 = kc * 32 + q * 8;
        short8 a = *(const short8*)&As[(wr0 + m) * ES + k0];
        #pragma unroll
        for (int ct = 0; ct < 4; ct++) {
            short8 b = *(const short8*)&Bg[((ct0 + ct) * 16 + m) * 128 + k0];
            acc[ct] = __builtin_amdgcn_mfma_f32_16x16x32_bf16(a, b, acc[ct], 0, 0, 0);
        }
    }
}

__device__ __forceinline__ void mm256(const short* cs, const short* hd,
                                      const short* __restrict__ Bg,
                                      int wr0, int ct0, int m, int q, f32x4 acc[4])
{
    #pragma unroll
    for (int ct = 0; ct < 4; ct++) acc[ct] = (f32x4)0.0f;
    #pragma unroll
    for (int kc = 0; kc < 8; kc++) {
        int k0 = kc * 32 + q * 8;
        short8 a = (kc < 4) ? *(const short8*)&cs[(wr0 + m) * ES + k0]
                            : *(const short8*)&hd[(wr0 + m) * ES + (k0 - 128)];
        #pragma unroll
        for (int ct = 0; ct < 4; ct++) {
            short8 b = *(const short8*)&Bg[((ct0 + ct) * 16 + m) * 256 + k0];
            acc[ct] = __builtin_amdgcn_mfma_f32_16x16x32_bf16(a, b, acc[ct], 0, 0, 0);
        }
    }
}

__device__ __forceinline__ void epi1_f(const f32x4 acc[4], const float btr[4],
                                       short* cs, const short* hd,
                                       int wr0, int ct0, int m, int q)
{
    #pragma unroll
    for (int ct = 0; ct < 4; ct++) {
        int col = (ct0 + ct) * 16 + m;
        #pragma unroll
        for (int rg = 0; rg < 4; rg++) {
            int rl = wr0 + q * 4 + rg;
            float tw = sigm(acc[ct][rg] + btr[ct]);
            float curn = bs2f(cs[rl * ES + col]);
            float hv = bs2f(hd[rl * ES + col]);
            cs[rl * ES + col] = f2bs(tw * curn + (1.0f - tw) * hv);   // h1
        }
    }
}

__device__ __forceinline__ void epi2_f(const f32x4 acc[4], const float bgr[4],
                                       short* cs, short* hd,
                                       int wr0, int ct0, int m, int q)
{
    #pragma unroll
    for (int ct = 0; ct < 4; ct++) {
        int col = (ct0 + ct) * 16 + m;
        #pragma unroll
        for (int rg = 0; rg < 4; rg++) {
            int rl = wr0 + q * 4 + rg;
            float g = sigm(acc[ct][rg] + bgr[ct]);
            float h1v = bs2f(cs[rl * ES + col]);
            float hv = bs2f(hd[rl * ES + col]);
            float h2 = g * h1v + (1.0f - g) * hv;
            cs[rl * ES + col] = f2bs(h2);              // h2
            hd[rl * ES + col] = f2bs(h2 - hv);         // d (h dead now)
        }
    }
}

__device__ __forceinline__ void fin_f(const f32x4 acc[4], const float btdr[4],
                                      const short* cs, long rb,
                                      float* __restrict__ outp,
                                      short* __restrict__ abfo, int wf,
                                      int wr0, int ct0, int m, int q)
{
    #pragma unroll
    for (int ct = 0; ct < 4; ct++) {
        int col = (ct0 + ct) * 16 + m;
        #pragma unroll
        for (int rg = 0; rg < 4; rg++) {
            int rl = wr0 + q * 4 + rg;
            float td = fmaxf(acc[ct][rg] + btdr[ct], 0.0f);
            float val = bs2f(cs[rl * ES + col]) + td;
            if (wf) outp[(rb + rl) * HDIM + col] = val;
            else    abfo[(rb + rl) * HDIM + col] = f2bs(val);
        }
    }
}

__global__ __launch_bounds__(256, 4)
void fused_epi_kernel(const float* __restrict__ curf, const short* __restrict__ curb,
                      const short* __restrict__ hb,
                      const short* __restrict__ BTe1, const short* __restrict__ BTe2,
                      const short* __restrict__ BTe3,
                      const float* __restrict__ bt, const float* __restrict__ bg,
                      const float* __restrict__ btd,
                      float* __restrict__ outp, short* __restrict__ abfo, int wf)
{
    __shared__ __align__(16) short cs[2][ER * ES];   // cur_n -> h1 -> h2
    __shared__ __align__(16) short hd[2][ER * ES];   // h -> d
    const int tid = threadIdx.x;
    const long row0 = (long)blockIdx.x * (2 * ER);
    const long row1 = row0 + ER;
    const bool t1v = (row1 < N_ENT);

    stage_tile(curf, curb, hb, row0, tid, wf, cs[0], hd[0]);
    if (t1v) stage_tile(curf, curb, hb, row1, tid, wf, cs[1], hd[1]);
    __syncthreads();

    const int wv = tid >> 6, lane = tid & 63;
    const int m = lane & 15, q = lane >> 4;
    const int wr0 = (wv >> 1) * 16;                // wave's row base (0 or 16)
    const int ct0 = (wv & 1) * 4;                  // wave's col-tile base

    float btr[4], bgr[4], btdr[4];
    #pragma unroll
    for (int ct = 0; ct < 4; ct++) {
        btr[ct]  = bt[(ct0 + ct) * 16 + m];
        bgr[ct]  = bg[(ct0 + ct) * 16 + m];
        btdr[ct] = btd[(ct0 + ct) * 16 + m];
    }

    f32x4 a0[4], a1[4];

    // ---- E1 (both tiles, independent)
    mm128(cs[0], BTe1, wr0, ct0, m, q, a0);
    if (t1v) mm128(cs[1], BTe1, wr0, ct0, m, q, a1);
    __syncthreads();
    epi1_f(a0, btr, cs[0], hd[0], wr0, ct0, m, q);
    if (t1v) epi1_f(a1, btr, cs[1], hd[1], wr0, ct0, m, q);
    __syncthreads();

    // ---- E2
    mm256(cs[0], hd[0], BTe2, wr0, ct0, m, q, a0);
    if (t1v) mm256(cs[1], hd[1], BTe2, wr0, ct0, m, q, a1);
    __syncthreads();
    epi2_f(a0, bgr, cs[0], hd[0], wr0, ct0, m, q);
    if (t1v) epi2_f(a1, bgr, cs[1], hd[1], wr0, ct0, m, q);
    __syncthreads();

    // ---- E3
    mm128(hd[0], BTe3, wr0, ct0, m, q, a0);
    if (t1v) mm128(hd[1], BTe3, wr0, ct0, m, q, a1);
    // final: cs reads are same-lane (epi2 wrote them) -> no barrier
    fin_f(a0, btdr, cs[0], row0, outp, abfo, wf, wr0, ct0, m, q);
    if (t1v) fin_f(a1, btdr, cs[1], row1, outp, abfo, wf, wr0, ct0, m, q);
}

// ---------------------------------------------------------------------------
extern "C" void kernel_launch(void* const* d_in, const int* in_sizes, int n_in,
                              void* d_out, int out_size, void* d_ws, size_t ws_size,
                              hipStream_t stream)
{
    const int* src = (const int*)d_in[0];
    const int* dst = (const int*)d_in[1];
    const int* ety = (const int*)d_in[2];
    const float* dyn     = (const float*)d_in[3];
    const float* emb_rel = (const float*)d_in[4];
    const float* Wn1     = (const float*)d_in[5];
    const float* Wl1     = (const float*)d_in[6];
    const float* Wn2     = (const float*)d_in[7];
    const float* Wl2     = (const float*)d_in[8];
    const float* gWx     = (const float*)d_in[9];
    const float* gWh     = (const float*)d_in[10];
    const float* gbx     = (const float*)d_in[11];
    const float* gbh     = (const float*)d_in[12];
    const float* gateW   = (const float*)d_in[13];
    const float* gateb   = (const float*)d_in[14];
    const float* tdW     = (const float*)d_in[15];
    const float* tdb     = (const float*)d_in[16];
    const float* tgW     = (const float*)d_in[17];
    const float* tgb     = (const float*)d_in[18];

    const long NH = (long)N_ENT * HDIM;          // 12,800,000
    float* ws = (float*)d_ws;
    long off = 0;
    short* Abf  = (short*)(ws + off); off += NH / 2;   // bf16 h-state
    short* Bb   = (short*)(ws + off); off += NH / 2;   // bf16 layer1 out
    short* Cb   = (short*)(ws + off); off += NH / 2;   // bf16 layer2 out (t<3)
    float* rel  = ws + off; off += (long)NR * HDIM;
    short* relb = (short*)(ws + off); off += (NR * HDIM) / 2;
    float* WxT  = ws + off; off += 98304;
    float* WhT  = ws + off; off += 49152;
    short* BT1  = (short*)(ws + off); off += 16384;   // 128x256 bf16
    short* BT2  = (short*)(ws + off); off += 16384;
    short* BTe1 = (short*)(ws + off); off += 8192;    // 128x128 bf16
    short* BTe2 = (short*)(ws + off); off += 16384;
    short* BTe3 = (short*)(ws + off); off += 8192;
    int* rowptr = (int*)(ws + off); off += NPAD;
    int* cnt    = (int*)(ws + off); off += NPAD;
    int* eidx   = (int*)(ws + off); off += 200704;
    int* bsum   = (int*)(ws + off); off += 128;
    short* aggb = (short*)(ws + off);            // chunk*128 bf16
    float* C    = (float*)d_out;                 // f32 layer2 out (last step)

    const long avail = (long)(ws_size / 4) - off;
    const int cand[5] = {100000, 50000, 25008, 12512, 6256};
    int chunk = -1;
    for (int c = 0; c < 5; c++)
        if (avail >= (long)cand[c] * 64) { chunk = cand[c]; break; }

    if (chunk < 0) {
        diag_kernel<<<1, 64, 0, stream>>>((float*)d_out, (float)ws_size);
        return;
    }

    prep_kernel<<<256, 256, 0, stream>>>(
        emb_rel, gWx, gWh, Wn1, Wl1, Wn2, Wl2, tgW, gateW, tdW,
        rel, WxT, WhT, BT1, BT2, BTe1, BTe2, BTe3);

    norm_init_kernel<<<N_ENT, 64, 0, stream>>>(dyn, Abf);

    // cnt zeroed once; fill decrements it back to zero every step.
    zero_int_kernel<<<(NPAD + 255) / 256, 256, 0, stream>>>(cnt, NPAD);

    const int egrid = (NE + 255) / 256;          // 782 blocks
    const int fe_grid = (N_ENT + 63) / 64;       // 1563 dual-tile blocks

    for (int t = 0; t < NSTEP; t++) {
        const int* st = src + (long)t * NE;
        const int* dt = dst + (long)t * NE;
        const int* et = ety + (long)t * NE;

        // ---- CSR build (4 dispatches; scan3 folded into consumers)
        hist_kernel<<<egrid, 256, 0, stream>>>(dt, cnt);
        scan1_kernel<<<SCAN_NB, 256, 0, stream>>>(cnt, rowptr, bsum);
        scan2_kernel<<<1, 128, 0, stream>>>(bsum, SCAN_NB);
        fill_kernel<<<egrid, 256, 0, stream>>>(dt, rowptr, bsum, cnt, eidx);

        gru_kernel<<<NR, 128, 0, stream>>>(rel, relb, emb_rel, WxT, WhT, gbx, gbh);

        int wf = (t == NSTEP - 1) ? 1 : 0;

        // layer 1: Abf -> Bb (bf16)
        for (int lo = 0; lo < N_ENT; lo += chunk) {
            int hi = lo + chunk > N_ENT ? N_ENT : lo + chunk;
            gather_kernel<<<((hi - lo) * 8 + 255) / 256, 256, 0, stream>>>(
                st, et, eidx, rowptr, bsum, Abf, relb, aggb, lo, hi);
            layer_gemm<0><<<(hi - lo + 255) / 256, 256, 0, stream>>>(
                aggb, Abf, BT1, nullptr, Bb, lo, hi);
        }
        // layer 2: Bb -> Cb (bf16, t<3) or C (f32, t=3)
        for (int lo = 0; lo < N_ENT; lo += chunk) {
            int hi = lo + chunk > N_ENT ? N_ENT : lo + chunk;
            gather_kernel<<<((hi - lo) * 8 + 255) / 256, 256, 0, stream>>>(
                st, et, eidx, rowptr, bsum, Bb, relb, aggb, lo, hi);
            if (wf)
                layer_gemm<1><<<(hi - lo + 255) / 256, 256, 0, stream>>>(
                    aggb, Bb, BT2, C, nullptr, lo, hi);
            else
                layer_gemm<0><<<(hi - lo + 255) / 256, 256, 0, stream>>>(
                    aggb, Bb, BT2, nullptr, Cb, lo, hi);
        }

        // fused epilogue: (cur, Abf) -> Abf (t<3, bf16) or d_out == C (t=3)
        fused_epi_kernel<<<fe_grid, 256, 0, stream>>>(
            C, Cb, Abf, BTe1, BTe2, BTe3, tgb, gateb, tdb, C, Abf, wf);
    }
}

// Round 8
// 1031.429 us; speedup vs baseline: 1.5132x; 1.0057x over previous
//
#include <hip/hip_runtime.h>
#include <hip/hip_bf16.h>

#define N_ENT 100000
#define HDIM 128
#define NE 200000
#define NR 460
#define NSTEP 4
#define SLOPE 0.22916666666666666f
#define NPAD 100352            // N_ENT padded to 1024 multiple (98*1024)
#define SCAN_NB 98
#define HGRID 782              // hist blocks = ceil(NE/256)

typedef __attribute__((ext_vector_type(8))) short short8;
typedef __attribute__((ext_vector_type(4))) float f32x4;

__device__ __forceinline__ float sigm(float x) { return 1.0f / (1.0f + __expf(-x)); }
__device__ __forceinline__ short f2bs(float f) {
    __hip_bfloat16 b = __float2bfloat16(f);
    short s; __builtin_memcpy(&s, &b, 2); return s;
}
__device__ __forceinline__ float bs2f(short s) {
    union { unsigned int u; float f; } c;
    c.u = ((unsigned int)(unsigned short)s) << 16;
    return c.f;
}

// ---------------------------------------------------------------------------
__global__ void zero_int_kernel(int* __restrict__ p, int n)
{
    int i = blockIdx.x * 256 + threadIdx.x;
    if (i < n) p[i] = 0;
}

__global__ void diag_kernel(float* o, float v)
{
    if (threadIdx.x == 0) o[0] = v;
}

// ---------------------------------------------------------------------------
// hist + GRU fat kernel: blocks [0,HGRID) histogram dst into cnt; blocks
// [HGRID, HGRID+NR) run the GRUCell relation evolution (independent work,
// merged to hide gru latency under hist's atomics and save a launch).
// ---------------------------------------------------------------------------
__global__ __launch_bounds__(256)
void hist_gru_kernel(const int* __restrict__ dst, int* __restrict__ cnt,
                     float* rel, short* __restrict__ relb,
                     const float* __restrict__ emb_rel,
                     const float* __restrict__ WxT, const float* __restrict__ WhT,
                     const float* __restrict__ bx, const float* __restrict__ bh)
{
    if (blockIdx.x < HGRID) {
        int e = blockIdx.x * 256 + threadIdx.x;
        if (e < NE) atomicAdd(&cnt[dst[e]], 1);
        return;
    }
    // ---- GRU part
    __shared__ __align__(16) float x[256];
    __shared__ __align__(16) float hh[128];
    int b = blockIdx.x - HGRID;
    int j = threadIdx.x;
    float hj = 0.0f;
    if (j < 128) {
        hj = rel[b * HDIM + j];
        x[j] = emb_rel[b * HDIM + j];
        x[128 + j] = hj;
        hh[j] = hj;
    }
    __syncthreads();
    if (j >= 128) return;
    float xr = 0, xz = 0, xn = 0, hr = 0, hz = 0, hn = 0;
    for (int k = 0; k < 256; k++) {
        float xv = x[k];
        const float* w = &WxT[k * 384];
        xr += xv * w[j]; xz += xv * w[128 + j]; xn += xv * w[256 + j];
    }
    for (int k = 0; k < 128; k++) {
        float hv = hh[k];
        const float* w = &WhT[k * 384];
        hr += hv * w[j]; hz += hv * w[128 + j]; hn += hv * w[256 + j];
    }
    float r = sigm(xr + bx[j] + hr + bh[j]);
    float z = sigm(xz + bx[128 + j] + hz + bh[128 + j]);
    float n = tanhf(xn + bx[256 + j] + r * (hn + bh[256 + j]));
    float nv = (1.0f - z) * n + z * hj;
    rel[b * HDIM + j] = nv;
    relb[b * HDIM + j] = f2bs(nv);
}

__global__ __launch_bounds__(256)
void scan1_kernel(const int* __restrict__ cnt, int* __restrict__ rowptr,
                  int* __restrict__ bsum)
{
    __shared__ int ts[256];
    int b = blockIdx.x, t = threadIdx.x;
    int base = b * 1024 + t * 4;
    int4 v = *(const int4*)&cnt[base];
    int s = v.x + v.y + v.z + v.w;
    ts[t] = s;
    __syncthreads();
    for (int off = 1; off < 256; off <<= 1) {
        int x = 0;
        if (t >= off) x = ts[t - off];
        __syncthreads();
        if (t >= off) ts[t] += x;
        __syncthreads();
    }
    int excl = ts[t] - s;
    if (t == 255) bsum[b] = ts[t];
    rowptr[base + 0] = excl;
    rowptr[base + 1] = excl + v.x;
    rowptr[base + 2] = excl + v.x + v.y;
    rowptr[base + 3] = excl + v.x + v.y + v.z;
}

__global__ __launch_bounds__(128)
void scan2_kernel(int* __restrict__ bsum, int nb)
{
    __shared__ int ts[128];
    int t = threadIdx.x;
    int v = (t < nb) ? bsum[t] : 0;
    ts[t] = v;
    __syncthreads();
    for (int off = 1; off < 128; off <<= 1) {
        int x = 0;
        if (t >= off) x = ts[t - off];
        __syncthreads();
        if (t >= off) ts[t] += x;
        __syncthreads();
    }
    if (t < nb) bsum[t] = ts[t] - v;   // exclusive
}

// fill: slot = final_rowptr[d] + (cnt[d]-- - 1); leaves cnt all-zero.
__global__ void fill_kernel(const int* __restrict__ dst,
                            const int* __restrict__ rowptr,
                            const int* __restrict__ bsum,
                            int* __restrict__ cnt, int* __restrict__ eidx)
{
    int e = blockIdx.x * 256 + threadIdx.x;
    if (e < NE) {
        int d = dst[e];
        int p = atomicAdd(&cnt[d], -1);            // old value in [1..deg]
        eidx[rowptr[d] + bsum[d >> 10] + p - 1] = e;
    }
}

// ---------------------------------------------------------------------------
// Prep: GRU weight transposes (f32) + bf16 B^T buffers for the MFMA GEMMs.
// ---------------------------------------------------------------------------
__global__ void prep_kernel(
    const float* __restrict__ emb_rel,
    const float* __restrict__ Wx, const float* __restrict__ Wh,
    const float* __restrict__ Wn1, const float* __restrict__ Wl1,
    const float* __restrict__ Wn2, const float* __restrict__ Wl2,
    const float* __restrict__ tgW, const float* __restrict__ gateW,
    const float* __restrict__ tdW,
    float* __restrict__ rel,
    float* __restrict__ WxT, float* __restrict__ WhT,
    short* __restrict__ BT1, short* __restrict__ BT2,
    short* __restrict__ BTe1, short* __restrict__ BTe2,
    short* __restrict__ BTe3)
{
    int tid = blockIdx.x * blockDim.x + threadIdx.x;
    int nthr = gridDim.x * blockDim.x;
    for (int i = tid; i < NR * HDIM; i += nthr)
        rel[i] = emb_rel[i];
    for (int i = tid; i < 384 * 256; i += nthr) {
        int r = i >> 8, c = i & 255;
        WxT[c * 384 + r] = Wx[i];
    }
    for (int i = tid; i < 384 * 128; i += nthr) {
        int r = i >> 7, c = i & 127;
        WhT[c * 384 + r] = Wh[i];
    }
    for (int i = tid; i < 128 * 256; i += nthr) {   // layer BTs: [x|h]@[Wn;Wl]
        int n = i >> 8, k = i & 255;
        float v1 = (k < 128) ? Wn1[k * 128 + n] : Wl1[(k - 128) * 128 + n];
        float v2 = (k < 128) ? Wn2[k * 128 + n] : Wl2[(k - 128) * 128 + n];
        BT1[n * 256 + k] = f2bs(v1);
        BT2[n * 256 + k] = f2bs(v2);
    }
    for (int i = tid; i < 128 * 128; i += nthr) {   // E1 (transpose), E3 (direct)
        int n = i >> 7, k = i & 127;
        BTe1[n * 128 + k] = f2bs(tgW[k * 128 + n]);
        BTe3[n * 128 + k] = f2bs(tdW[n * 128 + k]);
    }
    for (int i = tid; i < 128 * 256; i += nthr) {   // E2 (direct)
        int n = i >> 8, k = i & 255;
        BTe2[n * 256 + k] = f2bs(gateW[n * 256 + k]);
    }
}

// ---------------------------------------------------------------------------
// h0 = l2norm(dynamic_emb) stored bf16; one wave per row.
// ---------------------------------------------------------------------------
__global__ __launch_bounds__(64)
void norm_init_kernel(const float* __restrict__ emb, short* __restrict__ hb)
{
    int row = blockIdx.x, lane = threadIdx.x;
    float v0 = emb[row * HDIM + lane];
    float v1 = emb[row * HDIM + 64 + lane];
    float s = v0 * v0 + v1 * v1;
    #pragma unroll
    for (int off = 32; off; off >>= 1) s += __shfl_xor(s, off);
    float invn = 1.0f / fmaxf(sqrtf(s), 1e-12f);
    hb[row * HDIM + lane] = f2bs(v0 * invn);
    hb[row * HDIM + 64 + lane] = f2bs(v1 * invn);
}

// ---------------------------------------------------------------------------
// CSR gather v3: 8 lanes/row (2x short8 per lane) -> 8 independent row
// chains per wave; 2-edge unrolled inner loop with independent load pairs.
// ---------------------------------------------------------------------------
__global__ __launch_bounds__(256)
void gather_kernel(const int* __restrict__ src, const int* __restrict__ et,
                   const int* __restrict__ eidx, const int* __restrict__ rowptr,
                   const int* __restrict__ bsum,
                   const short* __restrict__ hb, const short* __restrict__ relb,
                   short* __restrict__ aggb, int lo, int hi)
{
    int idx = blockIdx.x * 256 + threadIdx.x;
    int r = lo + (idx >> 3);
    if (r >= hi) return;
    int c16 = (idx & 7) * 16;
    int p0 = rowptr[r] + bsum[r >> 10];
    int p1 = rowptr[r + 1] + bsum[(r + 1) >> 10];
    float v[16];
    #pragma unroll
    for (int j = 0; j < 16; j++) v[j] = 0.0f;

    int p = p0;
    for (; p + 2 <= p1; p += 2) {
        int e0 = eidx[p], e1 = eidx[p + 1];
        int s0 = src[e0], t0 = et[e0];
        int s1 = src[e1], t1 = et[e1];
        short8 h00 = *(const short8*)&hb[(long)s0 * HDIM + c16];
        short8 h01 = *(const short8*)&hb[(long)s0 * HDIM + c16 + 8];
        short8 h10 = *(const short8*)&hb[(long)s1 * HDIM + c16];
        short8 h11 = *(const short8*)&hb[(long)s1 * HDIM + c16 + 8];
        short8 r00 = *(const short8*)&relb[t0 * HDIM + c16];
        short8 r01 = *(const short8*)&relb[t0 * HDIM + c16 + 8];
        short8 r10 = *(const short8*)&relb[t1 * HDIM + c16];
        short8 r11 = *(const short8*)&relb[t1 * HDIM + c16 + 8];
        #pragma unroll
        for (int j = 0; j < 8; j++) {
            v[j]     += bs2f(h00[j]) + bs2f(r00[j]) + bs2f(h10[j]) + bs2f(r10[j]);
            v[8 + j] += bs2f(h01[j]) + bs2f(r01[j]) + bs2f(h11[j]) + bs2f(r11[j]);
        }
    }
    if (p < p1) {
        int e0 = eidx[p];
        int s0 = src[e0], t0 = et[e0];
        short8 h00 = *(const short8*)&hb[(long)s0 * HDIM + c16];
        short8 h01 = *(const short8*)&hb[(long)s0 * HDIM + c16 + 8];
        short8 r00 = *(const short8*)&relb[t0 * HDIM + c16];
        short8 r01 = *(const short8*)&relb[t0 * HDIM + c16 + 8];
        #pragma unroll
        for (int j = 0; j < 8; j++) {
            v[j]     += bs2f(h00[j]) + bs2f(r00[j]);
            v[8 + j] += bs2f(h01[j]) + bs2f(r01[j]);
        }
    }

    float rdeg = (p1 > p0) ? 1.0f / (float)(p1 - p0) : 0.0f;
    short8 o0, o1;
    #pragma unroll
    for (int j = 0; j < 8; j++) {
        o0[j] = f2bs(v[j] * rdeg);
        o1[j] = f2bs(v[8 + j] * rdeg);
    }
    *(short8*)&aggb[(long)(r - lo) * HDIM + c16] = o0;
    *(short8*)&aggb[(long)(r - lo) * HDIM + c16 + 8] = o1;
}

// ---------------------------------------------------------------------------
// Layer MFMA GEMM: out = rrelu([aggb | hb] @ BT^T).
// BT (128x256 bf16 = 64 KB) staged into LDS once per block, XOR-swizzled.
// bf16 output goes through LDS for full-line coalesced short8 stores.
// ---------------------------------------------------------------------------
template<int F32OUT>
__global__ __launch_bounds__(256, 2)
void layer_gemm(const short* __restrict__ aggb, const short* __restrict__ hb,
                const short* __restrict__ BTg, float* __restrict__ outf,
                short* __restrict__ outb, int lo, int hi)
{
    __shared__ __align__(16) short smBT[128 * 256];   // 64 KB
    const int tid = threadIdx.x;

    // stage BT with swizzle: 4096 slots of 8 shorts, 16 per thread
    #pragma unroll
    for (int it = 0; it < 16; it++) {
        int s = it * 256 + tid;
        int row = s >> 5, k8 = s & 31;
        short8 v = *(const short8*)&BTg[row * 256 + k8 * 8];
        *(short8*)&smBT[row * 256 + 8 * (k8 ^ (row & 7))] = v;
    }
    __syncthreads();

    const int lane = tid & 63;
    const int wv = tid >> 6;
    const int m = lane & 15, q = lane >> 4;
    const int rowBase = lo + blockIdx.x * 256 + wv * 64;

    f32x4 acc[4][8];
    #pragma unroll
    for (int rt = 0; rt < 4; rt++)
        #pragma unroll
        for (int ct = 0; ct < 8; ct++)
            acc[rt][ct] = (f32x4)0.0f;

    for (int kc = 0; kc < 8; kc++) {
        short8 a[4];
        #pragma unroll
        for (int rt = 0; rt < 4; rt++) {
            int row = rowBase + rt * 16 + m;
            int k0 = kc * 32 + q * 8;
            if (row < hi) {
                if (kc < 4) {
                    a[rt] = *(const short8*)&aggb[(long)(row - lo) * HDIM + k0];
                } else {
                    a[rt] = *(const short8*)&hb[(long)row * HDIM + (k0 - 128)];
                }
            } else {
                short8 t;
                #pragma unroll
                for (int i = 0; i < 8; i++) t[i] = 0;
                a[rt] = t;
            }
        }
        short8 b[8];
        #pragma unroll
        for (int ct = 0; ct < 8; ct++)
            b[ct] = *(const short8*)&smBT[(ct * 16 + m) * 256
                                          + 8 * ((kc * 4 + q) ^ (m & 7))];
        #pragma unroll
        for (int rt = 0; rt < 4; rt++)
            #pragma unroll
            for (int ct = 0; ct < 8; ct++)
                acc[rt][ct] = __builtin_amdgcn_mfma_f32_16x16x32_bf16(
                    a[rt], b[ct], acc[rt][ct], 0, 0, 0);
    }

    #pragma unroll
    for (int rt = 0; rt < 4; rt++) {
        #pragma unroll
        for (int rg = 0; rg < 4; rg++) {
            int row = rowBase + rt * 16 + q * 4 + rg;
            if (row >= hi) continue;
            #pragma unroll
            for (int ct = 0; ct < 8; ct++) {
                int col = ct * 16 + m;
                float c = acc[rt][ct][rg];
                c = c >= 0.0f ? c : SLOPE * c;
                if (F32OUT) outf[(long)row * HDIM + col] = c;
                else        outb[(long)row * HDIM + col] = f2bs(c);
            }
        }
    }
}

// ---------------------------------------------------------------------------
// Fused epilogue v10 — dual-tile pipeline + coalesced bf16 output:
//   fin writes bf16 results into cs in place (same-lane), then a copy loop
//   streams cs -> abfo with short8 stores (16 B/lane, full HBM lines) —
//   replaces the 2-B scattered stores that caused 8x write amplification
//   (r6/r7 counters: WRITE_SIZE 202 MB vs 25.6 algorithmic).
// ---------------------------------------------------------------------------
#define ER 32                  // rows per tile
#define ES 136                 // bf16 row stride (shorts)

__device__ __forceinline__ void stage_tile(
    const float* __restrict__ curf, const short* __restrict__ curb,
    const short* __restrict__ hb, long rb, int tid, int wf,
    short* cs, short* hd)
{
    #pragma unroll
    for (int it = 0; it < 2; it++) {
        int s = it * 256 + tid;
        int r = s >> 4, c8 = (s & 15) * 8;
        float x[8];
        if (wf) {
            const float* pc = &curf[(rb + r) * HDIM + c8];
            float4 c0 = *(const float4*)pc, c1 = *(const float4*)(pc + 4);
            x[0]=c0.x; x[1]=c0.y; x[2]=c0.z; x[3]=c0.w;
            x[4]=c1.x; x[5]=c1.y; x[6]=c1.z; x[7]=c1.w;
        } else {
            short8 cv = *(const short8*)&curb[(rb + r) * HDIM + c8];
            #pragma unroll
            for (int j = 0; j < 8; j++) x[j] = bs2f(cv[j]);
        }
        short8 th = *(const short8*)&hb[(rb + r) * HDIM + c8];
        float ss = x[0]*x[0] + x[1]*x[1] + x[2]*x[2] + x[3]*x[3]
                 + x[4]*x[4] + x[5]*x[5] + x[6]*x[6] + x[7]*x[7];
        ss += __shfl_xor(ss, 1);
        ss += __shfl_xor(ss, 2);
        ss += __shfl_xor(ss, 4);
        ss += __shfl_xor(ss, 8);
        float inv = 1.0f / fmaxf(sqrtf(ss), 1e-12f);
        short8 tc;
        #pragma unroll
        for (int j = 0; j < 8; j++) tc[j] = f2bs(x[j] * inv);
        *(short8*)&cs[r * ES + c8] = tc;
        *(short8*)&hd[r * ES + c8] = th;
    }
}

__device__ __forceinline__ void mm128(const short* As, const short* __restrict__ Bg,
                                      int wr0, int ct0, int m, int q, f32x4 acc[4])
{
    #pragma unroll
    for (int ct = 0; ct < 4; ct++) acc[ct] = (f32x4)0.0f;
    #pragma unroll
    for (int kc = 0; kc < 4; kc++) {
        int k0 = kc * 32 + q * 8;
        short8 a = *(const short8*)&As[(wr0 + m) * ES + k0];
        #pragma unroll
        for (int ct = 0; ct < 4; ct++) {
            short8 b = *(const short8*)&Bg[((ct0 + ct) * 16 + m) * 128 + k0];
            acc[ct] = __builtin_amdgcn_mfma_f32_16x16x32_bf16(a, b, acc[ct], 0, 0, 0);
        }
    }
}

__device__ __forceinline__ void mm256(const short* cs, const short* hd,
                                      const short* __restrict__ Bg,
                                      int wr0, int ct0, int m, int q, f32x4 acc[4])
{
    #pragma unroll
    for (int ct = 0; ct < 4; ct++) acc[ct] = (f32x4)0.0f;
    #pragma unroll
    for (int kc = 0; kc < 8; kc++) {
        int k0 = kc * 32 + q * 8;
        short8 a = (kc < 4) ? *(const short8*)&cs[(wr0 + m) * ES + k0]
                            : *(const short8*)&hd[(wr0 + m) * ES + (k0 - 128)];
        #pragma unroll
        for (int ct = 0; ct < 4; ct++) {
            short8 b = *(const short8*)&Bg[((ct0 + ct) * 16 + m) * 256 + k0];
            acc[ct] = __builtin_amdgcn_mfma_f32_16x16x32_bf16(a, b, acc[ct], 0, 0, 0);
        }
    }
}

__device__ __forceinline__ void epi1_f(const f32x4 acc[4], const float btr[4],
                                       short* cs, const short* hd,
                                       int wr0, int ct0, int m, int q)
{
    #pragma unroll
    for (int ct = 0; ct < 4; ct++) {
        int col = (ct0 + ct) * 16 + m;
        #pragma unroll
        for (int rg = 0; rg < 4; rg++) {
            int rl = wr0 + q * 4 + rg;
            float tw = sigm(acc[ct][rg] + btr[ct]);
            float curn = bs2f(cs[rl * ES + col]);
            float hv = bs2f(hd[rl * ES + col]);
            cs[rl * ES + col] = f2bs(tw * curn + (1.0f - tw) * hv);   // h1
        }
    }
}

__device__ __forceinline__ void epi2_f(const f32x4 acc[4], const float bgr[4],
                                       short* cs, short* hd,
                                       int wr0, int ct0, int m, int q)
{
    #pragma unroll
    for (int ct = 0; ct < 4; ct++) {
        int col = (ct0 + ct) * 16 + m;
        #pragma unroll
        for (int rg = 0; rg < 4; rg++) {
            int rl = wr0 + q * 4 + rg;
            float g = sigm(acc[ct][rg] + bgr[ct]);
            float h1v = bs2f(cs[rl * ES + col]);
            float hv = bs2f(hd[rl * ES + col]);
            float h2 = g * h1v + (1.0f - g) * hv;
            cs[rl * ES + col] = f2bs(h2);              // h2
            hd[rl * ES + col] = f2bs(h2 - hv);         // d (h dead now)
        }
    }
}

// fin: wf=1 -> direct f32 stores (already 64-B segments);
//      wf=0 -> write bf16 result back into cs (same-lane), copied out later.
__device__ __forceinline__ void fin_f(const f32x4 acc[4], const float btdr[4],
                                      short* cs, long rb,
                                      float* __restrict__ outp, int wf,
                                      int wr0, int ct0, int m, int q)
{
    #pragma unroll
    for (int ct = 0; ct < 4; ct++) {
        int col = (ct0 + ct) * 16 + m;
        #pragma unroll
        for (int rg = 0; rg < 4; rg++) {
            int rl = wr0 + q * 4 + rg;
            float td = fmaxf(acc[ct][rg] + btdr[ct], 0.0f);
            float val = bs2f(cs[rl * ES + col]) + td;
            if (wf) outp[(rb + rl) * HDIM + col] = val;
            else    cs[rl * ES + col] = f2bs(val);
        }
    }
}

__global__ __launch_bounds__(256, 4)
void fused_epi_kernel(const float* __restrict__ curf, const short* __restrict__ curb,
                      const short* __restrict__ hb,
                      const short* __restrict__ BTe1, const short* __restrict__ BTe2,
                      const short* __restrict__ BTe3,
                      const float* __restrict__ bt, const float* __restrict__ bg,
                      const float* __restrict__ btd,
                      float* __restrict__ outp, short* __restrict__ abfo, int wf)
{
    __shared__ __align__(16) short cs[2][ER * ES];   // cur_n -> h1 -> h2 -> out
    __shared__ __align__(16) short hd[2][ER * ES];   // h -> d
    const int tid = threadIdx.x;
    const long row0 = (long)blockIdx.x * (2 * ER);
    const long row1 = row0 + ER;
    const bool t1v = (row1 < N_ENT);

    stage_tile(curf, curb, hb, row0, tid, wf, cs[0], hd[0]);
    if (t1v) stage_tile(curf, curb, hb, row1, tid, wf, cs[1], hd[1]);
    __syncthreads();

    const int wv = tid >> 6, lane = tid & 63;
    const int m = lane & 15, q = lane >> 4;
    const int wr0 = (wv >> 1) * 16;                // wave's row base (0 or 16)
    const int ct0 = (wv & 1) * 4;                  // wave's col-tile base

    float btr[4], bgr[4], btdr[4];
    #pragma unroll
    for (int ct = 0; ct < 4; ct++) {
        btr[ct]  = bt[(ct0 + ct) * 16 + m];
        bgr[ct]  = bg[(ct0 + ct) * 16 + m];
        btdr[ct] = btd[(ct0 + ct) * 16 + m];
    }

    f32x4 a0[4], a1[4];

    // ---- E1 (both tiles, independent)
    mm128(cs[0], BTe1, wr0, ct0, m, q, a0);
    if (t1v) mm128(cs[1], BTe1, wr0, ct0, m, q, a1);
    __syncthreads();
    epi1_f(a0, btr, cs[0], hd[0], wr0, ct0, m, q);
    if (t1v) epi1_f(a1, btr, cs[1], hd[1], wr0, ct0, m, q);
    __syncthreads();

    // ---- E2
    mm256(cs[0], hd[0], BTe2, wr0, ct0, m, q, a0);
    if (t1v) mm256(cs[1], hd[1], BTe2, wr0, ct0, m, q, a1);
    __syncthreads();
    epi2_f(a0, bgr, cs[0], hd[0], wr0, ct0, m, q);
    if (t1v) epi2_f(a1, bgr, cs[1], hd[1], wr0, ct0, m, q);
    __syncthreads();

    // ---- E3
    mm128(hd[0], BTe3, wr0, ct0, m, q, a0);
    if (t1v) mm128(hd[1], BTe3, wr0, ct0, m, q, a1);
    fin_f(a0, btdr, cs[0], row0, outp, wf, wr0, ct0, m, q);
    if (t1v) fin_f(a1, btdr, cs[1], row1, outp, wf, wr0, ct0, m, q);

    // ---- coalesced bf16 state store (wf=0): cs -> abfo as short8/lane
    if (!wf) {
        __syncthreads();
        #pragma unroll
        for (int it = 0; it < 4; it++) {
            int slot = it * 256 + tid;          // 0..1023
            int tile = slot >> 9;               // 0 or 1
            int rr = (slot >> 4) & 31;
            int c8 = (slot & 15) * 8;
            if (tile == 0 || t1v) {
                long gr = row0 + tile * ER + rr;
                *(short8*)&abfo[gr * HDIM + c8] =
                    *(const short8*)&cs[tile][rr * ES + c8];
            }
        }
    }
}

// ---------------------------------------------------------------------------
extern "C" void kernel_launch(void* const* d_in, const int* in_sizes, int n_in,
                              void* d_out, int out_size, void* d_ws, size_t ws_size,
                              hipStream_t stream)
{
    const int* src = (const int*)d_in[0];
    const int* dst = (const int*)d_in[1];
    const int* ety = (const int*)d_in[2];
    const float* dyn     = (const float*)d_in[3];
    const float* emb_rel = (const float*)d_in[4];
    const float* Wn1     = (const float*)d_in[5];
    const float* Wl1     = (const float*)d_in[6];
    const float* Wn2     = (const float*)d_in[7];
    const float* Wl2     = (const float*)d_in[8];
    const float* gWx     = (const float*)d_in[9];
    const float* gWh     = (const float*)d_in[10];
    const float* gbx     = (const float*)d_in[11];
    const float* gbh     = (const float*)d_in[12];
    const float* gateW   = (const float*)d_in[13];
    const float* gateb   = (const float*)d_in[14];
    const float* tdW     = (const float*)d_in[15];
    const float* tdb     = (const float*)d_in[16];
    const float* tgW     = (const float*)d_in[17];
    const float* tgb     = (const float*)d_in[18];

    const long NH = (long)N_ENT * HDIM;          // 12,800,000
    float* ws = (float*)d_ws;
    long off = 0;
    short* Abf  = (short*)(ws + off); off += NH / 2;   // bf16 h-state
    short* Bb   = (short*)(ws + off); off += NH / 2;   // bf16 layer1 out
    short* Cb   = (short*)(ws + off); off += NH / 2;   // bf16 layer2 out (t<3)
    float* rel  = ws + off; off += (long)NR * HDIM;
    short* relb = (short*)(ws + off); off += (NR * HDIM) / 2;
    float* WxT  = ws + off; off += 98304;
    float* WhT  = ws + off; off += 49152;
    short* BT1  = (short*)(ws + off); off += 16384;   // 128x256 bf16
    short* BT2  = (short*)(ws + off); off += 16384;
    short* BTe1 = (short*)(ws + off); off += 8192;    // 128x128 bf16
    short* BTe2 = (short*)(ws + off); off += 16384;
    short* BTe3 = (short*)(ws + off); off += 8192;
    int* rowptr = (int*)(ws + off); off += NPAD;
    int* cnt    = (int*)(ws + off); off += NPAD;
    int* eidx   = (int*)(ws + off); off += 200704;
    int* bsum   = (int*)(ws + off); off += 128;
    short* aggb = (short*)(ws + off);            // chunk*128 bf16
    float* C    = (float*)d_out;                 // f32 layer2 out (last step)

    const long avail = (long)(ws_size / 4) - off;
    const int cand[5] = {100000, 50000, 25008, 12512, 6256};
    int chunk = -1;
    for (int c = 0; c < 5; c++)
        if (avail >= (long)cand[c] * 64) { chunk = cand[c]; break; }

    if (chunk < 0) {
        diag_kernel<<<1, 64, 0, stream>>>((float*)d_out, (float)ws_size);
        return;
    }

    prep_kernel<<<256, 256, 0, stream>>>(
        emb_rel, gWx, gWh, Wn1, Wl1, Wn2, Wl2, tgW, gateW, tdW,
        rel, WxT, WhT, BT1, BT2, BTe1, BTe2, BTe3);

    norm_init_kernel<<<N_ENT, 64, 0, stream>>>(dyn, Abf);

    // cnt zeroed once; fill decrements it back to zero every step.
    zero_int_kernel<<<(NPAD + 255) / 256, 256, 0, stream>>>(cnt, NPAD);

    const int egrid = (NE + 255) / 256;          // 782 blocks
    const int fe_grid = (N_ENT + 63) / 64;       // 1563 dual-tile blocks

    for (int t = 0; t < NSTEP; t++) {
        const int* st = src + (long)t * NE;
        const int* dt = dst + (long)t * NE;
        const int* et = ety + (long)t * NE;

        // ---- hist + gru fat kernel, then scan/fill (3 more dispatches)
        hist_gru_kernel<<<HGRID + NR, 256, 0, stream>>>(
            dt, cnt, rel, relb, emb_rel, WxT, WhT, gbx, gbh);
        scan1_kernel<<<SCAN_NB, 256, 0, stream>>>(cnt, rowptr, bsum);
        scan2_kernel<<<1, 128, 0, stream>>>(bsum, SCAN_NB);
        fill_kernel<<<egrid, 256, 0, stream>>>(dt, rowptr, bsum, cnt, eidx);

        int wf = (t == NSTEP - 1) ? 1 : 0;

        // layer 1: Abf -> Bb (bf16)
        for (int lo = 0; lo < N_ENT; lo += chunk) {
            int hi = lo + chunk > N_ENT ? N_ENT : lo + chunk;
            gather_kernel<<<((hi - lo) * 8 + 255) / 256, 256, 0, stream>>>(
                st, et, eidx, rowptr, bsum, Abf, relb, aggb, lo, hi);
            layer_gemm<0><<<(hi - lo + 255) / 256, 256, 0, stream>>>(
                aggb, Abf, BT1, nullptr, Bb, lo, hi);
        }
        // layer 2: Bb -> Cb (bf16, t<3) or C (f32, t=3)
        for (int lo = 0; lo < N_ENT; lo += chunk) {
            int hi = lo + chunk > N_ENT ? N_ENT : lo + chunk;
            gather_kernel<<<((hi - lo) * 8 + 255) / 256, 256, 0, stream>>>(
                st, et, eidx, rowptr, bsum, Bb, relb, aggb, lo, hi);
            if (wf)
                layer_gemm<1><<<(hi - lo + 255) / 256, 256, 0, stream>>>(
                    aggb, Bb, BT2, C, nullptr, lo, hi);
            else
                layer_gemm<0><<<(hi - lo + 255) / 256, 256, 0, stream>>>(
                    aggb, Bb, BT2, nullptr, Cb, lo, hi);
        }

        // fused epilogue: (cur, Abf) -> Abf (t<3, bf16) or d_out == C (t=3)
        fused_epi_kernel<<<fe_grid, 256, 0, stream>>>(
            C, Cb, Abf, BTe1, BTe2, BTe3, tgb, gateb, tdb, C, Abf, wf);
    }
}

// Round 9
// 908.587 us; speedup vs baseline: 1.7178x; 1.1352x over previous
//
#include <hip/hip_runtime.h>
#include <hip/hip_bf16.h>

#define N_ENT 100000
#define HDIM 128
#define NE 200000
#define NR 460
#define NSTEP 4
#define SLOPE 0.22916666666666666f
#define NPAD 100352            // N_ENT padded to 1024 multiple (98*1024)
#define SCAN_NB 98
#define HGRID 782              // hist blocks = ceil(NE/256)

typedef __attribute__((ext_vector_type(8))) short short8;
typedef __attribute__((ext_vector_type(4))) float f32x4;

__device__ __forceinline__ float sigm(float x) { return 1.0f / (1.0f + __expf(-x)); }
__device__ __forceinline__ short f2bs(float f) {
    __hip_bfloat16 b = __float2bfloat16(f);
    short s; __builtin_memcpy(&s, &b, 2); return s;
}
__device__ __forceinline__ float bs2f(short s) {
    union { unsigned int u; float f; } c;
    c.u = ((unsigned int)(unsigned short)s) << 16;
    return c.f;
}

// ---------------------------------------------------------------------------
__global__ void zero_int_kernel(int* __restrict__ p, int n)
{
    int i = blockIdx.x * 256 + threadIdx.x;
    if (i < n) p[i] = 0;
}

__global__ void diag_kernel(float* o, float v)
{
    if (threadIdx.x == 0) o[0] = v;
}

// ---------------------------------------------------------------------------
// hist + GRU fat kernel: blocks [0,HGRID) histogram dst into cnt; blocks
// [HGRID, HGRID+NR) run the GRUCell relation evolution.
// ---------------------------------------------------------------------------
__global__ __launch_bounds__(256)
void hist_gru_kernel(const int* __restrict__ dst, int* __restrict__ cnt,
                     float* rel, short* __restrict__ relb,
                     const float* __restrict__ emb_rel,
                     const float* __restrict__ WxT, const float* __restrict__ WhT,
                     const float* __restrict__ bx, const float* __restrict__ bh)
{
    if (blockIdx.x < HGRID) {
        int e = blockIdx.x * 256 + threadIdx.x;
        if (e < NE) atomicAdd(&cnt[dst[e]], 1);
        return;
    }
    // ---- GRU part
    __shared__ __align__(16) float x[256];
    __shared__ __align__(16) float hh[128];
    int b = blockIdx.x - HGRID;
    int j = threadIdx.x;
    float hj = 0.0f;
    if (j < 128) {
        hj = rel[b * HDIM + j];
        x[j] = emb_rel[b * HDIM + j];
        x[128 + j] = hj;
        hh[j] = hj;
    }
    __syncthreads();
    if (j >= 128) return;
    float xr = 0, xz = 0, xn = 0, hr = 0, hz = 0, hn = 0;
    for (int k = 0; k < 256; k++) {
        float xv = x[k];
        const float* w = &WxT[k * 384];
        xr += xv * w[j]; xz += xv * w[128 + j]; xn += xv * w[256 + j];
    }
    for (int k = 0; k < 128; k++) {
        float hv = hh[k];
        const float* w = &WhT[k * 384];
        hr += hv * w[j]; hz += hv * w[128 + j]; hn += hv * w[256 + j];
    }
    float r = sigm(xr + bx[j] + hr + bh[j]);
    float z = sigm(xz + bx[128 + j] + hz + bh[128 + j]);
    float n = tanhf(xn + bx[256 + j] + r * (hn + bh[256 + j]));
    float nv = (1.0f - z) * n + z * hj;
    rel[b * HDIM + j] = nv;
    relb[b * HDIM + j] = f2bs(nv);
}

__global__ __launch_bounds__(256)
void scan1_kernel(const int* __restrict__ cnt, int* __restrict__ rowptr,
                  int* __restrict__ bsum)
{
    __shared__ int ts[256];
    int b = blockIdx.x, t = threadIdx.x;
    int base = b * 1024 + t * 4;
    int4 v = *(const int4*)&cnt[base];
    int s = v.x + v.y + v.z + v.w;
    ts[t] = s;
    __syncthreads();
    for (int off = 1; off < 256; off <<= 1) {
        int x = 0;
        if (t >= off) x = ts[t - off];
        __syncthreads();
        if (t >= off) ts[t] += x;
        __syncthreads();
    }
    int excl = ts[t] - s;
    if (t == 255) bsum[b] = ts[t];
    rowptr[base + 0] = excl;
    rowptr[base + 1] = excl + v.x;
    rowptr[base + 2] = excl + v.x + v.y;
    rowptr[base + 3] = excl + v.x + v.y + v.z;
}

__global__ __launch_bounds__(128)
void scan2_kernel(int* __restrict__ bsum, int nb)
{
    __shared__ int ts[128];
    int t = threadIdx.x;
    int v = (t < nb) ? bsum[t] : 0;
    ts[t] = v;
    __syncthreads();
    for (int off = 1; off < 128; off <<= 1) {
        int x = 0;
        if (t >= off) x = ts[t - off];
        __syncthreads();
        if (t >= off) ts[t] += x;
        __syncthreads();
    }
    if (t < nb) bsum[t] = ts[t] - v;   // exclusive
}

// fill: slot = final_rowptr[d] + (cnt[d]-- - 1); leaves cnt all-zero.
__global__ void fill_kernel(const int* __restrict__ dst,
                            const int* __restrict__ rowptr,
                            const int* __restrict__ bsum,
                            int* __restrict__ cnt, int* __restrict__ eidx)
{
    int e = blockIdx.x * 256 + threadIdx.x;
    if (e < NE) {
        int d = dst[e];
        int p = atomicAdd(&cnt[d], -1);            // old value in [1..deg]
        eidx[rowptr[d] + bsum[d >> 10] + p - 1] = e;
    }
}

// ---------------------------------------------------------------------------
// Prep: GRU weight transposes (f32) + bf16 B^T buffers for the MFMA GEMMs.
// ---------------------------------------------------------------------------
__global__ void prep_kernel(
    const float* __restrict__ emb_rel,
    const float* __restrict__ Wx, const float* __restrict__ Wh,
    const float* __restrict__ Wn1, const float* __restrict__ Wl1,
    const float* __restrict__ Wn2, const float* __restrict__ Wl2,
    const float* __restrict__ tgW, const float* __restrict__ gateW,
    const float* __restrict__ tdW,
    float* __restrict__ rel,
    float* __restrict__ WxT, float* __restrict__ WhT,
    short* __restrict__ BT1, short* __restrict__ BT2,
    short* __restrict__ BTe1, short* __restrict__ BTe2,
    short* __restrict__ BTe3)
{
    int tid = blockIdx.x * blockDim.x + threadIdx.x;
    int nthr = gridDim.x * blockDim.x;
    for (int i = tid; i < NR * HDIM; i += nthr)
        rel[i] = emb_rel[i];
    for (int i = tid; i < 384 * 256; i += nthr) {
        int r = i >> 8, c = i & 255;
        WxT[c * 384 + r] = Wx[i];
    }
    for (int i = tid; i < 384 * 128; i += nthr) {
        int r = i >> 7, c = i & 127;
        WhT[c * 384 + r] = Wh[i];
    }
    for (int i = tid; i < 128 * 256; i += nthr) {   // layer BTs: [x|h]@[Wn;Wl]
        int n = i >> 8, k = i & 255;
        float v1 = (k < 128) ? Wn1[k * 128 + n] : Wl1[(k - 128) * 128 + n];
        float v2 = (k < 128) ? Wn2[k * 128 + n] : Wl2[(k - 128) * 128 + n];
        BT1[n * 256 + k] = f2bs(v1);
        BT2[n * 256 + k] = f2bs(v2);
    }
    for (int i = tid; i < 128 * 128; i += nthr) {   // E1 (transpose), E3 (direct)
        int n = i >> 7, k = i & 127;
        BTe1[n * 128 + k] = f2bs(tgW[k * 128 + n]);
        BTe3[n * 128 + k] = f2bs(tdW[n * 128 + k]);
    }
    for (int i = tid; i < 128 * 256; i += nthr) {   // E2 (direct)
        int n = i >> 8, k = i & 255;
        BTe2[n * 256 + k] = f2bs(gateW[n * 256 + k]);
    }
}

// ---------------------------------------------------------------------------
// h0 = l2norm(dynamic_emb) stored bf16; one wave per row.
// ---------------------------------------------------------------------------
__global__ __launch_bounds__(64)
void norm_init_kernel(const float* __restrict__ emb, short* __restrict__ hb)
{
    int row = blockIdx.x, lane = threadIdx.x;
    float v0 = emb[row * HDIM + lane];
    float v1 = emb[row * HDIM + 64 + lane];
    float s = v0 * v0 + v1 * v1;
    #pragma unroll
    for (int off = 32; off; off >>= 1) s += __shfl_xor(s, off);
    float invn = 1.0f / fmaxf(sqrtf(s), 1e-12f);
    hb[row * HDIM + lane] = f2bs(v0 * invn);
    hb[row * HDIM + 64 + lane] = f2bs(v1 * invn);
}

// ---------------------------------------------------------------------------
// CSR gather v3: 8 lanes/row (2x short8 per lane) -> 8 independent row
// chains per wave; 2-edge unrolled inner loop with independent load pairs.
// ---------------------------------------------------------------------------
__global__ __launch_bounds__(256)
void gather_kernel(const int* __restrict__ src, const int* __restrict__ et,
                   const int* __restrict__ eidx, const int* __restrict__ rowptr,
                   const int* __restrict__ bsum,
                   const short* __restrict__ hb, const short* __restrict__ relb,
                   short* __restrict__ aggb, int lo, int hi)
{
    int idx = blockIdx.x * 256 + threadIdx.x;
    int r = lo + (idx >> 3);
    if (r >= hi) return;
    int c16 = (idx & 7) * 16;
    int p0 = rowptr[r] + bsum[r >> 10];
    int p1 = rowptr[r + 1] + bsum[(r + 1) >> 10];
    float v[16];
    #pragma unroll
    for (int j = 0; j < 16; j++) v[j] = 0.0f;

    int p = p0;
    for (; p + 2 <= p1; p += 2) {
        int e0 = eidx[p], e1 = eidx[p + 1];
        int s0 = src[e0], t0 = et[e0];
        int s1 = src[e1], t1 = et[e1];
        short8 h00 = *(const short8*)&hb[(long)s0 * HDIM + c16];
        short8 h01 = *(const short8*)&hb[(long)s0 * HDIM + c16 + 8];
        short8 h10 = *(const short8*)&hb[(long)s1 * HDIM + c16];
        short8 h11 = *(const short8*)&hb[(long)s1 * HDIM + c16 + 8];
        short8 r00 = *(const short8*)&relb[t0 * HDIM + c16];
        short8 r01 = *(const short8*)&relb[t0 * HDIM + c16 + 8];
        short8 r10 = *(const short8*)&relb[t1 * HDIM + c16];
        short8 r11 = *(const short8*)&relb[t1 * HDIM + c16 + 8];
        #pragma unroll
        for (int j = 0; j < 8; j++) {
            v[j]     += bs2f(h00[j]) + bs2f(r00[j]) + bs2f(h10[j]) + bs2f(r10[j]);
            v[8 + j] += bs2f(h01[j]) + bs2f(r01[j]) + bs2f(h11[j]) + bs2f(r11[j]);
        }
    }
    if (p < p1) {
        int e0 = eidx[p];
        int s0 = src[e0], t0 = et[e0];
        short8 h00 = *(const short8*)&hb[(long)s0 * HDIM + c16];
        short8 h01 = *(const short8*)&hb[(long)s0 * HDIM + c16 + 8];
        short8 r00 = *(const short8*)&relb[t0 * HDIM + c16];
        short8 r01 = *(const short8*)&relb[t0 * HDIM + c16 + 8];
        #pragma unroll
        for (int j = 0; j < 8; j++) {
            v[j]     += bs2f(h00[j]) + bs2f(r00[j]);
            v[8 + j] += bs2f(h01[j]) + bs2f(r01[j]);
        }
    }

    float rdeg = (p1 > p0) ? 1.0f / (float)(p1 - p0) : 0.0f;
    short8 o0, o1;
    #pragma unroll
    for (int j = 0; j < 8; j++) {
        o0[j] = f2bs(v[j] * rdeg);
        o1[j] = f2bs(v[8 + j] * rdeg);
    }
    *(short8*)&aggb[(long)(r - lo) * HDIM + c16] = o0;
    *(short8*)&aggb[(long)(r - lo) * HDIM + c16 + 8] = o1;
}

// ---------------------------------------------------------------------------
// Layer MFMA GEMM: out = rrelu([aggb | hb] @ BT^T).
// BT (128x256 bf16 = 64 KB) staged into LDS once per block, XOR-swizzled.
// ---------------------------------------------------------------------------
template<int F32OUT>
__global__ __launch_bounds__(256, 2)
void layer_gemm(const short* __restrict__ aggb, const short* __restrict__ hb,
                const short* __restrict__ BTg, float* __restrict__ outf,
                short* __restrict__ outb, int lo, int hi)
{
    __shared__ __align__(16) short smBT[128 * 256];   // 64 KB
    const int tid = threadIdx.x;

    // stage BT with swizzle: 4096 slots of 8 shorts, 16 per thread
    #pragma unroll
    for (int it = 0; it < 16; it++) {
        int s = it * 256 + tid;
        int row = s >> 5, k8 = s & 31;
        short8 v = *(const short8*)&BTg[row * 256 + k8 * 8];
        *(short8*)&smBT[row * 256 + 8 * (k8 ^ (row & 7))] = v;
    }
    __syncthreads();

    const int lane = tid & 63;
    const int wv = tid >> 6;
    const int m = lane & 15, q = lane >> 4;
    const int rowBase = lo + blockIdx.x * 256 + wv * 64;

    f32x4 acc[4][8];
    #pragma unroll
    for (int rt = 0; rt < 4; rt++)
        #pragma unroll
        for (int ct = 0; ct < 8; ct++)
            acc[rt][ct] = (f32x4)0.0f;

    for (int kc = 0; kc < 8; kc++) {
        short8 a[4];
        #pragma unroll
        for (int rt = 0; rt < 4; rt++) {
            int row = rowBase + rt * 16 + m;
            int k0 = kc * 32 + q * 8;
            if (row < hi) {
                if (kc < 4) {
                    a[rt] = *(const short8*)&aggb[(long)(row - lo) * HDIM + k0];
                } else {
                    a[rt] = *(const short8*)&hb[(long)row * HDIM + (k0 - 128)];
                }
            } else {
                short8 t;
                #pragma unroll
                for (int i = 0; i < 8; i++) t[i] = 0;
                a[rt] = t;
            }
        }
        short8 b[8];
        #pragma unroll
        for (int ct = 0; ct < 8; ct++)
            b[ct] = *(const short8*)&smBT[(ct * 16 + m) * 256
                                          + 8 * ((kc * 4 + q) ^ (m & 7))];
        #pragma unroll
        for (int rt = 0; rt < 4; rt++)
            #pragma unroll
            for (int ct = 0; ct < 8; ct++)
                acc[rt][ct] = __builtin_amdgcn_mfma_f32_16x16x32_bf16(
                    a[rt], b[ct], acc[rt][ct], 0, 0, 0);
    }

    #pragma unroll
    for (int rt = 0; rt < 4; rt++) {
        #pragma unroll
        for (int rg = 0; rg < 4; rg++) {
            int row = rowBase + rt * 16 + q * 4 + rg;
            if (row >= hi) continue;
            #pragma unroll
            for (int ct = 0; ct < 8; ct++) {
                int col = ct * 16 + m;
                float c = acc[rt][ct][rg];
                c = c >= 0.0f ? c : SLOPE * c;
                if (F32OUT) outf[(long)row * HDIM + col] = c;
                else        outb[(long)row * HDIM + col] = f2bs(c);
            }
        }
    }
}

// ---------------------------------------------------------------------------
// Fused epilogue v11 — dual-tile with SHARED B-fragments:
//   The two tiles are fused inside the k-loop: each B-fragment is loaded
//   from L2 once and feeds both tiles' MFMAs (v9/v10 loaded every fragment
//   twice; B-loads are 16-B stride-256 L2 hits with a dependent MFMA —
//   the prime latency-chain suspect for the ~110 us floor).  8 independent
//   accumulator chains per wave.  Barrier/LDS structure unchanged.
// ---------------------------------------------------------------------------
#define ER 32                  // rows per tile
#define ES 136                 // bf16 row stride (shorts)

__device__ __forceinline__ void stage_tile(
    const float* __restrict__ curf, const short* __restrict__ curb,
    const short* __restrict__ hb, long rb, int tid, int wf,
    short* cs, short* hd)
{
    #pragma unroll
    for (int it = 0; it < 2; it++) {
        int s = it * 256 + tid;
        int r = s >> 4, c8 = (s & 15) * 8;
        float x[8];
        if (wf) {
            const float* pc = &curf[(rb + r) * HDIM + c8];
            float4 c0 = *(const float4*)pc, c1 = *(const float4*)(pc + 4);
            x[0]=c0.x; x[1]=c0.y; x[2]=c0.z; x[3]=c0.w;
            x[4]=c1.x; x[5]=c1.y; x[6]=c1.z; x[7]=c1.w;
        } else {
            short8 cv = *(const short8*)&curb[(rb + r) * HDIM + c8];
            #pragma unroll
            for (int j = 0; j < 8; j++) x[j] = bs2f(cv[j]);
        }
        short8 th = *(const short8*)&hb[(rb + r) * HDIM + c8];
        float ss = x[0]*x[0] + x[1]*x[1] + x[2]*x[2] + x[3]*x[3]
                 + x[4]*x[4] + x[5]*x[5] + x[6]*x[6] + x[7]*x[7];
        ss += __shfl_xor(ss, 1);
        ss += __shfl_xor(ss, 2);
        ss += __shfl_xor(ss, 4);
        ss += __shfl_xor(ss, 8);
        float inv = 1.0f / fmaxf(sqrtf(ss), 1e-12f);
        short8 tc;
        #pragma unroll
        for (int j = 0; j < 8; j++) tc[j] = f2bs(x[j] * inv);
        *(short8*)&cs[r * ES + c8] = tc;
        *(short8*)&hd[r * ES + c8] = th;
    }
}

// K=128 dual-tile GEMM: one B-load feeds both tiles (8 chains/wave).
__device__ __forceinline__ void mm128_d(const short* As0, const short* As1,
                                        const short* __restrict__ Bg,
                                        int wr0, int ct0, int m, int q,
                                        f32x4 a0[4], f32x4 a1[4])
{
    #pragma unroll
    for (int ct = 0; ct < 4; ct++) { a0[ct] = (f32x4)0.0f; a1[ct] = (f32x4)0.0f; }
    #pragma unroll
    for (int kc = 0; kc < 4; kc++) {
        int k0 = kc * 32 + q * 8;
        short8 av0 = *(const short8*)&As0[(wr0 + m) * ES + k0];
        short8 av1 = *(const short8*)&As1[(wr0 + m) * ES + k0];
        #pragma unroll
        for (int ct = 0; ct < 4; ct++) {
            short8 b = *(const short8*)&Bg[((ct0 + ct) * 16 + m) * 128 + k0];
            a0[ct] = __builtin_amdgcn_mfma_f32_16x16x32_bf16(av0, b, a0[ct], 0, 0, 0);
            a1[ct] = __builtin_amdgcn_mfma_f32_16x16x32_bf16(av1, b, a1[ct], 0, 0, 0);
        }
    }
}

// K=256 dual-tile GEMM over [cs|hd], shared B.
__device__ __forceinline__ void mm256_d(const short* cs0, const short* hd0,
                                        const short* cs1, const short* hd1,
                                        const short* __restrict__ Bg,
                                        int wr0, int ct0, int m, int q,
                                        f32x4 a0[4], f32x4 a1[4])
{
    #pragma unroll
    for (int ct = 0; ct < 4; ct++) { a0[ct] = (f32x4)0.0f; a1[ct] = (f32x4)0.0f; }
    #pragma unroll
    for (int kc = 0; kc < 8; kc++) {
        int k0 = kc * 32 + q * 8;
        short8 av0 = (kc < 4) ? *(const short8*)&cs0[(wr0 + m) * ES + k0]
                              : *(const short8*)&hd0[(wr0 + m) * ES + (k0 - 128)];
        short8 av1 = (kc < 4) ? *(const short8*)&cs1[(wr0 + m) * ES + k0]
                              : *(const short8*)&hd1[(wr0 + m) * ES + (k0 - 128)];
        #pragma unroll
        for (int ct = 0; ct < 4; ct++) {
            short8 b = *(const short8*)&Bg[((ct0 + ct) * 16 + m) * 256 + k0];
            a0[ct] = __builtin_amdgcn_mfma_f32_16x16x32_bf16(av0, b, a0[ct], 0, 0, 0);
            a1[ct] = __builtin_amdgcn_mfma_f32_16x16x32_bf16(av1, b, a1[ct], 0, 0, 0);
        }
    }
}

__device__ __forceinline__ void epi1_f(const f32x4 acc[4], const float btr[4],
                                       short* cs, const short* hd,
                                       int wr0, int ct0, int m, int q)
{
    #pragma unroll
    for (int ct = 0; ct < 4; ct++) {
        int col = (ct0 + ct) * 16 + m;
        #pragma unroll
        for (int rg = 0; rg < 4; rg++) {
            int rl = wr0 + q * 4 + rg;
            float tw = sigm(acc[ct][rg] + btr[ct]);
            float curn = bs2f(cs[rl * ES + col]);
            float hv = bs2f(hd[rl * ES + col]);
            cs[rl * ES + col] = f2bs(tw * curn + (1.0f - tw) * hv);   // h1
        }
    }
}

__device__ __forceinline__ void epi2_f(const f32x4 acc[4], const float bgr[4],
                                       short* cs, short* hd,
                                       int wr0, int ct0, int m, int q)
{
    #pragma unroll
    for (int ct = 0; ct < 4; ct++) {
        int col = (ct0 + ct) * 16 + m;
        #pragma unroll
        for (int rg = 0; rg < 4; rg++) {
            int rl = wr0 + q * 4 + rg;
            float g = sigm(acc[ct][rg] + bgr[ct]);
            float h1v = bs2f(cs[rl * ES + col]);
            float hv = bs2f(hd[rl * ES + col]);
            float h2 = g * h1v + (1.0f - g) * hv;
            cs[rl * ES + col] = f2bs(h2);              // h2
            hd[rl * ES + col] = f2bs(h2 - hv);         // d (h dead now)
        }
    }
}

// fin: wf=1 -> direct f32 stores; wf=0 -> bf16 back into cs (same-lane).
__device__ __forceinline__ void fin_f(const f32x4 acc[4], const float btdr[4],
                                      short* cs, long rb,
                                      float* __restrict__ outp, int wf,
                                      int wr0, int ct0, int m, int q)
{
    #pragma unroll
    for (int ct = 0; ct < 4; ct++) {
        int col = (ct0 + ct) * 16 + m;
        #pragma unroll
        for (int rg = 0; rg < 4; rg++) {
            int rl = wr0 + q * 4 + rg;
            float td = fmaxf(acc[ct][rg] + btdr[ct], 0.0f);
            float val = bs2f(cs[rl * ES + col]) + td;
            if (wf) outp[(rb + rl) * HDIM + col] = val;
            else    cs[rl * ES + col] = f2bs(val);
        }
    }
}

__global__ __launch_bounds__(256, 4)
void fused_epi_kernel(const float* __restrict__ curf, const short* __restrict__ curb,
                      const short* __restrict__ hb,
                      const short* __restrict__ BTe1, const short* __restrict__ BTe2,
                      const short* __restrict__ BTe3,
                      const float* __restrict__ bt, const float* __restrict__ bg,
                      const float* __restrict__ btd,
                      float* __restrict__ outp, short* __restrict__ abfo, int wf)
{
    __shared__ __align__(16) short cs[2][ER * ES];   // cur_n -> h1 -> h2 -> out
    __shared__ __align__(16) short hd[2][ER * ES];   // h -> d
    const int tid = threadIdx.x;
    const long row0 = (long)blockIdx.x * (2 * ER);
    const long row1 = row0 + ER;
    const bool t1v = (row1 < N_ENT);

    stage_tile(curf, curb, hb, row0, tid, wf, cs[0], hd[0]);
    if (t1v) stage_tile(curf, curb, hb, row1, tid, wf, cs[1], hd[1]);
    __syncthreads();

    const int wv = tid >> 6, lane = tid & 63;
    const int m = lane & 15, q = lane >> 4;
    const int wr0 = (wv >> 1) * 16;                // wave's row base (0 or 16)
    const int ct0 = (wv & 1) * 4;                  // wave's col-tile base

    float btr[4], bgr[4], btdr[4];
    #pragma unroll
    for (int ct = 0; ct < 4; ct++) {
        btr[ct]  = bt[(ct0 + ct) * 16 + m];
        bgr[ct]  = bg[(ct0 + ct) * 16 + m];
        btdr[ct] = btd[(ct0 + ct) * 16 + m];
    }

    f32x4 a0[4], a1[4];

    // ---- E1 (shared-B dual-tile); tile1 compute is unguarded (LDS garbage
    //      for the tail block, discarded — only global stores are guarded).
    mm128_d(cs[0], cs[1], BTe1, wr0, ct0, m, q, a0, a1);
    __syncthreads();
    epi1_f(a0, btr, cs[0], hd[0], wr0, ct0, m, q);
    epi1_f(a1, btr, cs[1], hd[1], wr0, ct0, m, q);
    __syncthreads();

    // ---- E2
    mm256_d(cs[0], hd[0], cs[1], hd[1], BTe2, wr0, ct0, m, q, a0, a1);
    __syncthreads();
    epi2_f(a0, bgr, cs[0], hd[0], wr0, ct0, m, q);
    epi2_f(a1, bgr, cs[1], hd[1], wr0, ct0, m, q);
    __syncthreads();

    // ---- E3
    mm128_d(hd[0], hd[1], BTe3, wr0, ct0, m, q, a0, a1);
    fin_f(a0, btdr, cs[0], row0, outp, wf, wr0, ct0, m, q);
    if (t1v) fin_f(a1, btdr, cs[1], row1, outp, wf, wr0, ct0, m, q);

    // ---- coalesced bf16 state store (wf=0): cs -> abfo as short8/lane
    if (!wf) {
        __syncthreads();
        #pragma unroll
        for (int it = 0; it < 4; it++) {
            int slot = it * 256 + tid;          // 0..1023
            int tile = slot >> 9;               // 0 or 1
            int rr = (slot >> 4) & 31;
            int c8 = (slot & 15) * 8;
            if (tile == 0 || t1v) {
                long gr = row0 + tile * ER + rr;
                *(short8*)&abfo[gr * HDIM + c8] =
                    *(const short8*)&cs[tile][rr * ES + c8];
            }
        }
    }
}

// ---------------------------------------------------------------------------
extern "C" void kernel_launch(void* const* d_in, const int* in_sizes, int n_in,
                              void* d_out, int out_size, void* d_ws, size_t ws_size,
                              hipStream_t stream)
{
    const int* src = (const int*)d_in[0];
    const int* dst = (const int*)d_in[1];
    const int* ety = (const int*)d_in[2];
    const float* dyn     = (const float*)d_in[3];
    const float* emb_rel = (const float*)d_in[4];
    const float* Wn1     = (const float*)d_in[5];
    const float* Wl1     = (const float*)d_in[6];
    const float* Wn2     = (const float*)d_in[7];
    const float* Wl2     = (const float*)d_in[8];
    const float* gWx     = (const float*)d_in[9];
    const float* gWh     = (const float*)d_in[10];
    const float* gbx     = (const float*)d_in[11];
    const float* gbh     = (const float*)d_in[12];
    const float* gateW   = (const float*)d_in[13];
    const float* gateb   = (const float*)d_in[14];
    const float* tdW     = (const float*)d_in[15];
    const float* tdb     = (const float*)d_in[16];
    const float* tgW     = (const float*)d_in[17];
    const float* tgb     = (const float*)d_in[18];

    const long NH = (long)N_ENT * HDIM;          // 12,800,000
    float* ws = (float*)d_ws;
    long off = 0;
    short* Abf  = (short*)(ws + off); off += NH / 2;   // bf16 h-state
    short* Bb   = (short*)(ws + off); off += NH / 2;   // bf16 layer1 out
    short* Cb   = (short*)(ws + off); off += NH / 2;   // bf16 layer2 out (t<3)
    float* rel  = ws + off; off += (long)NR * HDIM;
    short* relb = (short*)(ws + off); off += (NR * HDIM) / 2;
    float* WxT  = ws + off; off += 98304;
    float* WhT  = ws + off; off += 49152;
    short* BT1  = (short*)(ws + off); off += 16384;   // 128x256 bf16
    short* BT2  = (short*)(ws + off); off += 16384;
    short* BTe1 = (short*)(ws + off); off += 8192;    // 128x128 bf16
    short* BTe2 = (short*)(ws + off); off += 16384;
    short* BTe3 = (short*)(ws + off); off += 8192;
    int* rowptr = (int*)(ws + off); off += NPAD;
    int* cnt    = (int*)(ws + off); off += NPAD;
    int* eidx   = (int*)(ws + off); off += 200704;
    int* bsum   = (int*)(ws + off); off += 128;
    short* aggb = (short*)(ws + off);            // chunk*128 bf16
    float* C    = (float*)d_out;                 // f32 layer2 out (last step)

    const long avail = (long)(ws_size / 4) - off;
    const int cand[5] = {100000, 50000, 25008, 12512, 6256};
    int chunk = -1;
    for (int c = 0; c < 5; c++)
        if (avail >= (long)cand[c] * 64) { chunk = cand[c]; break; }

    if (chunk < 0) {
        diag_kernel<<<1, 64, 0, stream>>>((float*)d_out, (float)ws_size);
        return;
    }

    prep_kernel<<<256, 256, 0, stream>>>(
        emb_rel, gWx, gWh, Wn1, Wl1, Wn2, Wl2, tgW, gateW, tdW,
        rel, WxT, WhT, BT1, BT2, BTe1, BTe2, BTe3);

    norm_init_kernel<<<N_ENT, 64, 0, stream>>>(dyn, Abf);

    // cnt zeroed once; fill decrements it back to zero every step.
    zero_int_kernel<<<(NPAD + 255) / 256, 256, 0, stream>>>(cnt, NPAD);

    const int egrid = (NE + 255) / 256;          // 782 blocks
    const int fe_grid = (N_ENT + 63) / 64;       // 1563 dual-tile blocks

    for (int t = 0; t < NSTEP; t++) {
        const int* st = src + (long)t * NE;
        const int* dt = dst + (long)t * NE;
        const int* et = ety + (long)t * NE;

        // ---- hist + gru fat kernel, then scan/fill
        hist_gru_kernel<<<HGRID + NR, 256, 0, stream>>>(
            dt, cnt, rel, relb, emb_rel, WxT, WhT, gbx, gbh);
        scan1_kernel<<<SCAN_NB, 256, 0, stream>>>(cnt, rowptr, bsum);
        scan2_kernel<<<1, 128, 0, stream>>>(bsum, SCAN_NB);
        fill_kernel<<<egrid, 256, 0, stream>>>(dt, rowptr, bsum, cnt, eidx);

        int wf = (t == NSTEP - 1) ? 1 : 0;

        // layer 1: Abf -> Bb (bf16)
        for (int lo = 0; lo < N_ENT; lo += chunk) {
            int hi = lo + chunk > N_ENT ? N_ENT : lo + chunk;
            gather_kernel<<<((hi - lo) * 8 + 255) / 256, 256, 0, stream>>>(
                st, et, eidx, rowptr, bsum, Abf, relb, aggb, lo, hi);
            layer_gemm<0><<<(hi - lo + 255) / 256, 256, 0, stream>>>(
                aggb, Abf, BT1, nullptr, Bb, lo, hi);
        }
        // layer 2: Bb -> Cb (bf16, t<3) or C (f32, t=3)
        for (int lo = 0; lo < N_ENT; lo += chunk) {
            int hi = lo + chunk > N_ENT ? N_ENT : lo + chunk;
            gather_kernel<<<((hi - lo) * 8 + 255) / 256, 256, 0, stream>>>(
                st, et, eidx, rowptr, bsum, Bb, relb, aggb, lo, hi);
            if (wf)
                layer_gemm<1><<<(hi - lo + 255) / 256, 256, 0, stream>>>(
                    aggb, Bb, BT2, C, nullptr, lo, hi);
            else
                layer_gemm<0><<<(hi - lo + 255) / 256, 256, 0, stream>>>(
                    aggb, Bb, BT2, nullptr, Cb, lo, hi);
        }

        // fused epilogue: (cur, Abf) -> Abf (t<3, bf16) or d_out == C (t=3)
        fused_epi_kernel<<<fe_grid, 256, 0, stream>>>(
            C, Cb, Abf, BTe1, BTe2, BTe3, tgb, gateb, tdb, C, Abf, wf);
    }
}

// Round 10
// 833.010 us; speedup vs baseline: 1.8736x; 1.0907x over previous
//
#include <hip/hip_runtime.h>
#include <hip/hip_bf16.h>

#define N_ENT 100000
#define HDIM 128
#define NE 200000
#define NR 460
#define NSTEP 4
#define SLOPE 0.22916666666666666f
#define NPAD 100352            // N_ENT padded to 1024 multiple (98*1024)
#define SCAN_NB 98
#define EGRID 782              // ceil(NE/256)
#define ESZ 200704             // eidx slice per step
#define FEG 1563               // epi blocks = ceil(N_ENT/64)

typedef __attribute__((ext_vector_type(8))) short short8;
typedef __attribute__((ext_vector_type(4))) float f32x4;

__device__ __forceinline__ float sigm(float x) { return 1.0f / (1.0f + __expf(-x)); }
__device__ __forceinline__ short f2bs(float f) {
    __hip_bfloat16 b = __float2bfloat16(f);
    short s; __builtin_memcpy(&s, &b, 2); return s;
}
__device__ __forceinline__ float bs2f(short s) {
    union { unsigned int u; float f; } c;
    c.u = ((unsigned int)(unsigned short)s) << 16;
    return c.f;
}

// ---------------------------------------------------------------------------
__global__ void zero_int_kernel(int* __restrict__ p, int n)
{
    int i = blockIdx.x * 256 + threadIdx.x;
    if (i < n) p[i] = 0;
}

__global__ void diag_kernel(float* o, float v)
{
    if (threadIdx.x == 0) o[0] = v;
}

// ---------------------------------------------------------------------------
// Batched CSR build for all 4 snapshot graphs (state-independent -> hoisted
// out of the time loop).  blockIdx.y = t.
// ---------------------------------------------------------------------------
__global__ void hist4_kernel(const int* __restrict__ dst, int* __restrict__ cnt4)
{
    int t = blockIdx.y;
    int e = blockIdx.x * 256 + threadIdx.x;
    if (e < NE) atomicAdd(&cnt4[t * NPAD + dst[(long)t * NE + e]], 1);
}

__global__ __launch_bounds__(256)
void scan1_4_kernel(const int* __restrict__ cnt4, int* __restrict__ rowptr4,
                    int* __restrict__ bsum4)
{
    __shared__ int ts[256];
    int t = blockIdx.y;
    int b = blockIdx.x, tt = threadIdx.x;
    int base = t * NPAD + b * 1024 + tt * 4;
    int4 v = *(const int4*)&cnt4[base];
    int s = v.x + v.y + v.z + v.w;
    ts[tt] = s;
    __syncthreads();
    for (int off = 1; off < 256; off <<= 1) {
        int x = 0;
        if (tt >= off) x = ts[tt - off];
        __syncthreads();
        if (tt >= off) ts[tt] += x;
        __syncthreads();
    }
    int excl = ts[tt] - s;
    if (tt == 255) bsum4[t * 128 + b] = ts[tt];
    rowptr4[base + 0] = excl;
    rowptr4[base + 1] = excl + v.x;
    rowptr4[base + 2] = excl + v.x + v.y;
    rowptr4[base + 3] = excl + v.x + v.y + v.z;
}

__global__ __launch_bounds__(128)
void scan2_4_kernel(int* __restrict__ bsum4)
{
    __shared__ int ts[128];
    int t = blockIdx.x;
    int tt = threadIdx.x;
    int v = (tt < SCAN_NB) ? bsum4[t * 128 + tt] : 0;
    ts[tt] = v;
    __syncthreads();
    for (int off = 1; off < 128; off <<= 1) {
        int x = 0;
        if (tt >= off) x = ts[tt - off];
        __syncthreads();
        if (tt >= off) ts[tt] += x;
        __syncthreads();
    }
    if (tt < SCAN_NB) bsum4[t * 128 + tt] = ts[tt] - v;   // exclusive
}

// fill: slot = rowptr[d] + bsum[d>>10] + (cnt[d]-- - 1); leaves cnt at zero.
__global__ void fill4_kernel(const int* __restrict__ dst,
                             const int* __restrict__ rowptr4,
                             const int* __restrict__ bsum4,
                             int* __restrict__ cnt4, int* __restrict__ eidx4)
{
    int t = blockIdx.y;
    int e = blockIdx.x * 256 + threadIdx.x;
    if (e < NE) {
        int d = dst[(long)t * NE + e];
        int p = atomicAdd(&cnt4[t * NPAD + d], -1);       // old value in [1..deg]
        eidx4[(long)t * ESZ + rowptr4[t * NPAD + d]
              + bsum4[t * 128 + (d >> 10)] + p - 1] = e;
    }
}

// ---------------------------------------------------------------------------
// Prep: GRU weight transposes (f32) + bf16 B^T buffers for the MFMA GEMMs.
// ---------------------------------------------------------------------------
__global__ void prep_kernel(
    const float* __restrict__ emb_rel,
    const float* __restrict__ Wx, const float* __restrict__ Wh,
    const float* __restrict__ Wn1, const float* __restrict__ Wl1,
    const float* __restrict__ Wn2, const float* __restrict__ Wl2,
    const float* __restrict__ tgW, const float* __restrict__ gateW,
    const float* __restrict__ tdW,
    float* __restrict__ rel,
    float* __restrict__ WxT, float* __restrict__ WhT,
    short* __restrict__ BT1, short* __restrict__ BT2,
    short* __restrict__ BTe1, short* __restrict__ BTe2,
    short* __restrict__ BTe3)
{
    int tid = blockIdx.x * blockDim.x + threadIdx.x;
    int nthr = gridDim.x * blockDim.x;
    for (int i = tid; i < NR * HDIM; i += nthr)
        rel[i] = emb_rel[i];
    for (int i = tid; i < 384 * 256; i += nthr) {
        int r = i >> 8, c = i & 255;
        WxT[c * 384 + r] = Wx[i];
    }
    for (int i = tid; i < 384 * 128; i += nthr) {
        int r = i >> 7, c = i & 127;
        WhT[c * 384 + r] = Wh[i];
    }
    for (int i = tid; i < 128 * 256; i += nthr) {   // layer BTs: [x|h]@[Wn;Wl]
        int n = i >> 8, k = i & 255;
        float v1 = (k < 128) ? Wn1[k * 128 + n] : Wl1[(k - 128) * 128 + n];
        float v2 = (k < 128) ? Wn2[k * 128 + n] : Wl2[(k - 128) * 128 + n];
        BT1[n * 256 + k] = f2bs(v1);
        BT2[n * 256 + k] = f2bs(v2);
    }
    for (int i = tid; i < 128 * 128; i += nthr) {   // E1 (transpose), E3 (direct)
        int n = i >> 7, k = i & 127;
        BTe1[n * 128 + k] = f2bs(tgW[k * 128 + n]);
        BTe3[n * 128 + k] = f2bs(tdW[n * 128 + k]);
    }
    for (int i = tid; i < 128 * 256; i += nthr) {   // E2 (direct)
        int n = i >> 8, k = i & 255;
        BTe2[n * 256 + k] = f2bs(gateW[n * 256 + k]);
    }
}

// ---------------------------------------------------------------------------
// h0 = l2norm(dynamic_emb) stored bf16; one wave per row.
// ---------------------------------------------------------------------------
__global__ __launch_bounds__(64)
void norm_init_kernel(const float* __restrict__ emb, short* __restrict__ hb)
{
    int row = blockIdx.x, lane = threadIdx.x;
    float v0 = emb[row * HDIM + lane];
    float v1 = emb[row * HDIM + 64 + lane];
    float s = v0 * v0 + v1 * v1;
    #pragma unroll
    for (int off = 32; off; off >>= 1) s += __shfl_xor(s, off);
    float invn = 1.0f / fmaxf(sqrtf(s), 1e-12f);
    hb[row * HDIM + lane] = f2bs(v0 * invn);
    hb[row * HDIM + 64 + lane] = f2bs(v1 * invn);
}

// ---------------------------------------------------------------------------
// GRUCell relation evolution (standalone — used for step 0 only; later steps
// ride inside the previous step's epi dispatch).
// ---------------------------------------------------------------------------
__global__ __launch_bounds__(128)
void gru_kernel(float* rel, short* __restrict__ relb,
                const float* __restrict__ emb_rel,
                const float* __restrict__ WxT, const float* __restrict__ WhT,
                const float* __restrict__ bx, const float* __restrict__ bh)
{
    __shared__ __align__(16) float x[256];
    __shared__ __align__(16) float hh[128];
    int b = blockIdx.x, j = threadIdx.x;
    float hj = rel[b * HDIM + j];
    x[j] = emb_rel[b * HDIM + j];
    x[128 + j] = hj;
    hh[j] = hj;
    __syncthreads();
    float xr = 0, xz = 0, xn = 0, hr = 0, hz = 0, hn = 0;
    for (int k = 0; k < 256; k++) {
        float xv = x[k];
        const float* w = &WxT[k * 384];
        xr += xv * w[j]; xz += xv * w[128 + j]; xn += xv * w[256 + j];
    }
    for (int k = 0; k < 128; k++) {
        float hv = hh[k];
        const float* w = &WhT[k * 384];
        hr += hv * w[j]; hz += hv * w[128 + j]; hn += hv * w[256 + j];
    }
    float r = sigm(xr + bx[j] + hr + bh[j]);
    float z = sigm(xz + bx[128 + j] + hz + bh[128 + j]);
    float n = tanhf(xn + bx[256 + j] + r * (hn + bh[256 + j]));
    float nv = (1.0f - z) * n + z * hj;
    rel[b * HDIM + j] = nv;
    relb[b * HDIM + j] = f2bs(nv);
}

// ---------------------------------------------------------------------------
// CSR gather v3: 8 lanes/row (2x short8 per lane) -> 8 independent row
// chains per wave; 2-edge unrolled inner loop with independent load pairs.
// ---------------------------------------------------------------------------
__global__ __launch_bounds__(256)
void gather_kernel(const int* __restrict__ src, const int* __restrict__ et,
                   const int* __restrict__ eidx, const int* __restrict__ rowptr,
                   const int* __restrict__ bsum,
                   const short* __restrict__ hb, const short* __restrict__ relb,
                   short* __restrict__ aggb, int lo, int hi)
{
    int idx = blockIdx.x * 256 + threadIdx.x;
    int r = lo + (idx >> 3);
    if (r >= hi) return;
    int c16 = (idx & 7) * 16;
    int p0 = rowptr[r] + bsum[r >> 10];
    int p1 = rowptr[r + 1] + bsum[(r + 1) >> 10];
    float v[16];
    #pragma unroll
    for (int j = 0; j < 16; j++) v[j] = 0.0f;

    int p = p0;
    for (; p + 2 <= p1; p += 2) {
        int e0 = eidx[p], e1 = eidx[p + 1];
        int s0 = src[e0], t0 = et[e0];
        int s1 = src[e1], t1 = et[e1];
        short8 h00 = *(const short8*)&hb[(long)s0 * HDIM + c16];
        short8 h01 = *(const short8*)&hb[(long)s0 * HDIM + c16 + 8];
        short8 h10 = *(const short8*)&hb[(long)s1 * HDIM + c16];
        short8 h11 = *(const short8*)&hb[(long)s1 * HDIM + c16 + 8];
        short8 r00 = *(const short8*)&relb[t0 * HDIM + c16];
        short8 r01 = *(const short8*)&relb[t0 * HDIM + c16 + 8];
        short8 r10 = *(const short8*)&relb[t1 * HDIM + c16];
        short8 r11 = *(const short8*)&relb[t1 * HDIM + c16 + 8];
        #pragma unroll
        for (int j = 0; j < 8; j++) {
            v[j]     += bs2f(h00[j]) + bs2f(r00[j]) + bs2f(h10[j]) + bs2f(r10[j]);
            v[8 + j] += bs2f(h01[j]) + bs2f(r01[j]) + bs2f(h11[j]) + bs2f(r11[j]);
        }
    }
    if (p < p1) {
        int e0 = eidx[p];
        int s0 = src[e0], t0 = et[e0];
        short8 h00 = *(const short8*)&hb[(long)s0 * HDIM + c16];
        short8 h01 = *(const short8*)&hb[(long)s0 * HDIM + c16 + 8];
        short8 r00 = *(const short8*)&relb[t0 * HDIM + c16];
        short8 r01 = *(const short8*)&relb[t0 * HDIM + c16 + 8];
        #pragma unroll
        for (int j = 0; j < 8; j++) {
            v[j]     += bs2f(h00[j]) + bs2f(r00[j]);
            v[8 + j] += bs2f(h01[j]) + bs2f(r01[j]);
        }
    }

    float rdeg = (p1 > p0) ? 1.0f / (float)(p1 - p0) : 0.0f;
    short8 o0, o1;
    #pragma unroll
    for (int j = 0; j < 8; j++) {
        o0[j] = f2bs(v[j] * rdeg);
        o1[j] = f2bs(v[8 + j] * rdeg);
    }
    *(short8*)&aggb[(long)(r - lo) * HDIM + c16] = o0;
    *(short8*)&aggb[(long)(r - lo) * HDIM + c16 + 8] = o1;
}

// ---------------------------------------------------------------------------
// Layer MFMA GEMM: out = rrelu([aggb | hb] @ BT^T).
// BT (128x256 bf16 = 64 KB) staged into LDS once per block, XOR-swizzled.
// ---------------------------------------------------------------------------
template<int F32OUT>
__global__ __launch_bounds__(256, 2)
void layer_gemm(const short* __restrict__ aggb, const short* __restrict__ hb,
                const short* __restrict__ BTg, float* __restrict__ outf,
                short* __restrict__ outb, int lo, int hi)
{
    __shared__ __align__(16) short smBT[128 * 256];   // 64 KB
    const int tid = threadIdx.x;

    // stage BT with swizzle: 4096 slots of 8 shorts, 16 per thread
    #pragma unroll
    for (int it = 0; it < 16; it++) {
        int s = it * 256 + tid;
        int row = s >> 5, k8 = s & 31;
        short8 v = *(const short8*)&BTg[row * 256 + k8 * 8];
        *(short8*)&smBT[row * 256 + 8 * (k8 ^ (row & 7))] = v;
    }
    __syncthreads();

    const int lane = tid & 63;
    const int wv = tid >> 6;
    const int m = lane & 15, q = lane >> 4;
    const int rowBase = lo + blockIdx.x * 256 + wv * 64;

    f32x4 acc[4][8];
    #pragma unroll
    for (int rt = 0; rt < 4; rt++)
        #pragma unroll
        for (int ct = 0; ct < 8; ct++)
            acc[rt][ct] = (f32x4)0.0f;

    for (int kc = 0; kc < 8; kc++) {
        short8 a[4];
        #pragma unroll
        for (int rt = 0; rt < 4; rt++) {
            int row = rowBase + rt * 16 + m;
            int k0 = kc * 32 + q * 8;
            if (row < hi) {
                if (kc < 4) {
                    a[rt] = *(const short8*)&aggb[(long)(row - lo) * HDIM + k0];
                } else {
                    a[rt] = *(const short8*)&hb[(long)row * HDIM + (k0 - 128)];
                }
            } else {
                short8 t;
                #pragma unroll
                for (int i = 0; i < 8; i++) t[i] = 0;
                a[rt] = t;
            }
        }
        short8 b[8];
        #pragma unroll
        for (int ct = 0; ct < 8; ct++)
            b[ct] = *(const short8*)&smBT[(ct * 16 + m) * 256
                                          + 8 * ((kc * 4 + q) ^ (m & 7))];
        #pragma unroll
        for (int rt = 0; rt < 4; rt++)
            #pragma unroll
            for (int ct = 0; ct < 8; ct++)
                acc[rt][ct] = __builtin_amdgcn_mfma_f32_16x16x32_bf16(
                    a[rt], b[ct], acc[rt][ct], 0, 0, 0);
    }

    #pragma unroll
    for (int rt = 0; rt < 4; rt++) {
        #pragma unroll
        for (int rg = 0; rg < 4; rg++) {
            int row = rowBase + rt * 16 + q * 4 + rg;
            if (row >= hi) continue;
            #pragma unroll
            for (int ct = 0; ct < 8; ct++) {
                int col = ct * 16 + m;
                float c = acc[rt][ct][rg];
                c = c >= 0.0f ? c : SLOPE * c;
                if (F32OUT) outf[(long)row * HDIM + col] = c;
                else        outb[(long)row * HDIM + col] = f2bs(c);
            }
        }
    }
}

// ---------------------------------------------------------------------------
// Fused epilogue v12 — dual-tile shared-B pipeline (r9 winner, frozen) +
// piggy-backed GRU blocks: blockIdx >= FEG run the GRUCell for the NEXT
// step (independent work; saves a dispatch and hides gru latency).
// ---------------------------------------------------------------------------
#define ER 32                  // rows per tile
#define ES 136                 // bf16 row stride (shorts)

__device__ __forceinline__ void stage_tile(
    const float* __restrict__ curf, const short* __restrict__ curb,
    const short* __restrict__ hb, long rb, int tid, int wf,
    short* cs, short* hd)
{
    #pragma unroll
    for (int it = 0; it < 2; it++) {
        int s = it * 256 + tid;
        int r = s >> 4, c8 = (s & 15) * 8;
        float x[8];
        if (wf) {
            const float* pc = &curf[(rb + r) * HDIM + c8];
            float4 c0 = *(const float4*)pc, c1 = *(const float4*)(pc + 4);
            x[0]=c0.x; x[1]=c0.y; x[2]=c0.z; x[3]=c0.w;
            x[4]=c1.x; x[5]=c1.y; x[6]=c1.z; x[7]=c1.w;
        } else {
            short8 cv = *(const short8*)&curb[(rb + r) * HDIM + c8];
            #pragma unroll
            for (int j = 0; j < 8; j++) x[j] = bs2f(cv[j]);
        }
        short8 th = *(const short8*)&hb[(rb + r) * HDIM + c8];
        float ss = x[0]*x[0] + x[1]*x[1] + x[2]*x[2] + x[3]*x[3]
                 + x[4]*x[4] + x[5]*x[5] + x[6]*x[6] + x[7]*x[7];
        ss += __shfl_xor(ss, 1);
        ss += __shfl_xor(ss, 2);
        ss += __shfl_xor(ss, 4);
        ss += __shfl_xor(ss, 8);
        float inv = 1.0f / fmaxf(sqrtf(ss), 1e-12f);
        short8 tc;
        #pragma unroll
        for (int j = 0; j < 8; j++) tc[j] = f2bs(x[j] * inv);
        *(short8*)&cs[r * ES + c8] = tc;
        *(short8*)&hd[r * ES + c8] = th;
    }
}

// K=128 dual-tile GEMM: one B-load feeds both tiles (8 chains/wave).
__device__ __forceinline__ void mm128_d(const short* As0, const short* As1,
                                        const short* __restrict__ Bg,
                                        int wr0, int ct0, int m, int q,
                                        f32x4 a0[4], f32x4 a1[4])
{
    #pragma unroll
    for (int ct = 0; ct < 4; ct++) { a0[ct] = (f32x4)0.0f; a1[ct] = (f32x4)0.0f; }
    #pragma unroll
    for (int kc = 0; kc < 4; kc++) {
        int k0 = kc * 32 + q * 8;
        short8 av0 = *(const short8*)&As0[(wr0 + m) * ES + k0];
        short8 av1 = *(const short8*)&As1[(wr0 + m) * ES + k0];
        #pragma unroll
        for (int ct = 0; ct < 4; ct++) {
            short8 b = *(const short8*)&Bg[((ct0 + ct) * 16 + m) * 128 + k0];
            a0[ct] = __builtin_amdgcn_mfma_f32_16x16x32_bf16(av0, b, a0[ct], 0, 0, 0);
            a1[ct] = __builtin_amdgcn_mfma_f32_16x16x32_bf16(av1, b, a1[ct], 0, 0, 0);
        }
    }
}

// K=256 dual-tile GEMM over [cs|hd], shared B.
__device__ __forceinline__ void mm256_d(const short* cs0, const short* hd0,
                                        const short* cs1, const short* hd1,
                                        const short* __restrict__ Bg,
                                        int wr0, int ct0, int m, int q,
                                        f32x4 a0[4], f32x4 a1[4])
{
    #pragma unroll
    for (int ct = 0; ct < 4; ct++) { a0[ct] = (f32x4)0.0f; a1[ct] = (f32x4)0.0f; }
    #pragma unroll
    for (int kc = 0; kc < 8; kc++) {
        int k0 = kc * 32 + q * 8;
        short8 av0 = (kc < 4) ? *(const short8*)&cs0[(wr0 + m) * ES + k0]
                              : *(const short8*)&hd0[(wr0 + m) * ES + (k0 - 128)];
        short8 av1 = (kc < 4) ? *(const short8*)&cs1[(wr0 + m) * ES + k0]
                              : *(const short8*)&hd1[(wr0 + m) * ES + (k0 - 128)];
        #pragma unroll
        for (int ct = 0; ct < 4; ct++) {
            short8 b = *(const short8*)&Bg[((ct0 + ct) * 16 + m) * 256 + k0];
            a0[ct] = __builtin_amdgcn_mfma_f32_16x16x32_bf16(av0, b, a0[ct], 0, 0, 0);
            a1[ct] = __builtin_amdgcn_mfma_f32_16x16x32_bf16(av1, b, a1[ct], 0, 0, 0);
        }
    }
}

__device__ __forceinline__ void epi1_f(const f32x4 acc[4], const float btr[4],
                                       short* cs, const short* hd,
                                       int wr0, int ct0, int m, int q)
{
    #pragma unroll
    for (int ct = 0; ct < 4; ct++) {
        int col = (ct0 + ct) * 16 + m;
        #pragma unroll
        for (int rg = 0; rg < 4; rg++) {
            int rl = wr0 + q * 4 + rg;
            float tw = sigm(acc[ct][rg] + btr[ct]);
            float curn = bs2f(cs[rl * ES + col]);
            float hv = bs2f(hd[rl * ES + col]);
            cs[rl * ES + col] = f2bs(tw * curn + (1.0f - tw) * hv);   // h1
        }
    }
}

__device__ __forceinline__ void epi2_f(const f32x4 acc[4], const float bgr[4],
                                       short* cs, short* hd,
                                       int wr0, int ct0, int m, int q)
{
    #pragma unroll
    for (int ct = 0; ct < 4; ct++) {
        int col = (ct0 + ct) * 16 + m;
        #pragma unroll
        for (int rg = 0; rg < 4; rg++) {
            int rl = wr0 + q * 4 + rg;
            float g = sigm(acc[ct][rg] + bgr[ct]);
            float h1v = bs2f(cs[rl * ES + col]);
            float hv = bs2f(hd[rl * ES + col]);
            float h2 = g * h1v + (1.0f - g) * hv;
            cs[rl * ES + col] = f2bs(h2);              // h2
            hd[rl * ES + col] = f2bs(h2 - hv);         // d (h dead now)
        }
    }
}

// fin: wf=1 -> direct f32 stores; wf=0 -> bf16 back into cs (same-lane).
__device__ __forceinline__ void fin_f(const f32x4 acc[4], const float btdr[4],
                                      short* cs, long rb,
                                      float* __restrict__ outp, int wf,
                                      int wr0, int ct0, int m, int q)
{
    #pragma unroll
    for (int ct = 0; ct < 4; ct++) {
        int col = (ct0 + ct) * 16 + m;
        #pragma unroll
        for (int rg = 0; rg < 4; rg++) {
            int rl = wr0 + q * 4 + rg;
            float td = fmaxf(acc[ct][rg] + btdr[ct], 0.0f);
            float val = bs2f(cs[rl * ES + col]) + td;
            if (wf) outp[(rb + rl) * HDIM + col] = val;
            else    cs[rl * ES + col] = f2bs(val);
        }
    }
}

__global__ __launch_bounds__(256, 4)
void fused_epi_kernel(const float* __restrict__ curf, const short* __restrict__ curb,
                      const short* __restrict__ hb,
                      const short* __restrict__ BTe1, const short* __restrict__ BTe2,
                      const short* __restrict__ BTe3,
                      const float* __restrict__ bt, const float* __restrict__ bg,
                      const float* __restrict__ btd,
                      float* __restrict__ outp, short* __restrict__ abfo, int wf,
                      float* rel, short* __restrict__ relb,
                      const float* __restrict__ emb_rel,
                      const float* __restrict__ WxT, const float* __restrict__ WhT,
                      const float* __restrict__ gbx, const float* __restrict__ gbh)
{
    __shared__ __align__(16) short cs[2][ER * ES];   // cur_n -> h1 -> h2 -> out
    __shared__ __align__(16) short hd[2][ER * ES];   // h -> d
    const int tid = threadIdx.x;

    // ---- piggy-backed GRU blocks (next step's relation evolution)
    if (blockIdx.x >= FEG) {
        float* x = (float*)cs;           // overlay LDS
        float* hh = x + 256;
        int b = blockIdx.x - FEG;
        int j = tid;
        float hj = 0.0f;
        if (j < 128) {
            hj = rel[b * HDIM + j];
            x[j] = emb_rel[b * HDIM + j];
            x[128 + j] = hj;
            hh[j] = hj;
        }
        __syncthreads();
        if (j >= 128) return;
        float xr = 0, xz = 0, xn = 0, hr = 0, hz = 0, hn = 0;
        for (int k = 0; k < 256; k++) {
            float xv = x[k];
            const float* w = &WxT[k * 384];
            xr += xv * w[j]; xz += xv * w[128 + j]; xn += xv * w[256 + j];
        }
        for (int k = 0; k < 128; k++) {
            float hv = hh[k];
            const float* w = &WhT[k * 384];
            hr += hv * w[j]; hz += hv * w[128 + j]; hn += hv * w[256 + j];
        }
        float r = sigm(xr + gbx[j] + hr + gbh[j]);
        float z = sigm(xz + gbx[128 + j] + hz + gbh[128 + j]);
        float n = tanhf(xn + gbx[256 + j] + r * (hn + gbh[256 + j]));
        float nv = (1.0f - z) * n + z * hj;
        rel[b * HDIM + j] = nv;
        relb[b * HDIM + j] = f2bs(nv);
        return;
    }

    const long row0 = (long)blockIdx.x * (2 * ER);
    const long row1 = row0 + ER;
    const bool t1v = (row1 < N_ENT);

    stage_tile(curf, curb, hb, row0, tid, wf, cs[0], hd[0]);
    if (t1v) stage_tile(curf, curb, hb, row1, tid, wf, cs[1], hd[1]);
    __syncthreads();

    const int wv = tid >> 6, lane = tid & 63;
    const int m = lane & 15, q = lane >> 4;
    const int wr0 = (wv >> 1) * 16;                // wave's row base (0 or 16)
    const int ct0 = (wv & 1) * 4;                  // wave's col-tile base

    float btr[4], bgr[4], btdr[4];
    #pragma unroll
    for (int ct = 0; ct < 4; ct++) {
        btr[ct]  = bt[(ct0 + ct) * 16 + m];
        bgr[ct]  = bg[(ct0 + ct) * 16 + m];
        btdr[ct] = btd[(ct0 + ct) * 16 + m];
    }

    f32x4 a0[4], a1[4];

    // ---- E1 (shared-B dual-tile); tile1 compute unguarded for tail block.
    mm128_d(cs[0], cs[1], BTe1, wr0, ct0, m, q, a0, a1);
    __syncthreads();
    epi1_f(a0, btr, cs[0], hd[0], wr0, ct0, m, q);
    epi1_f(a1, btr, cs[1], hd[1], wr0, ct0, m, q);
    __syncthreads();

    // ---- E2
    mm256_d(cs[0], hd[0], cs[1], hd[1], BTe2, wr0, ct0, m, q, a0, a1);
    __syncthreads();
    epi2_f(a0, bgr, cs[0], hd[0], wr0, ct0, m, q);
    epi2_f(a1, bgr, cs[1], hd[1], wr0, ct0, m, q);
    __syncthreads();

    // ---- E3
    mm128_d(hd[0], hd[1], BTe3, wr0, ct0, m, q, a0, a1);
    fin_f(a0, btdr, cs[0], row0, outp, wf, wr0, ct0, m, q);
    if (t1v) fin_f(a1, btdr, cs[1], row1, outp, wf, wr0, ct0, m, q);

    // ---- coalesced bf16 state store (wf=0): cs -> abfo as short8/lane
    if (!wf) {
        __syncthreads();
        #pragma unroll
        for (int it = 0; it < 4; it++) {
            int slot = it * 256 + tid;          // 0..1023
            int tile = slot >> 9;               // 0 or 1
            int rr = (slot >> 4) & 31;
            int c8 = (slot & 15) * 8;
            if (tile == 0 || t1v) {
                long gr = row0 + tile * ER + rr;
                *(short8*)&abfo[gr * HDIM + c8] =
                    *(const short8*)&cs[tile][rr * ES + c8];
            }
        }
    }
}

// ---------------------------------------------------------------------------
extern "C" void kernel_launch(void* const* d_in, const int* in_sizes, int n_in,
                              void* d_out, int out_size, void* d_ws, size_t ws_size,
                              hipStream_t stream)
{
    const int* src = (const int*)d_in[0];
    const int* dst = (const int*)d_in[1];
    const int* ety = (const int*)d_in[2];
    const float* dyn     = (const float*)d_in[3];
    const float* emb_rel = (const float*)d_in[4];
    const float* Wn1     = (const float*)d_in[5];
    const float* Wl1     = (const float*)d_in[6];
    const float* Wn2     = (const float*)d_in[7];
    const float* Wl2     = (const float*)d_in[8];
    const float* gWx     = (const float*)d_in[9];
    const float* gWh     = (const float*)d_in[10];
    const float* gbx     = (const float*)d_in[11];
    const float* gbh     = (const float*)d_in[12];
    const float* gateW   = (const float*)d_in[13];
    const float* gateb   = (const float*)d_in[14];
    const float* tdW     = (const float*)d_in[15];
    const float* tdb     = (const float*)d_in[16];
    const float* tgW     = (const float*)d_in[17];
    const float* tgb     = (const float*)d_in[18];

    const long NH = (long)N_ENT * HDIM;          // 12,800,000
    float* ws = (float*)d_ws;
    long off = 0;
    short* Abf  = (short*)(ws + off); off += NH / 2;   // bf16 h-state
    short* Bb   = (short*)(ws + off); off += NH / 2;   // bf16 layer1 out
    short* Cb   = (short*)(ws + off); off += NH / 2;   // bf16 layer2 out (t<3)
    float* rel  = ws + off; off += (long)NR * HDIM;
    short* relb = (short*)(ws + off); off += (NR * HDIM) / 2;
    float* WxT  = ws + off; off += 98304;
    float* WhT  = ws + off; off += 49152;
    short* BT1  = (short*)(ws + off); off += 16384;   // 128x256 bf16
    short* BT2  = (short*)(ws + off); off += 16384;
    short* BTe1 = (short*)(ws + off); off += 8192;    // 128x128 bf16
    short* BTe2 = (short*)(ws + off); off += 16384;
    short* BTe3 = (short*)(ws + off); off += 8192;
    int* rowptr4 = (int*)(ws + off); off += 4 * NPAD;
    int* cnt4    = (int*)(ws + off); off += 4 * NPAD;
    int* eidx4   = (int*)(ws + off); off += 4 * ESZ;
    int* bsum4   = (int*)(ws + off); off += 4 * 128;
    short* aggb = (short*)(ws + off);            // chunk*128 bf16
    float* C    = (float*)d_out;                 // f32 layer2 out (last step)

    const long avail = (long)(ws_size / 4) - off;
    const int cand[5] = {100000, 50000, 25008, 12512, 6256};
    int chunk = -1;
    for (int c = 0; c < 5; c++)
        if (avail >= (long)cand[c] * 64) { chunk = cand[c]; break; }

    if (chunk < 0) {
        diag_kernel<<<1, 64, 0, stream>>>((float*)d_out, (float)ws_size);
        return;
    }

    prep_kernel<<<256, 256, 0, stream>>>(
        emb_rel, gWx, gWh, Wn1, Wl1, Wn2, Wl2, tgW, gateW, tdW,
        rel, WxT, WhT, BT1, BT2, BTe1, BTe2, BTe3);

    norm_init_kernel<<<N_ENT, 64, 0, stream>>>(dyn, Abf);

    // ---- batched CSR build for ALL 4 snapshot graphs (state-independent)
    zero_int_kernel<<<(4 * NPAD + 255) / 256, 256, 0, stream>>>(cnt4, 4 * NPAD);
    {
        dim3 g2(EGRID, 4), g3(SCAN_NB, 4);
        hist4_kernel<<<g2, 256, 0, stream>>>(dst, cnt4);
        scan1_4_kernel<<<g3, 256, 0, stream>>>(cnt4, rowptr4, bsum4);
        scan2_4_kernel<<<4, 128, 0, stream>>>(bsum4);
        fill4_kernel<<<g2, 256, 0, stream>>>(dst, rowptr4, bsum4, cnt4, eidx4);
    }

    // step-0 relation evolution (later steps ride in the epi dispatch)
    gru_kernel<<<NR, 128, 0, stream>>>(rel, relb, emb_rel, WxT, WhT, gbx, gbh);

    for (int t = 0; t < NSTEP; t++) {
        const int* st = src + (long)t * NE;
        const int* et = ety + (long)t * NE;
        const int* rp = rowptr4 + t * NPAD;
        const int* bs = bsum4 + t * 128;
        const int* ei = eidx4 + (long)t * ESZ;

        int wf = (t == NSTEP - 1) ? 1 : 0;

        // layer 1: Abf -> Bb (bf16)
        for (int lo = 0; lo < N_ENT; lo += chunk) {
            int hi = lo + chunk > N_ENT ? N_ENT : lo + chunk;
            gather_kernel<<<((hi - lo) * 8 + 255) / 256, 256, 0, stream>>>(
                st, et, ei, rp, bs, Abf, relb, aggb, lo, hi);
            layer_gemm<0><<<(hi - lo + 255) / 256, 256, 0, stream>>>(
                aggb, Abf, BT1, nullptr, Bb, lo, hi);
        }
        // layer 2: Bb -> Cb (bf16, t<3) or C (f32, t=3)
        for (int lo = 0; lo < N_ENT; lo += chunk) {
            int hi = lo + chunk > N_ENT ? N_ENT : lo + chunk;
            gather_kernel<<<((hi - lo) * 8 + 255) / 256, 256, 0, stream>>>(
                st, et, ei, rp, bs, Bb, relb, aggb, lo, hi);
            if (wf)
                layer_gemm<1><<<(hi - lo + 255) / 256, 256, 0, stream>>>(
                    aggb, Bb, BT2, C, nullptr, lo, hi);
            else
                layer_gemm<0><<<(hi - lo + 255) / 256, 256, 0, stream>>>(
                    aggb, Bb, BT2, nullptr, Cb, lo, hi);
        }

        // fused epilogue (+ next step's GRU blocks when t<3):
        // (cur, Abf) -> Abf (t<3, bf16) or d_out == C (t=3)
        int ngru = wf ? 0 : NR;
        fused_epi_kernel<<<FEG + ngru, 256, 0, stream>>>(
            C, Cb, Abf, BTe1, BTe2, BTe3, tgb, gateb, tdb, C, Abf, wf,
            rel, relb, emb_rel, WxT, WhT, gbx, gbh);
    }
}